// Round 4
// baseline (317.884 us; speedup 1.0000x reference)
//
#include <hip/hip_runtime.h>
#include <math.h>

#define DI __device__ __forceinline__

typedef __attribute__((ext_vector_type(8))) short bf16x8;
typedef __attribute__((ext_vector_type(4))) float f32x4;

static constexpr int CC = 384;
// attn scale * log2(e): scores come out of QK^T already in log2 domain
static constexpr float QSCALE = 0.17677669529663687f * 1.4426950408889634f;
static constexpr float INVQS  = 1.0f / QSCALE;

DI unsigned short f2bf(float f){
  unsigned u = __float_as_uint(f);
  u += 0x7FFFu + ((u >> 16) & 1u);
  return (unsigned short)(u >> 16);
}
DI float bf2f(unsigned short u){ return __uint_as_float((unsigned)u << 16); }
DI float gelu_t(float x){
  return 0.5f * x * (1.f + tanhf(0.79788456080286536f * (x + 0.044715f * x * x * x)));
}
DI f32x4 mfma16(bf16x8 a, bf16x8 b, f32x4 c){
  return __builtin_amdgcn_mfma_f32_16x16x32_bf16(a, b, c, 0, 0, 0);
}
DI void gload16(const unsigned short* g, unsigned short* l){
  __builtin_amdgcn_global_load_lds(
      (const __attribute__((address_space(1))) unsigned int*)(const void*)g,
      (__attribute__((address_space(3))) unsigned int*)(void*)l, 16, 0, 0);
}

// ---------------- weight fp32 -> bf16 (six matmul weights, contiguous dst) -------
__global__ __launch_bounds__(256) void k_cvt_all(
    const float* __restrict__ wq, const float* __restrict__ wk,
    const float* __restrict__ wv, const float* __restrict__ wo,
    const float* __restrict__ w1, const float* __restrict__ w2,
    unsigned short* __restrict__ dst)
{
  int i = blockIdx.x*256 + threadIdx.x;
  if (i >= 1769472) return;
  const float* src; int off;
  if (i < 147456){ src = wq; off = i; }
  else if (i < 294912){ src = wk; off = i - 147456; }
  else if (i < 442368){ src = wv; off = i - 294912; }
  else if (i < 589824){ src = wo; off = i - 442368; }
  else if (i < 1179648){ src = w1; off = i - 589824; }
  else { src = w2; off = i - 1179648; }
  dst[i] = f2bf(src[off]);
}

// ---------------- LayerNorm over C=384, one wave per row -------------------------
__global__ __launch_bounds__(64) void k_ln(const float* __restrict__ x,
    const float* __restrict__ g, const float* __restrict__ b,
    float* __restrict__ outf, unsigned short* __restrict__ outb)
{
  int row = blockIdx.x; int l = threadIdx.x;
  const float* xp = x + (size_t)row * CC;
  float v[6]; float s = 0.f, s2 = 0.f;
#pragma unroll
  for (int p = 0; p < 6; p++){ float t = xp[l + 64*p]; v[p] = t; s += t; s2 += t*t; }
#pragma unroll
  for (int m = 32; m; m >>= 1){ s += __shfl_xor(s, m); s2 += __shfl_xor(s2, m); }
  float mu = s * (1.f/CC);
  float var = s2 * (1.f/CC) - mu*mu;
  float rs = rsqrtf(var + 1e-5f);
#pragma unroll
  for (int p = 0; p < 6; p++){
    int c = l + 64*p;
    float o = (v[p] - mu) * rs * g[c] + b[c];
    if (outf) outf[(size_t)row*CC + c] = o;
    if (outb) outb[(size_t)row*CC + c] = f2bf(o);
  }
}

// ---------------- 128x128 GEMM, BK=64, global_load_lds + XOR swizzle -------------
// out(M,N) = A(M,K) @ W(N,K)^T + bias
// EPI 0: f32   1: bf16   2: f32 + res   3: bf16 gelu
// EPI 4: bf16 transposed+key-permuted to VT[b][h][d][permkey]
// EPI 5: bf16 * QSCALE only
template<int EPI>
__global__ __launch_bounds__(256) void k_gemm128(
    const unsigned short* __restrict__ A, const unsigned short* __restrict__ W,
    const float* __restrict__ bias, const float* __restrict__ res,
    float* __restrict__ outf, unsigned short* __restrict__ outb, int N, int K)
{
  __shared__ unsigned short As[8192];   // 128 rows x 64 cols bf16, slot-swizzled
  __shared__ unsigned short Bs[8192];
  int t = threadIdx.x;
  int w = t >> 6, l = t & 63;
  int g = l >> 4, ln = l & 15;
  int wm = w >> 1, wn = w & 1;
  int bm = blockIdx.y * 128, bn = blockIdx.x * 128;
  f32x4 acc[4][4];
#pragma unroll
  for (int i = 0; i < 4; i++)
#pragma unroll
    for (int j = 0; j < 4; j++) acc[i][j] = (f32x4){0.f,0.f,0.f,0.f};
  int srcoff = ((l & 7) ^ (l >> 3)) * 8;
  const unsigned short* Ap[4]; const unsigned short* Wp[4];
#pragma unroll
  for (int j = 0; j < 4; j++){
    int row = j*32 + w*8 + (l >> 3);
    Ap[j] = A + (size_t)(bm + row)*K + srcoff;
    Wp[j] = W + (size_t)(bn + row)*K + srcoff;
  }
  unsigned short* Asl = As + w*512;
  unsigned short* Bsl = Bs + w*512;
  for (int k0 = 0; k0 < K; k0 += 64){
#pragma unroll
    for (int j = 0; j < 4; j++) gload16(Ap[j] + k0, Asl + j*2048);
#pragma unroll
    for (int j = 0; j < 4; j++) gload16(Wp[j] + k0, Bsl + j*2048);
    __syncthreads();
#pragma unroll
    for (int kk = 0; kk < 2; kk++){
      bf16x8 af[4], bf[4];
#pragma unroll
      for (int mi = 0; mi < 4; mi++){
        int row = wm*64 + mi*16 + ln;
        int sl = (kk*4 + g) ^ (ln & 7);
        af[mi] = *(const bf16x8*)((const char*)As + row*128 + sl*16);
      }
#pragma unroll
      for (int ni = 0; ni < 4; ni++){
        int row = wn*64 + ni*16 + ln;
        int sl = (kk*4 + g) ^ (ln & 7);
        bf[ni] = *(const bf16x8*)((const char*)Bs + row*128 + sl*16);
      }
#pragma unroll
      for (int mi = 0; mi < 4; mi++)
#pragma unroll
        for (int ni = 0; ni < 4; ni++)
          acc[mi][ni] = mfma16(af[mi], bf[ni], acc[mi][ni]);
    }
    __syncthreads();
  }
#pragma unroll
  for (int mi = 0; mi < 4; mi++)
#pragma unroll
  for (int ni = 0; ni < 4; ni++){
    int col = bn + wn*64 + ni*16 + ln;
    float bv = bias[col];
#pragma unroll
    for (int i = 0; i < 4; i++){
      int row = bm + wm*64 + mi*16 + g*4 + i;
      float v = acc[mi][ni][i] + bv;
      if constexpr (EPI == 2) v += res[(size_t)row*N + col];
      if constexpr (EPI == 3) v = gelu_t(v);
      if constexpr (EPI == 0 || EPI == 2) outf[(size_t)row*N + col] = v;
      if constexpr (EPI == 1 || EPI == 3) outb[(size_t)row*N + col] = f2bf(v);
      if constexpr (EPI == 5) outb[(size_t)row*N + col] = f2bf(v * QSCALE);
      if constexpr (EPI == 4){
        int bb = row >> 10, key = row & 1023, h = col >> 5, d = col & 31;
        int k6 = key & 63;
        int phys = (key & ~63) | ((k6 & 15) << 2) | (k6 >> 4);
        outb[(size_t)(((bb*12 + h) << 5) + d)*1024 + phys] = f2bf(v);
      }
    }
  }
}

// ---------------- fused offset net + grid sample (bf16 inputs) -------------------
// qs: scaled bf16 Q (QSCALE folded in); xnb: bf16 LN1 output
__global__ __launch_bounds__(128) void k_offset_sample(
    const unsigned short* __restrict__ qs, const unsigned short* __restrict__ xnb,
    const float* __restrict__ offk, const float* __restrict__ offkb,
    const float* __restrict__ offg, const float* __restrict__ offb,
    const float* __restrict__ Woff, const float* __restrict__ boff,
    unsigned short* __restrict__ xsb)
{
  int blk = blockIdx.x;
  int pix = (blk & 7)*2048 + (blk >> 3);   // each XCD gets 2 contiguous images
  int b = pix >> 10, n = pix & 1023;
  int y = n >> 5, x = n & 31;
  int t = threadIdx.x;
  int w = t >> 6;
  const unsigned short* qb = qs + (size_t)b*1024*CC;
  int toff[25]; bool tval[25];
#pragma unroll
  for (int tap = 0; tap < 25; tap++){
    int ky = tap/5, kx = tap - ky*5;
    int yy = y + ky - 2, xx = x + kx - 2;
    tval[tap] = (yy >= 0) & (yy < 32) & (xx >= 0) & (xx < 32);
    int yc = yy < 0 ? 0 : (yy > 31 ? 31 : yy);
    int xc = xx < 0 ? 0 : (xx > 31 ? 31 : xx);
    toff[tap] = (yc*32 + xc)*CC;
  }
  float conv[3];
#pragma unroll
  for (int cc = 0; cc < 3; cc++){
    int c = t + cc*128;
    float qv[25], wv[25];
#pragma unroll
    for (int tap = 0; tap < 25; tap++){
      qv[tap] = bf2f(qb[toff[tap] + c]);
      wv[tap] = offk[tap*CC + c];
    }
    float acc = 0.f;
#pragma unroll
    for (int tap = 0; tap < 25; tap++)
      acc = fmaf(tval[tap] ? qv[tap] : 0.f, wv[tap], acc);
    conv[cc] = acc * INVQS + offkb[c];   // undo QSCALE on the dot, then bias
  }
  __shared__ float rb[2][2];
  float s = conv[0]+conv[1]+conv[2];
  float s2 = conv[0]*conv[0]+conv[1]*conv[1]+conv[2]*conv[2];
#pragma unroll
  for (int m = 32; m; m >>= 1){ s += __shfl_xor(s, m); s2 += __shfl_xor(s2, m); }
  if ((t & 63) == 0){ rb[w][0] = s; rb[w][1] = s2; }
  __syncthreads();
  s = rb[0][0] + rb[1][0]; s2 = rb[0][1] + rb[1][1];
  float mu = s * (1.f/CC);
  float var = s2 * (1.f/CC) - mu*mu;
  float rs = rsqrtf(var + 1e-5f);
  __syncthreads();
  float p0 = 0.f, p1 = 0.f;
#pragma unroll
  for (int cc = 0; cc < 3; cc++){
    int c = t + cc*128;
    float v = (conv[cc] - mu) * rs * offg[c] + offb[c];
    v = gelu_t(v);
    p0 += v * Woff[c];
    p1 += v * Woff[CC + c];
  }
#pragma unroll
  for (int m = 32; m; m >>= 1){ p0 += __shfl_xor(p0, m); p1 += __shfl_xor(p1, m); }
  if ((t & 63) == 0){ rb[w][0] = p0; rb[w][1] = p1; }
  __syncthreads();
  p0 = rb[0][0] + rb[1][0]; p1 = rb[0][1] + rb[1][1];
  float offy = tanhf(p0 + boff[0]) * 0.125f;
  float offx = tanhf(p1 + boff[1]) * 0.125f;
  float py = ((y + 0.5f)/16.f - 1.f + offy + 1.f) * 0.5f * 31.f;
  float px = ((x + 0.5f)/16.f - 1.f + offx + 1.f) * 0.5f * 31.f;
  float y0f = floorf(py), x0f = floorf(px);
  float wy = py - y0f, wx = px - x0f;
  int y0 = (int)y0f, x0 = (int)x0f;
  y0 = y0 < 0 ? 0 : (y0 > 31 ? 31 : y0);
  x0 = x0 < 0 ? 0 : (x0 > 31 ? 31 : x0);
  int y1 = y0 + 1 > 31 ? 31 : y0 + 1;
  int x1 = x0 + 1 > 31 ? 31 : x0 + 1;
  size_t i00 = (size_t)(b*1024 + y0*32 + x0)*CC;
  size_t i01 = (size_t)(b*1024 + y0*32 + x1)*CC;
  size_t i10 = (size_t)(b*1024 + y1*32 + x0)*CC;
  size_t i11 = (size_t)(b*1024 + y1*32 + x1)*CC;
  float w00 = (1.f-wy)*(1.f-wx), w01 = (1.f-wy)*wx, w10 = wy*(1.f-wx), w11 = wy*wx;
#pragma unroll
  for (int cc = 0; cc < 3; cc++){
    int c = t + cc*128;
    float r = bf2f(xnb[i00+c])*w00 + bf2f(xnb[i01+c])*w01
            + bf2f(xnb[i10+c])*w10 + bf2f(xnb[i11+c])*w11;
    xsb[(size_t)(b*1024 + n)*CC + c] = f2bf(r);
  }
}

// ---------------- attention: base-2 no-max softmax, packed P writes --------------
// qs: bf16 Q scaled by QSCALE; kb row-major; vt: V^T [b][h][d][1024] key-permuted
// (within each 64-key block, phys slot p holds logical key (p&3)*16 + (p>>2))
__global__ __launch_bounds__(256) void k_attn(
    const unsigned short* __restrict__ qs, const unsigned short* __restrict__ kb,
    const unsigned short* __restrict__ vt, unsigned short* __restrict__ ob)
{
  __shared__ unsigned short Ks[64][40];   // [key][dim]
  __shared__ unsigned short Vs[32][72];   // [dim][physkey]
  __shared__ unsigned short Ps[4][32][72];// [qrow][physkey]
  int blk = blockIdx.x;
  int sw = (blk & 7)*192 + (blk >> 3);    // XCD-grouped
  int qt = sw & 7, h = (sw >> 3) % 12, b = sw / 96;
  int t = threadIdx.x;
  int w = t >> 6, l = t & 63;
  int g = l >> 4, ln = l & 15;
  int q0 = qt*128 + w*32;
  bf16x8 qa[2];
#pragma unroll
  for (int mi = 0; mi < 2; mi++)
    qa[mi] = *(const bf16x8*)&qs[(size_t)(b*1024 + q0 + mi*16 + ln)*CC + h*32 + g*8];
  f32x4 z = {0.f,0.f,0.f,0.f};
  f32x4 oacc[2][2]; oacc[0][0]=z; oacc[0][1]=z; oacc[1][0]=z; oacc[1][1]=z;
  float lsum[2][4] = {{0.f,0.f,0.f,0.f},{0.f,0.f,0.f,0.f}};
  const unsigned short* vbase = vt + (size_t)((b*12 + h)*32)*1024;
  const unsigned short* kbase = kb + (size_t)(b*1024)*CC + h*32;

  for (int kt = 0; kt < 16; kt++){
    int k0 = kt*64;
    *(uint4*)&Ks[t>>2][(t&3)*8] = *(const uint4*)(kbase + (size_t)(k0 + (t>>2))*CC + (t&3)*8);
    *(uint4*)&Vs[t>>3][(t&7)*8] = *(const uint4*)(vbase + (size_t)(t>>3)*1024 + k0 + (t&7)*8);
    __syncthreads();
    bf16x8 kf[4];
#pragma unroll
    for (int nt = 0; nt < 4; nt++) kf[nt] = *(const bf16x8*)&Ks[nt*16 + ln][g*8];
    f32x4 s[2][4];
#pragma unroll
    for (int mi = 0; mi < 2; mi++)
#pragma unroll
      for (int nt = 0; nt < 4; nt++) s[mi][nt] = mfma16(qa[mi], kf[nt], z);
#pragma unroll
    for (int mi = 0; mi < 2; mi++)
#pragma unroll
      for (int i = 0; i < 4; i++){
        float p0 = exp2f(s[mi][0][i]);
        float p1 = exp2f(s[mi][1][i]);
        float p2 = exp2f(s[mi][2][i]);
        float p3 = exp2f(s[mi][3][i]);
        lsum[mi][i] += (p0 + p1) + (p2 + p3);
        int prow = mi*16 + g*4 + i;
        // logical key nt*16+ln -> phys slot ln*4+nt: one aligned b64 store
        unsigned lo = ((unsigned)f2bf(p1) << 16) | f2bf(p0);
        unsigned hi = ((unsigned)f2bf(p3) << 16) | f2bf(p2);
        uint2 pk; pk.x = lo; pk.y = hi;
        *(uint2*)&Ps[w][prow][ln*4] = pk;
      }
#pragma unroll
    for (int k2 = 0; k2 < 2; k2++){
      bf16x8 va[2];
#pragma unroll
      for (int d2 = 0; d2 < 2; d2++) va[d2] = *(const bf16x8*)&Vs[d2*16 + ln][k2*32 + g*8];
#pragma unroll
      for (int mi = 0; mi < 2; mi++){
        bf16x8 pf = *(const bf16x8*)&Ps[w][mi*16 + ln][k2*32 + g*8];
#pragma unroll
        for (int d2 = 0; d2 < 2; d2++) oacc[mi][d2] = mfma16(pf, va[d2], oacc[mi][d2]);
      }
    }
    __syncthreads();
  }
#pragma unroll
  for (int mi = 0; mi < 2; mi++)
#pragma unroll
    for (int i = 0; i < 4; i++){
#pragma unroll
      for (int mk = 8; mk; mk >>= 1) lsum[mi][i] += __shfl_xor(lsum[mi][i], mk);
      lsum[mi][i] = 1.f / lsum[mi][i];
    }
#pragma unroll
  for (int mi = 0; mi < 2; mi++)
#pragma unroll
  for (int d2 = 0; d2 < 2; d2++)
#pragma unroll
  for (int i = 0; i < 4; i++){
    float v = oacc[mi][d2][i] * lsum[mi][i];
    int row = q0 + mi*16 + g*4 + i;
    ob[(size_t)(b*1024 + row)*CC + h*32 + d2*16 + ln] = f2bf(v);
  }
}

extern "C" void kernel_launch(void* const* d_in, const int* in_sizes, int n_in,
                              void* d_out, int out_size, void* d_ws, size_t ws_size,
                              hipStream_t stream)
{
  (void)in_sizes; (void)n_in; (void)out_size; (void)ws_size;
  const float* x     = (const float*)d_in[0];
  const float* ln1g  = (const float*)d_in[1];
  const float* ln1b  = (const float*)d_in[2];
  const float* Wq    = (const float*)d_in[3];
  const float* bq    = (const float*)d_in[4];
  const float* offk  = (const float*)d_in[5];
  const float* offkb = (const float*)d_in[6];
  const float* offg  = (const float*)d_in[7];
  const float* offb  = (const float*)d_in[8];
  const float* Woff  = (const float*)d_in[9];
  const float* boff  = (const float*)d_in[10];
  const float* Wk    = (const float*)d_in[11];
  const float* bk    = (const float*)d_in[12];
  const float* Wv    = (const float*)d_in[13];
  const float* bv    = (const float*)d_in[14];
  const float* Wo    = (const float*)d_in[15];
  const float* bo    = (const float*)d_in[16];
  const float* ln2g  = (const float*)d_in[17];
  const float* ln2b  = (const float*)d_in[18];
  const float* W1    = (const float*)d_in[19];
  const float* b1    = (const float*)d_in[20];
  const float* W2    = (const float*)d_in[21];
  const float* b2    = (const float*)d_in[22];

  char* ws = (char*)d_ws;
  // layout (bytes):
  //   [0, 25165824)          X2 fp32
  //   [25165824, 37748736)   XSB bf16      -+
  //   [37748736, 50331648)   KB bf16        |  reused as HB (50331648 B) in MLP
  //   [50331648, 62914560)   VT bf16        |
  //   [62914560, 75497472)   OB bf16       -+
  //   [75497472, 88080384)   XNB bf16
  //   [88080384, 100663296)  QSB bf16 -> reused as YB after attn
  //   [100663296, 104202240) weights bf16
  float* X2 = (float*)ws;
  unsigned short* XSB = (unsigned short*)(ws + 25165824);
  unsigned short* KB  = (unsigned short*)(ws + 37748736);
  unsigned short* VT  = (unsigned short*)(ws + 50331648);
  unsigned short* OB  = (unsigned short*)(ws + 62914560);
  unsigned short* XNB = (unsigned short*)(ws + 75497472);
  unsigned short* QSB = (unsigned short*)(ws + 88080384);
  unsigned short* YB  = QSB;
  unsigned short* HB  = (unsigned short*)(ws + 25165824);
  unsigned short* WQB = (unsigned short*)(ws + 100663296);
  unsigned short* WKB = WQB + 147456;
  unsigned short* WVB = WKB + 147456;
  unsigned short* WOB = WVB + 147456;
  unsigned short* W1B = WOB + 147456;
  unsigned short* W2B = W1B + 589824;

  k_cvt_all<<<6912, 256, 0, stream>>>(Wq, Wk, Wv, Wo, W1, W2, WQB);
  k_ln<<<16384, 64, 0, stream>>>(x, ln1g, ln1b, nullptr, XNB);
  k_gemm128<5><<<dim3(3,128), 256, 0, stream>>>(XNB, WQB, bq, nullptr, nullptr, QSB, 384, 384);
  k_offset_sample<<<16384, 128, 0, stream>>>(QSB, XNB, offk, offkb, offg, offb, Woff, boff, XSB);
  k_gemm128<1><<<dim3(3,128), 256, 0, stream>>>(XSB, WKB, bk, nullptr, nullptr, KB, 384, 384);
  k_gemm128<4><<<dim3(3,128), 256, 0, stream>>>(XSB, WVB, bv, nullptr, nullptr, VT, 384, 384);
  k_attn<<<1536, 256, 0, stream>>>(QSB, KB, VT, OB);
  k_gemm128<2><<<dim3(3,128), 256, 0, stream>>>(OB, WOB, bo, x, X2, nullptr, 384, 384);
  k_ln<<<16384, 64, 0, stream>>>(X2, ln2g, ln2b, nullptr, YB);
  k_gemm128<3><<<dim3(12,128), 256, 0, stream>>>(YB, W1B, b1, nullptr, nullptr, HB, 1536, 384);
  k_gemm128<2><<<dim3(3,128), 256, 0, stream>>>(HB, W2B, b2, X2, (float*)d_out, nullptr, 384, 1536);
}

// Round 5
// 296.993 us; speedup vs baseline: 1.0703x; 1.0703x over previous
//
#include <hip/hip_runtime.h>
#include <math.h>

#define DI __device__ __forceinline__

typedef __attribute__((ext_vector_type(8))) short bf16x8;
typedef __attribute__((ext_vector_type(4))) float f32x4;

static constexpr int CC = 384;
// attn scale * log2(e): scores come out of QK^T already in log2 domain
static constexpr float QSCALE = 0.17677669529663687f * 1.4426950408889634f;
static constexpr float INVQS  = 1.0f / QSCALE;

DI unsigned short f2bf(float f){
  unsigned u = __float_as_uint(f);
  u += 0x7FFFu + ((u >> 16) & 1u);
  return (unsigned short)(u >> 16);
}
DI float bf2f(unsigned short u){ return __uint_as_float((unsigned)u << 16); }
DI float gelu_t(float x){
  return 0.5f * x * (1.f + tanhf(0.79788456080286536f * (x + 0.044715f * x * x * x)));
}
DI f32x4 mfma16(bf16x8 a, bf16x8 b, f32x4 c){
  return __builtin_amdgcn_mfma_f32_16x16x32_bf16(a, b, c, 0, 0, 0);
}
DI void gload16(const unsigned short* g, unsigned short* l){
  __builtin_amdgcn_global_load_lds(
      (const __attribute__((address_space(1))) unsigned int*)(const void*)g,
      (__attribute__((address_space(3))) unsigned int*)(void*)l, 16, 0, 0);
}

// ---------------- weight fp32 -> bf16 (six matmul weights, contiguous dst) -------
__global__ __launch_bounds__(256) void k_cvt_all(
    const float* __restrict__ wq, const float* __restrict__ wk,
    const float* __restrict__ wv, const float* __restrict__ wo,
    const float* __restrict__ w1, const float* __restrict__ w2,
    unsigned short* __restrict__ dst)
{
  int i = blockIdx.x*256 + threadIdx.x;
  if (i >= 1769472) return;
  const float* src; int off;
  if (i < 147456){ src = wq; off = i; }
  else if (i < 294912){ src = wk; off = i - 147456; }
  else if (i < 442368){ src = wv; off = i - 294912; }
  else if (i < 589824){ src = wo; off = i - 442368; }
  else if (i < 1179648){ src = w1; off = i - 589824; }
  else { src = w2; off = i - 1179648; }
  dst[i] = f2bf(src[off]);
}

// ---------------- LayerNorm over C=384, one wave per row, 4 rows/block ----------
__global__ __launch_bounds__(256) void k_ln(const float* __restrict__ x,
    const float* __restrict__ g, const float* __restrict__ b,
    float* __restrict__ outf, unsigned short* __restrict__ outb)
{
  int row = blockIdx.x*4 + (threadIdx.x >> 6);
  int l = threadIdx.x & 63;
  const float* xp = x + (size_t)row * CC;
  float v[6]; float s = 0.f, s2 = 0.f;
#pragma unroll
  for (int p = 0; p < 6; p++){ float t = xp[l + 64*p]; v[p] = t; s += t; s2 += t*t; }
#pragma unroll
  for (int m = 32; m; m >>= 1){ s += __shfl_xor(s, m); s2 += __shfl_xor(s2, m); }
  float mu = s * (1.f/CC);
  float var = s2 * (1.f/CC) - mu*mu;
  float rs = rsqrtf(var + 1e-5f);
#pragma unroll
  for (int p = 0; p < 6; p++){
    int c = l + 64*p;
    float o = (v[p] - mu) * rs * g[c] + b[c];
    if (outf) outf[(size_t)row*CC + c] = o;
    if (outb) outb[(size_t)row*CC + c] = f2bf(o);
  }
}

// ---------------- 128x128 GEMM, BK=64, global_load_lds + XOR swizzle -------------
// out(M,N) = A(M,K) @ W(N,K)^T + bias
// EPI 0: f32   1: bf16   2: f32 + res   3: bf16 gelu   5: bf16 * QSCALE
// EPI 6: fused K|V (N=768): col<384 -> KB bf16 row-major (stride 384, bias)
//        col>=384 -> VT bf16 transposed+key-permuted (bias2)
template<int EPI>
__global__ __launch_bounds__(256) void k_gemm128(
    const unsigned short* __restrict__ A, const unsigned short* __restrict__ W,
    const float* __restrict__ bias, const float* __restrict__ bias2,
    const float* __restrict__ res,
    float* __restrict__ outf, unsigned short* __restrict__ outb,
    unsigned short* __restrict__ outb2, int N, int K)
{
  __shared__ unsigned short As[8192];   // 128 rows x 64 cols bf16, slot-swizzled
  __shared__ unsigned short Bs[8192];
  int t = threadIdx.x;
  int w = t >> 6, l = t & 63;
  int g = l >> 4, ln = l & 15;
  int wm = w >> 1, wn = w & 1;
  int bm = blockIdx.y * 128, bn = blockIdx.x * 128;
  f32x4 acc[4][4];
#pragma unroll
  for (int i = 0; i < 4; i++)
#pragma unroll
    for (int j = 0; j < 4; j++) acc[i][j] = (f32x4){0.f,0.f,0.f,0.f};
  int srcoff = ((l & 7) ^ (l >> 3)) * 8;
  const unsigned short* Ap[4]; const unsigned short* Wp[4];
#pragma unroll
  for (int j = 0; j < 4; j++){
    int row = j*32 + w*8 + (l >> 3);
    Ap[j] = A + (size_t)(bm + row)*K + srcoff;
    Wp[j] = W + (size_t)(bn + row)*K + srcoff;
  }
  unsigned short* Asl = As + w*512;
  unsigned short* Bsl = Bs + w*512;
  for (int k0 = 0; k0 < K; k0 += 64){
#pragma unroll
    for (int j = 0; j < 4; j++) gload16(Ap[j] + k0, Asl + j*2048);
#pragma unroll
    for (int j = 0; j < 4; j++) gload16(Wp[j] + k0, Bsl + j*2048);
    __syncthreads();
#pragma unroll
    for (int kk = 0; kk < 2; kk++){
      bf16x8 af[4], bf[4];
#pragma unroll
      for (int mi = 0; mi < 4; mi++){
        int row = wm*64 + mi*16 + ln;
        int sl = (kk*4 + g) ^ (ln & 7);
        af[mi] = *(const bf16x8*)((const char*)As + row*128 + sl*16);
      }
#pragma unroll
      for (int ni = 0; ni < 4; ni++){
        int row = wn*64 + ni*16 + ln;
        int sl = (kk*4 + g) ^ (ln & 7);
        bf[ni] = *(const bf16x8*)((const char*)Bs + row*128 + sl*16);
      }
#pragma unroll
      for (int mi = 0; mi < 4; mi++)
#pragma unroll
        for (int ni = 0; ni < 4; ni++)
          acc[mi][ni] = mfma16(af[mi], bf[ni], acc[mi][ni]);
    }
    __syncthreads();
  }
#pragma unroll
  for (int mi = 0; mi < 4; mi++)
#pragma unroll
  for (int ni = 0; ni < 4; ni++){
    int col = bn + wn*64 + ni*16 + ln;
    float bv;
    if constexpr (EPI == 6) bv = col < 384 ? bias[col] : bias2[col - 384];
    else bv = bias[col];
#pragma unroll
    for (int i = 0; i < 4; i++){
      int row = bm + wm*64 + mi*16 + g*4 + i;
      float v = acc[mi][ni][i] + bv;
      if constexpr (EPI == 2) v += res[(size_t)row*N + col];
      if constexpr (EPI == 3) v = gelu_t(v);
      if constexpr (EPI == 0 || EPI == 2) outf[(size_t)row*N + col] = v;
      if constexpr (EPI == 1 || EPI == 3) outb[(size_t)row*N + col] = f2bf(v);
      if constexpr (EPI == 5) outb[(size_t)row*N + col] = f2bf(v * QSCALE);
      if constexpr (EPI == 6){
        if (col < 384){
          outb[(size_t)row*384 + col] = f2bf(v);
        } else {
          int c = col - 384;
          int bb = row >> 10, key = row & 1023, h = c >> 5, d = c & 31;
          int k6 = key & 63;
          int phys = (key & ~63) | ((k6 & 15) << 2) | (k6 >> 4);
          outb2[(size_t)(((bb*12 + h) << 5) + d)*1024 + phys] = f2bf(v);
        }
      }
    }
  }
}

// ---------------- fused offset net + grid sample (bf16 inputs) -------------------
__global__ __launch_bounds__(128) void k_offset_sample(
    const unsigned short* __restrict__ qs, const unsigned short* __restrict__ xnb,
    const float* __restrict__ offk, const float* __restrict__ offkb,
    const float* __restrict__ offg, const float* __restrict__ offb,
    const float* __restrict__ Woff, const float* __restrict__ boff,
    unsigned short* __restrict__ xsb)
{
  int blk = blockIdx.x;
  int pix = (blk & 7)*2048 + (blk >> 3);   // each XCD gets 2 contiguous images
  int b = pix >> 10, n = pix & 1023;
  int y = n >> 5, x = n & 31;
  int t = threadIdx.x;
  int w = t >> 6;
  const unsigned short* qb = qs + (size_t)b*1024*CC;
  int toff[25]; bool tval[25];
#pragma unroll
  for (int tap = 0; tap < 25; tap++){
    int ky = tap/5, kx = tap - ky*5;
    int yy = y + ky - 2, xx = x + kx - 2;
    tval[tap] = (yy >= 0) & (yy < 32) & (xx >= 0) & (xx < 32);
    int yc = yy < 0 ? 0 : (yy > 31 ? 31 : yy);
    int xc = xx < 0 ? 0 : (xx > 31 ? 31 : xx);
    toff[tap] = (yc*32 + xc)*CC;
  }
  float conv[3];
#pragma unroll
  for (int cc = 0; cc < 3; cc++){
    int c = t + cc*128;
    float qv[25], wv[25];
#pragma unroll
    for (int tap = 0; tap < 25; tap++){
      qv[tap] = bf2f(qb[toff[tap] + c]);
      wv[tap] = offk[tap*CC + c];
    }
    float acc = 0.f;
#pragma unroll
    for (int tap = 0; tap < 25; tap++)
      acc = fmaf(tval[tap] ? qv[tap] : 0.f, wv[tap], acc);
    conv[cc] = acc * INVQS + offkb[c];   // undo QSCALE on the dot, then bias
  }
  __shared__ float rb[2][2];
  float s = conv[0]+conv[1]+conv[2];
  float s2 = conv[0]*conv[0]+conv[1]*conv[1]+conv[2]*conv[2];
#pragma unroll
  for (int m = 32; m; m >>= 1){ s += __shfl_xor(s, m); s2 += __shfl_xor(s2, m); }
  if ((t & 63) == 0){ rb[w][0] = s; rb[w][1] = s2; }
  __syncthreads();
  s = rb[0][0] + rb[1][0]; s2 = rb[0][1] + rb[1][1];
  float mu = s * (1.f/CC);
  float var = s2 * (1.f/CC) - mu*mu;
  float rs = rsqrtf(var + 1e-5f);
  __syncthreads();
  float p0 = 0.f, p1 = 0.f;
#pragma unroll
  for (int cc = 0; cc < 3; cc++){
    int c = t + cc*128;
    float v = (conv[cc] - mu) * rs * offg[c] + offb[c];
    v = gelu_t(v);
    p0 += v * Woff[c];
    p1 += v * Woff[CC + c];
  }
#pragma unroll
  for (int m = 32; m; m >>= 1){ p0 += __shfl_xor(p0, m); p1 += __shfl_xor(p1, m); }
  if ((t & 63) == 0){ rb[w][0] = p0; rb[w][1] = p1; }
  __syncthreads();
  p0 = rb[0][0] + rb[1][0]; p1 = rb[0][1] + rb[1][1];
  float offy = tanhf(p0 + boff[0]) * 0.125f;
  float offx = tanhf(p1 + boff[1]) * 0.125f;
  float py = ((y + 0.5f)/16.f - 1.f + offy + 1.f) * 0.5f * 31.f;
  float px = ((x + 0.5f)/16.f - 1.f + offx + 1.f) * 0.5f * 31.f;
  float y0f = floorf(py), x0f = floorf(px);
  float wy = py - y0f, wx = px - x0f;
  int y0 = (int)y0f, x0 = (int)x0f;
  y0 = y0 < 0 ? 0 : (y0 > 31 ? 31 : y0);
  x0 = x0 < 0 ? 0 : (x0 > 31 ? 31 : x0);
  int y1 = y0 + 1 > 31 ? 31 : y0 + 1;
  int x1 = x0 + 1 > 31 ? 31 : x0 + 1;
  size_t i00 = (size_t)(b*1024 + y0*32 + x0)*CC;
  size_t i01 = (size_t)(b*1024 + y0*32 + x1)*CC;
  size_t i10 = (size_t)(b*1024 + y1*32 + x0)*CC;
  size_t i11 = (size_t)(b*1024 + y1*32 + x1)*CC;
  float w00 = (1.f-wy)*(1.f-wx), w01 = (1.f-wy)*wx, w10 = wy*(1.f-wx), w11 = wy*wx;
#pragma unroll
  for (int cc = 0; cc < 3; cc++){
    int c = t + cc*128;
    float r = bf2f(xnb[i00+c])*w00 + bf2f(xnb[i01+c])*w01
            + bf2f(xnb[i10+c])*w10 + bf2f(xnb[i11+c])*w11;
    xsb[(size_t)(b*1024 + n)*CC + c] = f2bf(r);
  }
}

// ---------------- attention: base-2 no-max softmax, raw v_exp, perm-packed P -----
// qs: bf16 Q scaled by QSCALE; kb row-major; vt: V^T [b][h][d][1024] key-permuted
// (within each 64-key block, phys slot p holds logical key (p&3)*16 + (p>>2))
__global__ __launch_bounds__(256) void k_attn(
    const unsigned short* __restrict__ qs, const unsigned short* __restrict__ kb,
    const unsigned short* __restrict__ vt, unsigned short* __restrict__ ob)
{
  __shared__ unsigned short Ks[64][40];   // [key][dim]
  __shared__ unsigned short Vs[32][72];   // [dim][physkey]
  __shared__ unsigned short Ps[4][32][72];// [qrow][physkey]
  int blk = blockIdx.x;
  int sw = (blk & 7)*192 + (blk >> 3);    // XCD-grouped
  int qt = sw & 7, h = (sw >> 3) % 12, b = sw / 96;
  int t = threadIdx.x;
  int w = t >> 6, l = t & 63;
  int g = l >> 4, ln = l & 15;
  int q0 = qt*128 + w*32;
  bf16x8 qa[2];
#pragma unroll
  for (int mi = 0; mi < 2; mi++)
    qa[mi] = *(const bf16x8*)&qs[(size_t)(b*1024 + q0 + mi*16 + ln)*CC + h*32 + g*8];
  f32x4 z = {0.f,0.f,0.f,0.f};
  f32x4 oacc[2][2]; oacc[0][0]=z; oacc[0][1]=z; oacc[1][0]=z; oacc[1][1]=z;
  float lsum[2][4] = {{0.f,0.f,0.f,0.f},{0.f,0.f,0.f,0.f}};
  const unsigned short* vbase = vt + (size_t)((b*12 + h)*32)*1024;
  const unsigned short* kbase = kb + (size_t)(b*1024)*CC + h*32;

  for (int kt = 0; kt < 16; kt++){
    int k0 = kt*64;
    *(uint4*)&Ks[t>>2][(t&3)*8] = *(const uint4*)(kbase + (size_t)(k0 + (t>>2))*CC + (t&3)*8);
    *(uint4*)&Vs[t>>3][(t&7)*8] = *(const uint4*)(vbase + (size_t)(t>>3)*1024 + k0 + (t&7)*8);
    __syncthreads();
    bf16x8 kf[4];
#pragma unroll
    for (int nt = 0; nt < 4; nt++) kf[nt] = *(const bf16x8*)&Ks[nt*16 + ln][g*8];
    f32x4 s[2][4];
#pragma unroll
    for (int mi = 0; mi < 2; mi++)
#pragma unroll
      for (int nt = 0; nt < 4; nt++) s[mi][nt] = mfma16(qa[mi], kf[nt], z);
#pragma unroll
    for (int mi = 0; mi < 2; mi++)
#pragma unroll
      for (int i = 0; i < 4; i++){
        float p0 = __builtin_amdgcn_exp2f(s[mi][0][i]);
        float p1 = __builtin_amdgcn_exp2f(s[mi][1][i]);
        float p2 = __builtin_amdgcn_exp2f(s[mi][2][i]);
        float p3 = __builtin_amdgcn_exp2f(s[mi][3][i]);
        lsum[mi][i] += (p0 + p1) + (p2 + p3);
        int prow = mi*16 + g*4 + i;
        // logical key nt*16+ln -> phys slot ln*4+nt; truncation-pack hi16 pairs
        uint2 pk;
        pk.x = __builtin_amdgcn_perm(__float_as_uint(p1), __float_as_uint(p0), 0x07060302u);
        pk.y = __builtin_amdgcn_perm(__float_as_uint(p3), __float_as_uint(p2), 0x07060302u);
        *(uint2*)&Ps[w][prow][ln*4] = pk;
      }
#pragma unroll
    for (int k2 = 0; k2 < 2; k2++){
      bf16x8 va[2];
#pragma unroll
      for (int d2 = 0; d2 < 2; d2++) va[d2] = *(const bf16x8*)&Vs[d2*16 + ln][k2*32 + g*8];
#pragma unroll
      for (int mi = 0; mi < 2; mi++){
        bf16x8 pf = *(const bf16x8*)&Ps[w][mi*16 + ln][k2*32 + g*8];
#pragma unroll
        for (int d2 = 0; d2 < 2; d2++) oacc[mi][d2] = mfma16(pf, va[d2], oacc[mi][d2]);
      }
    }
    __syncthreads();
  }
#pragma unroll
  for (int mi = 0; mi < 2; mi++)
#pragma unroll
    for (int i = 0; i < 4; i++){
#pragma unroll
      for (int mk = 8; mk; mk >>= 1) lsum[mi][i] += __shfl_xor(lsum[mi][i], mk);
      lsum[mi][i] = 1.f / lsum[mi][i];
    }
#pragma unroll
  for (int mi = 0; mi < 2; mi++)
#pragma unroll
  for (int d2 = 0; d2 < 2; d2++)
#pragma unroll
  for (int i = 0; i < 4; i++){
    float v = oacc[mi][d2][i] * lsum[mi][i];
    int row = q0 + mi*16 + g*4 + i;
    ob[(size_t)(b*1024 + row)*CC + h*32 + d2*16 + ln] = f2bf(v);
  }
}

extern "C" void kernel_launch(void* const* d_in, const int* in_sizes, int n_in,
                              void* d_out, int out_size, void* d_ws, size_t ws_size,
                              hipStream_t stream)
{
  (void)in_sizes; (void)n_in; (void)out_size; (void)ws_size;
  const float* x     = (const float*)d_in[0];
  const float* ln1g  = (const float*)d_in[1];
  const float* ln1b  = (const float*)d_in[2];
  const float* Wq    = (const float*)d_in[3];
  const float* bq    = (const float*)d_in[4];
  const float* offk  = (const float*)d_in[5];
  const float* offkb = (const float*)d_in[6];
  const float* offg  = (const float*)d_in[7];
  const float* offb  = (const float*)d_in[8];
  const float* Woff  = (const float*)d_in[9];
  const float* boff  = (const float*)d_in[10];
  const float* Wk    = (const float*)d_in[11];
  const float* bk    = (const float*)d_in[12];
  const float* Wv    = (const float*)d_in[13];
  const float* bv    = (const float*)d_in[14];
  const float* Wo    = (const float*)d_in[15];
  const float* bo    = (const float*)d_in[16];
  const float* ln2g  = (const float*)d_in[17];
  const float* ln2b  = (const float*)d_in[18];
  const float* W1    = (const float*)d_in[19];
  const float* b1    = (const float*)d_in[20];
  const float* W2    = (const float*)d_in[21];
  const float* b2    = (const float*)d_in[22];

  char* ws = (char*)d_ws;
  // layout (bytes):
  //   [0, 25165824)          X2 fp32
  //   [25165824, 37748736)   XSB bf16      -+
  //   [37748736, 50331648)   KB bf16        |  reused as HB (50331648 B) in MLP
  //   [50331648, 62914560)   VT bf16        |
  //   [62914560, 75497472)   OB bf16       -+
  //   [75497472, 88080384)   XNB bf16
  //   [88080384, 100663296)  QSB bf16 -> reused as YB after attn
  //   [100663296, 104202240) weights bf16
  float* X2 = (float*)ws;
  unsigned short* XSB = (unsigned short*)(ws + 25165824);
  unsigned short* KB  = (unsigned short*)(ws + 37748736);
  unsigned short* VT  = (unsigned short*)(ws + 50331648);
  unsigned short* OB  = (unsigned short*)(ws + 62914560);
  unsigned short* XNB = (unsigned short*)(ws + 75497472);
  unsigned short* QSB = (unsigned short*)(ws + 88080384);
  unsigned short* YB  = QSB;
  unsigned short* HB  = (unsigned short*)(ws + 25165824);
  unsigned short* WQB = (unsigned short*)(ws + 100663296);
  unsigned short* WKB = WQB + 147456;   // Wk rows 0-383, Wv rows 384-767 (contiguous)
  unsigned short* WOB = WKB + 294912;
  unsigned short* W1B = WOB + 147456;
  unsigned short* W2B = W1B + 589824;

  k_cvt_all<<<6912, 256, 0, stream>>>(Wq, Wk, Wv, Wo, W1, W2, WQB);
  k_ln<<<4096, 256, 0, stream>>>(x, ln1g, ln1b, nullptr, XNB);
  k_gemm128<5><<<dim3(3,128), 256, 0, stream>>>(XNB, WQB, bq, nullptr, nullptr, nullptr, QSB, nullptr, 384, 384);
  k_offset_sample<<<16384, 128, 0, stream>>>(QSB, XNB, offk, offkb, offg, offb, Woff, boff, XSB);
  k_gemm128<6><<<dim3(6,128), 256, 0, stream>>>(XSB, WKB, bk, bv, nullptr, nullptr, KB, VT, 768, 384);
  k_attn<<<1536, 256, 0, stream>>>(QSB, KB, VT, OB);
  k_gemm128<2><<<dim3(3,128), 256, 0, stream>>>(OB, WOB, bo, nullptr, x, X2, nullptr, nullptr, 384, 384);
  k_ln<<<4096, 256, 0, stream>>>(X2, ln2g, ln2b, nullptr, YB);
  k_gemm128<3><<<dim3(12,128), 256, 0, stream>>>(YB, W1B, b1, nullptr, nullptr, nullptr, HB, nullptr, 1536, 384);
  k_gemm128<2><<<dim3(3,128), 256, 0, stream>>>(HB, W2B, b2, nullptr, X2, (float*)d_out, nullptr, nullptr, 384, 1536);
}

// Round 6
// 274.839 us; speedup vs baseline: 1.1566x; 1.0806x over previous
//
#include <hip/hip_runtime.h>
#include <math.h>

#define DI __device__ __forceinline__

typedef __attribute__((ext_vector_type(8))) short bf16x8;
typedef __attribute__((ext_vector_type(4))) float f32x4;

static constexpr int CC = 384;
// attn scale * log2(e): scores come out of QK^T already in log2 domain
static constexpr float QSCALE = 0.17677669529663687f * 1.4426950408889634f;
static constexpr float INVQS  = 1.0f / QSCALE;

DI unsigned short f2bf(float f){
  unsigned u = __float_as_uint(f);
  u += 0x7FFFu + ((u >> 16) & 1u);
  return (unsigned short)(u >> 16);
}
DI float bf2f(unsigned short u){ return __uint_as_float((unsigned)u << 16); }
DI float lo16(unsigned u){ return __uint_as_float(u << 16); }
DI float hi16(unsigned u){ return __uint_as_float(u & 0xFFFF0000u); }
DI float fexp2(float x){ return __builtin_amdgcn_exp2f(x); }
DI float frcp(float x){ return __builtin_amdgcn_rcpf(x); }
// tanh(z) = 1 - 2/(exp2(z*2*log2e)+1)
DI float tanh_fast(float z){ return 1.f - 2.f*frcp(fexp2(2.8853900817779268f*z) + 1.f); }
DI float gelu_fast(float v){
  float u = v*v;
  float z = 0.7978845608028654f * fmaf(0.044715f*u, v, v);
  return v - v*frcp(fexp2(2.8853900817779268f*z) + 1.f);
}
DI f32x4 mfma16(bf16x8 a, bf16x8 b, f32x4 c){
  return __builtin_amdgcn_mfma_f32_16x16x32_bf16(a, b, c, 0, 0, 0);
}
DI void gload16(const unsigned short* g, unsigned short* l){
  __builtin_amdgcn_global_load_lds(
      (const __attribute__((address_space(1))) unsigned int*)(const void*)g,
      (__attribute__((address_space(3))) unsigned int*)(void*)l, 16, 0, 0);
}

// ---------------- weight fp32 -> bf16, vectorized x4 ----------------------------
__global__ __launch_bounds__(256) void k_cvt_all(
    const float* __restrict__ wq, const float* __restrict__ wk,
    const float* __restrict__ wv, const float* __restrict__ wo,
    const float* __restrict__ w1, const float* __restrict__ w2,
    unsigned short* __restrict__ dst)
{
  int i4 = (blockIdx.x*256 + threadIdx.x)*4;
  if (i4 >= 1769472) return;
  const float* src; int off;
  if (i4 < 147456){ src = wq; off = i4; }
  else if (i4 < 294912){ src = wk; off = i4 - 147456; }
  else if (i4 < 442368){ src = wv; off = i4 - 294912; }
  else if (i4 < 589824){ src = wo; off = i4 - 442368; }
  else if (i4 < 1179648){ src = w1; off = i4 - 589824; }
  else { src = w2; off = i4 - 1179648; }
  float4 v = *(const float4*)(src + off);
  uint2 o;
  o.x = ((unsigned)f2bf(v.y) << 16) | f2bf(v.x);
  o.y = ((unsigned)f2bf(v.w) << 16) | f2bf(v.z);
  *(uint2*)(dst + i4) = o;
}

// ---------------- LayerNorm over C=384, one wave per row, 4 rows/block ----------
__global__ __launch_bounds__(256) void k_ln(const float* __restrict__ x,
    const float* __restrict__ g, const float* __restrict__ b,
    float* __restrict__ outf, unsigned short* __restrict__ outb)
{
  int row = blockIdx.x*4 + (threadIdx.x >> 6);
  int l = threadIdx.x & 63;
  const float* xp = x + (size_t)row * CC;
  float v[6]; float s = 0.f, s2 = 0.f;
#pragma unroll
  for (int p = 0; p < 6; p++){ float t = xp[l + 64*p]; v[p] = t; s += t; s2 += t*t; }
#pragma unroll
  for (int m = 32; m; m >>= 1){ s += __shfl_xor(s, m); s2 += __shfl_xor(s2, m); }
  float mu = s * (1.f/CC);
  float var = s2 * (1.f/CC) - mu*mu;
  float rs = rsqrtf(var + 1e-5f);
#pragma unroll
  for (int p = 0; p < 6; p++){
    int c = l + 64*p;
    float o = (v[p] - mu) * rs * g[c] + b[c];
    if (outf) outf[(size_t)row*CC + c] = o;
    if (outb) outb[(size_t)row*CC + c] = f2bf(o);
  }
}

// ---------------- 128x128 GEMM, BK=32, double-buffered LDS + gload_lds -----------
// out(M,N) = A(M,K) @ W(N,K)^T + bias
// EPI 0: f32   1: bf16   2: f32 + res   3: bf16 gelu   5: bf16 * QSCALE
// EPI 6: fused K|V (N=768): col<384 -> KB; col>=384 -> VT transposed+key-permuted
template<int EPI>
__global__ __launch_bounds__(256) void k_gemm128(
    const unsigned short* __restrict__ A, const unsigned short* __restrict__ W,
    const float* __restrict__ bias, const float* __restrict__ bias2,
    const float* __restrict__ res,
    float* __restrict__ outf, unsigned short* __restrict__ outb,
    unsigned short* __restrict__ outb2, int N, int K)
{
  __shared__ unsigned short As[2][4096];   // 128 rows x 32 cols, slot-swizzled
  __shared__ unsigned short Bs[2][4096];
  int t = threadIdx.x;
  int w = t >> 6, l = t & 63;
  int g = l >> 4, ln = l & 15;
  int wm = w >> 1, wn = w & 1;
  int bm = blockIdx.y * 128, bn = blockIdx.x * 128;
  f32x4 acc[4][4];
#pragma unroll
  for (int i = 0; i < 4; i++)
#pragma unroll
    for (int j = 0; j < 4; j++) acc[i][j] = (f32x4){0.f,0.f,0.f,0.f};
  int srow0 = t >> 2, slot = t & 3;
  int srow1 = srow0 + 64;
  int cb0 = (slot ^ (srow0 & 3) ^ ((srow0 >> 2) & 3)) * 8;
  int cb1 = (slot ^ (srow1 & 3) ^ ((srow1 >> 2) & 3)) * 8;
  const unsigned short* Ap0 = A + (size_t)(bm + srow0)*K + cb0;
  const unsigned short* Ap1 = A + (size_t)(bm + srow1)*K + cb1;
  const unsigned short* Wp0 = W + (size_t)(bn + srow0)*K + cb0;
  const unsigned short* Wp1 = W + (size_t)(bn + srow1)*K + cb1;
  int NT = K >> 5;
  int wl = w*512;
  // prologue: stage tile 0
  gload16(Ap0, &As[0][wl]);
  gload16(Ap1, &As[0][wl + 2048]);
  gload16(Wp0, &Bs[0][wl]);
  gload16(Wp1, &Bs[0][wl + 2048]);
  __syncthreads();
  for (int kt = 0; kt < NT; kt++){
    int cur = kt & 1;
    if (kt + 1 < NT){
      int k0 = (kt + 1) << 5;
      gload16(Ap0 + k0, &As[cur ^ 1][wl]);
      gload16(Ap1 + k0, &As[cur ^ 1][wl + 2048]);
      gload16(Wp0 + k0, &Bs[cur ^ 1][wl]);
      gload16(Wp1 + k0, &Bs[cur ^ 1][wl + 2048]);
    }
    bf16x8 af[4], bf[4];
#pragma unroll
    for (int mi = 0; mi < 4; mi++){
      int row = wm*64 + mi*16 + ln;
      int sl = g ^ (row & 3) ^ ((row >> 2) & 3);
      af[mi] = *(const bf16x8*)((const char*)As[cur] + row*64 + sl*16);
    }
#pragma unroll
    for (int ni = 0; ni < 4; ni++){
      int row = wn*64 + ni*16 + ln;
      int sl = g ^ (row & 3) ^ ((row >> 2) & 3);
      bf[ni] = *(const bf16x8*)((const char*)Bs[cur] + row*64 + sl*16);
    }
#pragma unroll
    for (int mi = 0; mi < 4; mi++)
#pragma unroll
      for (int ni = 0; ni < 4; ni++)
        acc[mi][ni] = mfma16(af[mi], bf[ni], acc[mi][ni]);
    if (kt + 1 < NT) __syncthreads();
  }
#pragma unroll
  for (int mi = 0; mi < 4; mi++)
#pragma unroll
  for (int ni = 0; ni < 4; ni++){
    int col = bn + wn*64 + ni*16 + ln;
    float bv;
    if constexpr (EPI == 6) bv = col < 384 ? bias[col] : bias2[col - 384];
    else bv = bias[col];
#pragma unroll
    for (int i = 0; i < 4; i++){
      int row = bm + wm*64 + mi*16 + g*4 + i;
      float v = acc[mi][ni][i] + bv;
      if constexpr (EPI == 2) v += res[(size_t)row*N + col];
      if constexpr (EPI == 3) v = gelu_fast(v);
      if constexpr (EPI == 0 || EPI == 2) outf[(size_t)row*N + col] = v;
      if constexpr (EPI == 1 || EPI == 3) outb[(size_t)row*N + col] = f2bf(v);
      if constexpr (EPI == 5) outb[(size_t)row*N + col] = f2bf(v * QSCALE);
      if constexpr (EPI == 6){
        if (col < 384){
          outb[(size_t)row*384 + col] = f2bf(v);
        } else {
          int c = col - 384;
          int bb = row >> 10, key = row & 1023, h = c >> 5, d = c & 31;
          int k6 = key & 63;
          int phys = (key & ~63) | ((k6 & 15) << 2) | (k6 >> 4);
          outb2[(size_t)(((bb*12 + h) << 5) + d)*1024 + phys] = f2bf(v);
        }
      }
    }
  }
}

// ---------------- fused offset net + grid sample: one WAVE per pixel -------------
// 64 threads, 6 channels each (4 via uint2 + 2 via uint), pure-shuffle reductions
__global__ __launch_bounds__(64) void k_offset_sample(
    const unsigned short* __restrict__ qs, const unsigned short* __restrict__ xnb,
    const float* __restrict__ offk, const float* __restrict__ offkb,
    const float* __restrict__ offg, const float* __restrict__ offb,
    const float* __restrict__ Woff, const float* __restrict__ boff,
    unsigned short* __restrict__ xsb)
{
  int blk = blockIdx.x;
  int pix = (blk & 7)*2048 + (blk >> 3);   // each XCD gets 2 contiguous images
  int b = pix >> 10, n = pix & 1023;
  int y = n >> 5, x = n & 31;
  int t = threadIdx.x;
  int cA = 4*t, cB = 256 + 2*t;
  const unsigned short* qb = qs + (size_t)b*1024*CC;
  int ry[5], rx[5]; unsigned my[5], mx[5];
#pragma unroll
  for (int k = 0; k < 5; k++){
    int yy = y + k - 2, xx = x + k - 2;
    my[k] = (yy >= 0 && yy < 32) ? 0xFFFFFFFFu : 0u;
    mx[k] = (xx >= 0 && xx < 32) ? 0xFFFFFFFFu : 0u;
    int yc = yy < 0 ? 0 : (yy > 31 ? 31 : yy);
    int xc = xx < 0 ? 0 : (xx > 31 ? 31 : xx);
    ry[k] = yc*32*CC; rx[k] = xc*CC;
  }
  float a0=0.f,a1=0.f,a2=0.f,a3=0.f,b0a=0.f,b1a=0.f;
#pragma unroll
  for (int ky = 0; ky < 5; ky++)
#pragma unroll
  for (int kx = 0; kx < 5; kx++){
    int tap = ky*5 + kx;
    unsigned m = my[ky] & mx[kx];
    const unsigned short* p = qb + (ry[ky] + rx[kx]);
    uint2 u2 = *(const uint2*)(p + cA);
    unsigned u1 = *(const unsigned*)(p + cB);
    float4 w4 = *(const float4*)(offk + tap*CC + cA);
    float2 w2 = *(const float2*)(offk + tap*CC + cB);
    u2.x &= m; u2.y &= m; u1 &= m;
    a0 = fmaf(lo16(u2.x), w4.x, a0); a1 = fmaf(hi16(u2.x), w4.y, a1);
    a2 = fmaf(lo16(u2.y), w4.z, a2); a3 = fmaf(hi16(u2.y), w4.w, a3);
    b0a = fmaf(lo16(u1), w2.x, b0a); b1a = fmaf(hi16(u1), w2.y, b1a);
  }
  float4 kb4 = *(const float4*)(offkb + cA);
  float2 kb2 = *(const float2*)(offkb + cB);
  float c0 = fmaf(a0, INVQS, kb4.x), c1 = fmaf(a1, INVQS, kb4.y);
  float c2 = fmaf(a2, INVQS, kb4.z), c3 = fmaf(a3, INVQS, kb4.w);
  float c4 = fmaf(b0a, INVQS, kb2.x), c5 = fmaf(b1a, INVQS, kb2.y);
  float s  = ((c0+c1)+(c2+c3))+(c4+c5);
  float s2 = ((c0*c0+c1*c1)+(c2*c2+c3*c3))+(c4*c4+c5*c5);
#pragma unroll
  for (int m2 = 32; m2; m2 >>= 1){ s += __shfl_xor(s, m2); s2 += __shfl_xor(s2, m2); }
  float mu = s * (1.f/CC);
  float var = s2 * (1.f/CC) - mu*mu;
  float rs = rsqrtf(var + 1e-5f);
  float4 g4 = *(const float4*)(offg + cA); float2 g2 = *(const float2*)(offg + cB);
  float4 o4 = *(const float4*)(offb + cA); float2 o2 = *(const float2*)(offb + cB);
  float4 wA = *(const float4*)(Woff + cA); float2 wB = *(const float2*)(Woff + cB);
  float4 wC = *(const float4*)(Woff + CC + cA); float2 wD = *(const float2*)(Woff + CC + cB);
  float v0 = gelu_fast((c0 - mu)*rs*g4.x + o4.x);
  float v1 = gelu_fast((c1 - mu)*rs*g4.y + o4.y);
  float v2 = gelu_fast((c2 - mu)*rs*g4.z + o4.z);
  float v3 = gelu_fast((c3 - mu)*rs*g4.w + o4.w);
  float v4 = gelu_fast((c4 - mu)*rs*g2.x + o2.x);
  float v5 = gelu_fast((c5 - mu)*rs*g2.y + o2.y);
  float p0 = ((v0*wA.x + v1*wA.y) + (v2*wA.z + v3*wA.w)) + (v4*wB.x + v5*wB.y);
  float p1 = ((v0*wC.x + v1*wC.y) + (v2*wC.z + v3*wC.w)) + (v4*wD.x + v5*wD.y);
#pragma unroll
  for (int m2 = 32; m2; m2 >>= 1){ p0 += __shfl_xor(p0, m2); p1 += __shfl_xor(p1, m2); }
  float offy = tanh_fast(p0 + boff[0]) * 0.125f;
  float offx = tanh_fast(p1 + boff[1]) * 0.125f;
  float py = ((y + 0.5f)/16.f - 1.f + offy + 1.f) * 0.5f * 31.f;
  float px = ((x + 0.5f)/16.f - 1.f + offx + 1.f) * 0.5f * 31.f;
  float y0f = floorf(py), x0f = floorf(px);
  float wy = py - y0f, wx = px - x0f;
  int y0 = (int)y0f, x0 = (int)x0f;
  y0 = y0 < 0 ? 0 : (y0 > 31 ? 31 : y0);
  x0 = x0 < 0 ? 0 : (x0 > 31 ? 31 : x0);
  int y1 = y0 + 1 > 31 ? 31 : y0 + 1;
  int x1 = x0 + 1 > 31 ? 31 : x0 + 1;
  const unsigned short* s00 = xnb + (size_t)(b*1024 + y0*32 + x0)*CC;
  const unsigned short* s01 = xnb + (size_t)(b*1024 + y0*32 + x1)*CC;
  const unsigned short* s10 = xnb + (size_t)(b*1024 + y1*32 + x0)*CC;
  const unsigned short* s11 = xnb + (size_t)(b*1024 + y1*32 + x1)*CC;
  float w00 = (1.f-wy)*(1.f-wx), w01 = (1.f-wy)*wx, w10 = wy*(1.f-wx), w11 = wy*wx;
  uint2 A00 = *(const uint2*)(s00 + cA); unsigned B00 = *(const unsigned*)(s00 + cB);
  uint2 A01 = *(const uint2*)(s01 + cA); unsigned B01 = *(const unsigned*)(s01 + cB);
  uint2 A10 = *(const uint2*)(s10 + cA); unsigned B10 = *(const unsigned*)(s10 + cB);
  uint2 A11 = *(const uint2*)(s11 + cA); unsigned B11 = *(const unsigned*)(s11 + cB);
  float r0 = ((w00*lo16(A00.x) + w01*lo16(A01.x)) + (w10*lo16(A10.x) + w11*lo16(A11.x)));
  float r1 = ((w00*hi16(A00.x) + w01*hi16(A01.x)) + (w10*hi16(A10.x) + w11*hi16(A11.x)));
  float r2 = ((w00*lo16(A00.y) + w01*lo16(A01.y)) + (w10*lo16(A10.y) + w11*lo16(A11.y)));
  float r3 = ((w00*hi16(A00.y) + w01*hi16(A01.y)) + (w10*hi16(A10.y) + w11*hi16(A11.y)));
  float r4 = ((w00*lo16(B00) + w01*lo16(B01)) + (w10*lo16(B10) + w11*lo16(B11)));
  float r5 = ((w00*hi16(B00) + w01*hi16(B01)) + (w10*hi16(B10) + w11*hi16(B11)));
  unsigned short* outp = xsb + (size_t)(b*1024 + n)*CC;
  uint2 st;
  st.x = ((unsigned)f2bf(r1) << 16) | f2bf(r0);
  st.y = ((unsigned)f2bf(r3) << 16) | f2bf(r2);
  *(uint2*)(outp + cA) = st;
  *(unsigned*)(outp + cB) = ((unsigned)f2bf(r5) << 16) | f2bf(r4);
}

// ---------------- attention: base-2 no-max softmax, raw v_exp, perm-packed P -----
__global__ __launch_bounds__(256) void k_attn(
    const unsigned short* __restrict__ qs, const unsigned short* __restrict__ kb,
    const unsigned short* __restrict__ vt, unsigned short* __restrict__ ob)
{
  __shared__ unsigned short Ks[64][40];   // [key][dim]
  __shared__ unsigned short Vs[32][72];   // [dim][physkey]
  __shared__ unsigned short Ps[4][32][72];// [qrow][physkey]
  int blk = blockIdx.x;
  int sw = (blk & 7)*192 + (blk >> 3);    // XCD-grouped
  int qt = sw & 7, h = (sw >> 3) % 12, b = sw / 96;
  int t = threadIdx.x;
  int w = t >> 6, l = t & 63;
  int g = l >> 4, ln = l & 15;
  int q0 = qt*128 + w*32;
  bf16x8 qa[2];
#pragma unroll
  for (int mi = 0; mi < 2; mi++)
    qa[mi] = *(const bf16x8*)&qs[(size_t)(b*1024 + q0 + mi*16 + ln)*CC + h*32 + g*8];
  f32x4 z = {0.f,0.f,0.f,0.f};
  f32x4 oacc[2][2]; oacc[0][0]=z; oacc[0][1]=z; oacc[1][0]=z; oacc[1][1]=z;
  float lsum[2][4] = {{0.f,0.f,0.f,0.f},{0.f,0.f,0.f,0.f}};
  const unsigned short* vbase = vt + (size_t)((b*12 + h)*32)*1024;
  const unsigned short* kbase = kb + (size_t)(b*1024)*CC + h*32;

  for (int kt = 0; kt < 16; kt++){
    int k0 = kt*64;
    *(uint4*)&Ks[t>>2][(t&3)*8] = *(const uint4*)(kbase + (size_t)(k0 + (t>>2))*CC + (t&3)*8);
    *(uint4*)&Vs[t>>3][(t&7)*8] = *(const uint4*)(vbase + (size_t)(t>>3)*1024 + k0 + (t&7)*8);
    __syncthreads();
    bf16x8 kf[4];
#pragma unroll
    for (int nt = 0; nt < 4; nt++) kf[nt] = *(const bf16x8*)&Ks[nt*16 + ln][g*8];
    f32x4 s[2][4];
#pragma unroll
    for (int mi = 0; mi < 2; mi++)
#pragma unroll
      for (int nt = 0; nt < 4; nt++) s[mi][nt] = mfma16(qa[mi], kf[nt], z);
#pragma unroll
    for (int mi = 0; mi < 2; mi++)
#pragma unroll
      for (int i = 0; i < 4; i++){
        float p0 = fexp2(s[mi][0][i]);
        float p1 = fexp2(s[mi][1][i]);
        float p2 = fexp2(s[mi][2][i]);
        float p3 = fexp2(s[mi][3][i]);
        lsum[mi][i] += (p0 + p1) + (p2 + p3);
        int prow = mi*16 + g*4 + i;
        uint2 pk;
        pk.x = __builtin_amdgcn_perm(__float_as_uint(p1), __float_as_uint(p0), 0x07060302u);
        pk.y = __builtin_amdgcn_perm(__float_as_uint(p3), __float_as_uint(p2), 0x07060302u);
        *(uint2*)&Ps[w][prow][ln*4] = pk;
      }
#pragma unroll
    for (int k2 = 0; k2 < 2; k2++){
      bf16x8 va[2];
#pragma unroll
      for (int d2 = 0; d2 < 2; d2++) va[d2] = *(const bf16x8*)&Vs[d2*16 + ln][k2*32 + g*8];
#pragma unroll
      for (int mi = 0; mi < 2; mi++){
        bf16x8 pf = *(const bf16x8*)&Ps[w][mi*16 + ln][k2*32 + g*8];
#pragma unroll
        for (int d2 = 0; d2 < 2; d2++) oacc[mi][d2] = mfma16(pf, va[d2], oacc[mi][d2]);
      }
    }
    __syncthreads();
  }
#pragma unroll
  for (int mi = 0; mi < 2; mi++)
#pragma unroll
    for (int i = 0; i < 4; i++){
#pragma unroll
      for (int mk = 8; mk; mk >>= 1) lsum[mi][i] += __shfl_xor(lsum[mi][i], mk);
      lsum[mi][i] = 1.f / lsum[mi][i];
    }
#pragma unroll
  for (int mi = 0; mi < 2; mi++)
#pragma unroll
  for (int d2 = 0; d2 < 2; d2++)
#pragma unroll
  for (int i = 0; i < 4; i++){
    float v = oacc[mi][d2][i] * lsum[mi][i];
    int row = q0 + mi*16 + g*4 + i;
    ob[(size_t)(b*1024 + row)*CC + h*32 + d2*16 + ln] = f2bf(v);
  }
}

extern "C" void kernel_launch(void* const* d_in, const int* in_sizes, int n_in,
                              void* d_out, int out_size, void* d_ws, size_t ws_size,
                              hipStream_t stream)
{
  (void)in_sizes; (void)n_in; (void)out_size; (void)ws_size;
  const float* x     = (const float*)d_in[0];
  const float* ln1g  = (const float*)d_in[1];
  const float* ln1b  = (const float*)d_in[2];
  const float* Wq    = (const float*)d_in[3];
  const float* bq    = (const float*)d_in[4];
  const float* offk  = (const float*)d_in[5];
  const float* offkb = (const float*)d_in[6];
  const float* offg  = (const float*)d_in[7];
  const float* offb  = (const float*)d_in[8];
  const float* Woff  = (const float*)d_in[9];
  const float* boff  = (const float*)d_in[10];
  const float* Wk    = (const float*)d_in[11];
  const float* bk    = (const float*)d_in[12];
  const float* Wv    = (const float*)d_in[13];
  const float* bv    = (const float*)d_in[14];
  const float* Wo    = (const float*)d_in[15];
  const float* bo    = (const float*)d_in[16];
  const float* ln2g  = (const float*)d_in[17];
  const float* ln2b  = (const float*)d_in[18];
  const float* W1    = (const float*)d_in[19];
  const float* b1    = (const float*)d_in[20];
  const float* W2    = (const float*)d_in[21];
  const float* b2    = (const float*)d_in[22];

  char* ws = (char*)d_ws;
  float* X2 = (float*)ws;
  unsigned short* XSB = (unsigned short*)(ws + 25165824);
  unsigned short* KB  = (unsigned short*)(ws + 37748736);
  unsigned short* VT  = (unsigned short*)(ws + 50331648);
  unsigned short* OB  = (unsigned short*)(ws + 62914560);
  unsigned short* XNB = (unsigned short*)(ws + 75497472);
  unsigned short* QSB = (unsigned short*)(ws + 88080384);
  unsigned short* YB  = QSB;
  unsigned short* HB  = (unsigned short*)(ws + 25165824);
  unsigned short* WQB = (unsigned short*)(ws + 100663296);
  unsigned short* WKB = WQB + 147456;   // Wk rows 0-383, Wv rows 384-767 (contiguous)
  unsigned short* WOB = WKB + 294912;
  unsigned short* W1B = WOB + 147456;
  unsigned short* W2B = W1B + 589824;

  k_cvt_all<<<1728, 256, 0, stream>>>(Wq, Wk, Wv, Wo, W1, W2, WQB);
  k_ln<<<4096, 256, 0, stream>>>(x, ln1g, ln1b, nullptr, XNB);
  k_gemm128<5><<<dim3(3,128), 256, 0, stream>>>(XNB, WQB, bq, nullptr, nullptr, nullptr, QSB, nullptr, 384, 384);
  k_offset_sample<<<16384, 64, 0, stream>>>(QSB, XNB, offk, offkb, offg, offb, Woff, boff, XSB);
  k_gemm128<6><<<dim3(6,128), 256, 0, stream>>>(XSB, WKB, bk, bv, nullptr, nullptr, KB, VT, 768, 384);
  k_attn<<<1536, 256, 0, stream>>>(QSB, KB, VT, OB);
  k_gemm128<2><<<dim3(3,128), 256, 0, stream>>>(OB, WOB, bo, nullptr, x, X2, nullptr, nullptr, 384, 384);
  k_ln<<<4096, 256, 0, stream>>>(X2, ln2g, ln2b, nullptr, YB);
  k_gemm128<3><<<dim3(12,128), 256, 0, stream>>>(YB, W1B, b1, nullptr, nullptr, nullptr, HB, nullptr, 1536, 384);
  k_gemm128<2><<<dim3(3,128), 256, 0, stream>>>(HB, W2B, b2, nullptr, X2, (float*)d_out, nullptr, nullptr, 384, 1536);
}

// Round 7
// 260.589 us; speedup vs baseline: 1.2199x; 1.0547x over previous
//
#include <hip/hip_runtime.h>
#include <math.h>

#define DI __device__ __forceinline__

typedef __attribute__((ext_vector_type(8))) short bf16x8;
typedef __attribute__((ext_vector_type(4))) float f32x4;

static constexpr int CC = 384;
// attn scale * log2(e): scores come out of QK^T already in log2 domain
static constexpr float QSCALE = 0.17677669529663687f * 1.4426950408889634f;
static constexpr float INVQS  = 1.0f / QSCALE;

DI unsigned short f2bf(float f){
  unsigned u = __float_as_uint(f);
  u += 0x7FFFu + ((u >> 16) & 1u);
  return (unsigned short)(u >> 16);
}
DI float bf2f(unsigned short u){ return __uint_as_float((unsigned)u << 16); }
DI float lo16(unsigned u){ return __uint_as_float(u << 16); }
DI float hi16(unsigned u){ return __uint_as_float(u & 0xFFFF0000u); }
DI float fexp2(float x){ return __builtin_amdgcn_exp2f(x); }
DI float frcp(float x){ return __builtin_amdgcn_rcpf(x); }
// tanh(z) = 1 - 2/(exp2(z*2*log2e)+1)
DI float tanh_fast(float z){ return 1.f - 2.f*frcp(fexp2(2.8853900817779268f*z) + 1.f); }
DI float gelu_fast(float v){
  float u = v*v;
  float z = 0.7978845608028654f * fmaf(0.044715f*u, v, v);
  return v - v*frcp(fexp2(2.8853900817779268f*z) + 1.f);
}
DI f32x4 mfma16(bf16x8 a, bf16x8 b, f32x4 c){
  return __builtin_amdgcn_mfma_f32_16x16x32_bf16(a, b, c, 0, 0, 0);
}
DI void gload16(const unsigned short* g, unsigned short* l){
  __builtin_amdgcn_global_load_lds(
      (const __attribute__((address_space(1))) unsigned int*)(const void*)g,
      (__attribute__((address_space(3))) unsigned int*)(void*)l, 16, 0, 0);
}

// ---------------- weight fp32 -> bf16, vectorized x4 ----------------------------
__global__ __launch_bounds__(256) void k_cvt_all(
    const float* __restrict__ wq, const float* __restrict__ wk,
    const float* __restrict__ wv, const float* __restrict__ wo,
    const float* __restrict__ w1, const float* __restrict__ w2,
    unsigned short* __restrict__ dst)
{
  int i4 = (blockIdx.x*256 + threadIdx.x)*4;
  if (i4 >= 1769472) return;
  const float* src; int off;
  if (i4 < 147456){ src = wq; off = i4; }
  else if (i4 < 294912){ src = wk; off = i4 - 147456; }
  else if (i4 < 442368){ src = wv; off = i4 - 294912; }
  else if (i4 < 589824){ src = wo; off = i4 - 442368; }
  else if (i4 < 1179648){ src = w1; off = i4 - 589824; }
  else { src = w2; off = i4 - 1179648; }
  float4 v = *(const float4*)(src + off);
  uint2 o;
  o.x = ((unsigned)f2bf(v.y) << 16) | f2bf(v.x);
  o.y = ((unsigned)f2bf(v.w) << 16) | f2bf(v.z);
  *(uint2*)(dst + i4) = o;
}

// ---------------- LayerNorm over C=384, one wave/row, 4 rows/block --------------
// BIN=0: f32 input (scalar loads)   BIN=1: bf16 input (vectorized 6 ch/lane)
template<int BIN>
__global__ __launch_bounds__(256) void k_ln(const float* __restrict__ xf,
    const unsigned short* __restrict__ xb,
    const float* __restrict__ g, const float* __restrict__ b,
    unsigned short* __restrict__ outb)
{
  int row = blockIdx.x*4 + (threadIdx.x >> 6);
  int l = threadIdx.x & 63;
  float v[6]; int ch[6];
  if constexpr (BIN){
    int cA = 4*l, cB = 256 + 2*l;
    ch[0]=cA; ch[1]=cA+1; ch[2]=cA+2; ch[3]=cA+3; ch[4]=cB; ch[5]=cB+1;
    const unsigned short* xp = xb + (size_t)row * CC;
    uint2 u2 = *(const uint2*)(xp + cA);
    unsigned u1 = *(const unsigned*)(xp + cB);
    v[0]=lo16(u2.x); v[1]=hi16(u2.x); v[2]=lo16(u2.y); v[3]=hi16(u2.y);
    v[4]=lo16(u1);   v[5]=hi16(u1);
  } else {
    const float* xp = xf + (size_t)row * CC;
#pragma unroll
    for (int p = 0; p < 6; p++){ ch[p] = l + 64*p; v[p] = xp[ch[p]]; }
  }
  float s = 0.f, s2 = 0.f;
#pragma unroll
  for (int p = 0; p < 6; p++){ s += v[p]; s2 += v[p]*v[p]; }
#pragma unroll
  for (int m = 32; m; m >>= 1){ s += __shfl_xor(s, m); s2 += __shfl_xor(s2, m); }
  float mu = s * (1.f/CC);
  float var = s2 * (1.f/CC) - mu*mu;
  float rs = rsqrtf(var + 1e-5f);
  float o[6];
#pragma unroll
  for (int p = 0; p < 6; p++) o[p] = (v[p] - mu) * rs * g[ch[p]] + b[ch[p]];
  unsigned short* op = outb + (size_t)row*CC;
  if constexpr (BIN){
    uint2 st;
    st.x = ((unsigned)f2bf(o[1]) << 16) | f2bf(o[0]);
    st.y = ((unsigned)f2bf(o[3]) << 16) | f2bf(o[2]);
    *(uint2*)(op + ch[0]) = st;
    *(unsigned*)(op + ch[4]) = ((unsigned)f2bf(o[5]) << 16) | f2bf(o[4]);
  } else {
#pragma unroll
    for (int p = 0; p < 6; p++) op[ch[p]] = f2bf(o[p]);
  }
}

// ---------------- 128x128 GEMM, BK=32, double-buffered LDS + gload_lds -----------
// out(M,N) = A(M,K) @ W(N,K)^T + bias
// EPI 0: f32   1: bf16   3: bf16 gelu   5: bf16 * QSCALE
// EPI 2: + f32 res -> bf16 out          7: + bf16 res -> f32 out
// EPI 6: fused K|V (N=768): col<384 -> KB; col>=384 -> VT transposed+key-permuted
template<int EPI>
__global__ __launch_bounds__(256) void k_gemm128(
    const unsigned short* __restrict__ A, const unsigned short* __restrict__ W,
    const float* __restrict__ bias, const float* __restrict__ bias2,
    const float* __restrict__ res, const unsigned short* __restrict__ resb,
    float* __restrict__ outf, unsigned short* __restrict__ outb,
    unsigned short* __restrict__ outb2, int N, int K)
{
  __shared__ unsigned short As[2][4096];   // 128 rows x 32 cols, slot-swizzled
  __shared__ unsigned short Bs[2][4096];
  int t = threadIdx.x;
  int w = t >> 6, l = t & 63;
  int g = l >> 4, ln = l & 15;
  int wm = w >> 1, wn = w & 1;
  int bm = blockIdx.y * 128, bn = blockIdx.x * 128;
  f32x4 acc[4][4];
#pragma unroll
  for (int i = 0; i < 4; i++)
#pragma unroll
    for (int j = 0; j < 4; j++) acc[i][j] = (f32x4){0.f,0.f,0.f,0.f};
  int srow0 = t >> 2, slot = t & 3;
  int srow1 = srow0 + 64;
  int cb0 = (slot ^ (srow0 & 3) ^ ((srow0 >> 2) & 3)) * 8;
  int cb1 = (slot ^ (srow1 & 3) ^ ((srow1 >> 2) & 3)) * 8;
  const unsigned short* Ap0 = A + (size_t)(bm + srow0)*K + cb0;
  const unsigned short* Ap1 = A + (size_t)(bm + srow1)*K + cb1;
  const unsigned short* Wp0 = W + (size_t)(bn + srow0)*K + cb0;
  const unsigned short* Wp1 = W + (size_t)(bn + srow1)*K + cb1;
  int NT = K >> 5;
  int wl = w*512;
  gload16(Ap0, &As[0][wl]);
  gload16(Ap1, &As[0][wl + 2048]);
  gload16(Wp0, &Bs[0][wl]);
  gload16(Wp1, &Bs[0][wl + 2048]);
  __syncthreads();
  for (int kt = 0; kt < NT; kt++){
    int cur = kt & 1;
    if (kt + 1 < NT){
      int k0 = (kt + 1) << 5;
      gload16(Ap0 + k0, &As[cur ^ 1][wl]);
      gload16(Ap1 + k0, &As[cur ^ 1][wl + 2048]);
      gload16(Wp0 + k0, &Bs[cur ^ 1][wl]);
      gload16(Wp1 + k0, &Bs[cur ^ 1][wl + 2048]);
    }
    bf16x8 af[4], bf[4];
#pragma unroll
    for (int mi = 0; mi < 4; mi++){
      int row = wm*64 + mi*16 + ln;
      int sl = g ^ (row & 3) ^ ((row >> 2) & 3);
      af[mi] = *(const bf16x8*)((const char*)As[cur] + row*64 + sl*16);
    }
#pragma unroll
    for (int ni = 0; ni < 4; ni++){
      int row = wn*64 + ni*16 + ln;
      int sl = g ^ (row & 3) ^ ((row >> 2) & 3);
      bf[ni] = *(const bf16x8*)((const char*)Bs[cur] + row*64 + sl*16);
    }
#pragma unroll
    for (int mi = 0; mi < 4; mi++)
#pragma unroll
      for (int ni = 0; ni < 4; ni++)
        acc[mi][ni] = mfma16(af[mi], bf[ni], acc[mi][ni]);
    if (kt + 1 < NT) __syncthreads();
  }
#pragma unroll
  for (int mi = 0; mi < 4; mi++)
#pragma unroll
  for (int ni = 0; ni < 4; ni++){
    int col = bn + wn*64 + ni*16 + ln;
    float bv;
    if constexpr (EPI == 6) bv = col < 384 ? bias[col] : bias2[col - 384];
    else bv = bias[col];
#pragma unroll
    for (int i = 0; i < 4; i++){
      int row = bm + wm*64 + mi*16 + g*4 + i;
      float v = acc[mi][ni][i] + bv;
      if constexpr (EPI == 2){ v += res[(size_t)row*N + col]; outb[(size_t)row*N + col] = f2bf(v); }
      if constexpr (EPI == 7){ v += bf2f(resb[(size_t)row*N + col]); outf[(size_t)row*N + col] = v; }
      if constexpr (EPI == 3) v = gelu_fast(v);
      if constexpr (EPI == 0) outf[(size_t)row*N + col] = v;
      if constexpr (EPI == 1 || EPI == 3) outb[(size_t)row*N + col] = f2bf(v);
      if constexpr (EPI == 5) outb[(size_t)row*N + col] = f2bf(v * QSCALE);
      if constexpr (EPI == 6){
        if (col < 384){
          outb[(size_t)row*384 + col] = f2bf(v);
        } else {
          int c = col - 384;
          int bb = row >> 10, key = row & 1023, h = c >> 5, d = c & 31;
          int k6 = key & 63;
          int phys = (key & ~63) | ((k6 & 15) << 2) | (k6 >> 4);
          outb2[(size_t)(((bb*12 + h) << 5) + d)*1024 + phys] = f2bf(v);
        }
      }
    }
  }
}

// ---------------- fused offset net + grid sample: one WAVE per pixel -------------
__global__ __launch_bounds__(64) void k_offset_sample(
    const unsigned short* __restrict__ qs, const unsigned short* __restrict__ xnb,
    const float* __restrict__ offk, const float* __restrict__ offkb,
    const float* __restrict__ offg, const float* __restrict__ offb,
    const float* __restrict__ Woff, const float* __restrict__ boff,
    unsigned short* __restrict__ xsb)
{
  int blk = blockIdx.x;
  int pix = (blk & 7)*2048 + (blk >> 3);   // each XCD gets 2 contiguous images
  int b = pix >> 10, n = pix & 1023;
  int y = n >> 5, x = n & 31;
  int t = threadIdx.x;
  int cA = 4*t, cB = 256 + 2*t;
  const unsigned short* qb = qs + (size_t)b*1024*CC;
  int ry[5], rx[5]; unsigned my[5], mx[5];
#pragma unroll
  for (int k = 0; k < 5; k++){
    int yy = y + k - 2, xx = x + k - 2;
    my[k] = (yy >= 0 && yy < 32) ? 0xFFFFFFFFu : 0u;
    mx[k] = (xx >= 0 && xx < 32) ? 0xFFFFFFFFu : 0u;
    int yc = yy < 0 ? 0 : (yy > 31 ? 31 : yy);
    int xc = xx < 0 ? 0 : (xx > 31 ? 31 : xx);
    ry[k] = yc*32*CC; rx[k] = xc*CC;
  }
  float a0=0.f,a1=0.f,a2=0.f,a3=0.f,b0a=0.f,b1a=0.f;
#pragma unroll
  for (int ky = 0; ky < 5; ky++)
#pragma unroll
  for (int kx = 0; kx < 5; kx++){
    int tap = ky*5 + kx;
    unsigned m = my[ky] & mx[kx];
    const unsigned short* p = qb + (ry[ky] + rx[kx]);
    uint2 u2 = *(const uint2*)(p + cA);
    unsigned u1 = *(const unsigned*)(p + cB);
    float4 w4 = *(const float4*)(offk + tap*CC + cA);
    float2 w2 = *(const float2*)(offk + tap*CC + cB);
    u2.x &= m; u2.y &= m; u1 &= m;
    a0 = fmaf(lo16(u2.x), w4.x, a0); a1 = fmaf(hi16(u2.x), w4.y, a1);
    a2 = fmaf(lo16(u2.y), w4.z, a2); a3 = fmaf(hi16(u2.y), w4.w, a3);
    b0a = fmaf(lo16(u1), w2.x, b0a); b1a = fmaf(hi16(u1), w2.y, b1a);
  }
  float4 kb4 = *(const float4*)(offkb + cA);
  float2 kb2 = *(const float2*)(offkb + cB);
  float c0 = fmaf(a0, INVQS, kb4.x), c1 = fmaf(a1, INVQS, kb4.y);
  float c2 = fmaf(a2, INVQS, kb4.z), c3 = fmaf(a3, INVQS, kb4.w);
  float c4 = fmaf(b0a, INVQS, kb2.x), c5 = fmaf(b1a, INVQS, kb2.y);
  float s  = ((c0+c1)+(c2+c3))+(c4+c5);
  float s2 = ((c0*c0+c1*c1)+(c2*c2+c3*c3))+(c4*c4+c5*c5);
#pragma unroll
  for (int m2 = 32; m2; m2 >>= 1){ s += __shfl_xor(s, m2); s2 += __shfl_xor(s2, m2); }
  float mu = s * (1.f/CC);
  float var = s2 * (1.f/CC) - mu*mu;
  float rs = rsqrtf(var + 1e-5f);
  float4 g4 = *(const float4*)(offg + cA); float2 g2 = *(const float2*)(offg + cB);
  float4 o4 = *(const float4*)(offb + cA); float2 o2 = *(const float2*)(offb + cB);
  float4 wA = *(const float4*)(Woff + cA); float2 wB = *(const float2*)(Woff + cB);
  float4 wC = *(const float4*)(Woff + CC + cA); float2 wD = *(const float2*)(Woff + CC + cB);
  float v0 = gelu_fast((c0 - mu)*rs*g4.x + o4.x);
  float v1 = gelu_fast((c1 - mu)*rs*g4.y + o4.y);
  float v2 = gelu_fast((c2 - mu)*rs*g4.z + o4.z);
  float v3 = gelu_fast((c3 - mu)*rs*g4.w + o4.w);
  float v4 = gelu_fast((c4 - mu)*rs*g2.x + o2.x);
  float v5 = gelu_fast((c5 - mu)*rs*g2.y + o2.y);
  float p0 = ((v0*wA.x + v1*wA.y) + (v2*wA.z + v3*wA.w)) + (v4*wB.x + v5*wB.y);
  float p1 = ((v0*wC.x + v1*wC.y) + (v2*wC.z + v3*wC.w)) + (v4*wD.x + v5*wD.y);
#pragma unroll
  for (int m2 = 32; m2; m2 >>= 1){ p0 += __shfl_xor(p0, m2); p1 += __shfl_xor(p1, m2); }
  float offy = tanh_fast(p0 + boff[0]) * 0.125f;
  float offx = tanh_fast(p1 + boff[1]) * 0.125f;
  float py = ((y + 0.5f)/16.f - 1.f + offy + 1.f) * 0.5f * 31.f;
  float px = ((x + 0.5f)/16.f - 1.f + offx + 1.f) * 0.5f * 31.f;
  float y0f = floorf(py), x0f = floorf(px);
  float wy = py - y0f, wx = px - x0f;
  int y0 = (int)y0f, x0 = (int)x0f;
  y0 = y0 < 0 ? 0 : (y0 > 31 ? 31 : y0);
  x0 = x0 < 0 ? 0 : (x0 > 31 ? 31 : x0);
  int y1 = y0 + 1 > 31 ? 31 : y0 + 1;
  int x1 = x0 + 1 > 31 ? 31 : x0 + 1;
  const unsigned short* s00 = xnb + (size_t)(b*1024 + y0*32 + x0)*CC;
  const unsigned short* s01 = xnb + (size_t)(b*1024 + y0*32 + x1)*CC;
  const unsigned short* s10 = xnb + (size_t)(b*1024 + y1*32 + x0)*CC;
  const unsigned short* s11 = xnb + (size_t)(b*1024 + y1*32 + x1)*CC;
  float w00 = (1.f-wy)*(1.f-wx), w01 = (1.f-wy)*wx, w10 = wy*(1.f-wx), w11 = wy*wx;
  uint2 A00 = *(const uint2*)(s00 + cA); unsigned B00 = *(const unsigned*)(s00 + cB);
  uint2 A01 = *(const uint2*)(s01 + cA); unsigned B01 = *(const unsigned*)(s01 + cB);
  uint2 A10 = *(const uint2*)(s10 + cA); unsigned B10 = *(const unsigned*)(s10 + cB);
  uint2 A11 = *(const uint2*)(s11 + cA); unsigned B11 = *(const unsigned*)(s11 + cB);
  float r0 = ((w00*lo16(A00.x) + w01*lo16(A01.x)) + (w10*lo16(A10.x) + w11*lo16(A11.x)));
  float r1 = ((w00*hi16(A00.x) + w01*hi16(A01.x)) + (w10*hi16(A10.x) + w11*hi16(A11.x)));
  float r2 = ((w00*lo16(A00.y) + w01*lo16(A01.y)) + (w10*lo16(A10.y) + w11*lo16(A11.y)));
  float r3 = ((w00*hi16(A00.y) + w01*hi16(A01.y)) + (w10*hi16(A10.y) + w11*hi16(A11.y)));
  float r4 = ((w00*lo16(B00) + w01*lo16(B01)) + (w10*lo16(B10) + w11*lo16(B11)));
  float r5 = ((w00*hi16(B00) + w01*hi16(B01)) + (w10*hi16(B10) + w11*hi16(B11)));
  unsigned short* outp = xsb + (size_t)(b*1024 + n)*CC;
  uint2 st;
  st.x = ((unsigned)f2bf(r1) << 16) | f2bf(r0);
  st.y = ((unsigned)f2bf(r3) << 16) | f2bf(r2);
  *(uint2*)(outp + cA) = st;
  *(unsigned*)(outp + cB) = ((unsigned)f2bf(r5) << 16) | f2bf(r4);
}

// ---------------- attention: dbuf K/V + async-stage split, base-2 softmax --------
// qs: bf16 Q scaled by QSCALE; kb row-major; vt: V^T [b][h][d][1024] key-permuted
__global__ __launch_bounds__(256) void k_attn(
    const unsigned short* __restrict__ qs, const unsigned short* __restrict__ kb,
    const unsigned short* __restrict__ vt, unsigned short* __restrict__ ob)
{
  __shared__ unsigned short Ks[2][64][40];   // [buf][key][dim]
  __shared__ unsigned short Vs[2][32][72];   // [buf][dim][physkey]
  __shared__ unsigned short Ps[4][32][72];   // [wave][qrow][physkey]
  int blk = blockIdx.x;
  int sw = (blk & 7)*192 + (blk >> 3);    // XCD-grouped
  int qt = sw & 7, h = (sw >> 3) % 12, b = sw / 96;
  int t = threadIdx.x;
  int w = t >> 6, l = t & 63;
  int g = l >> 4, ln = l & 15;
  int q0 = qt*128 + w*32;
  bf16x8 qa[2];
#pragma unroll
  for (int mi = 0; mi < 2; mi++)
    qa[mi] = *(const bf16x8*)&qs[(size_t)(b*1024 + q0 + mi*16 + ln)*CC + h*32 + g*8];
  f32x4 z = {0.f,0.f,0.f,0.f};
  f32x4 oacc[2][2]; oacc[0][0]=z; oacc[0][1]=z; oacc[1][0]=z; oacc[1][1]=z;
  float lsum[2][4] = {{0.f,0.f,0.f,0.f},{0.f,0.f,0.f,0.f}};
  // staging addresses (per thread: one uint4 of K, one uint4 of V)
  int krow = t >> 2, kc = (t & 3)*8;
  int vdim = t >> 3, vc = (t & 7)*8;
  const unsigned short* kptr = kb + (size_t)(b*1024 + krow)*CC + h*32 + kc;
  const unsigned short* vptr = vt + (size_t)((b*12 + h)*32 + vdim)*1024 + vc;
  {
    uint4 kr = *(const uint4*)kptr;
    uint4 vr = *(const uint4*)vptr;
    *(uint4*)&Ks[0][krow][kc] = kr;
    *(uint4*)&Vs[0][vdim][vc] = vr;
  }
  __syncthreads();
  for (int kt = 0; kt < 16; kt++){
    int cur = kt & 1;
    uint4 kr2, vr2;
    if (kt < 15){
      int k0 = (kt + 1)*64;
      kr2 = *(const uint4*)(kptr + (size_t)k0*CC);
      vr2 = *(const uint4*)(vptr + k0);
    }
    bf16x8 kf[4];
#pragma unroll
    for (int nt = 0; nt < 4; nt++) kf[nt] = *(const bf16x8*)&Ks[cur][nt*16 + ln][g*8];
    f32x4 s[2][4];
    __builtin_amdgcn_s_setprio(1);
#pragma unroll
    for (int mi = 0; mi < 2; mi++)
#pragma unroll
      for (int nt = 0; nt < 4; nt++) s[mi][nt] = mfma16(qa[mi], kf[nt], z);
    __builtin_amdgcn_s_setprio(0);
#pragma unroll
    for (int mi = 0; mi < 2; mi++)
#pragma unroll
      for (int i = 0; i < 4; i++){
        float p0 = fexp2(s[mi][0][i]);
        float p1 = fexp2(s[mi][1][i]);
        float p2 = fexp2(s[mi][2][i]);
        float p3 = fexp2(s[mi][3][i]);
        lsum[mi][i] += (p0 + p1) + (p2 + p3);
        int prow = mi*16 + g*4 + i;
        uint2 pk;
        pk.x = __builtin_amdgcn_perm(__float_as_uint(p1), __float_as_uint(p0), 0x07060302u);
        pk.y = __builtin_amdgcn_perm(__float_as_uint(p3), __float_as_uint(p2), 0x07060302u);
        *(uint2*)&Ps[w][prow][ln*4] = pk;
      }
    __builtin_amdgcn_s_setprio(1);
#pragma unroll
    for (int k2 = 0; k2 < 2; k2++){
      bf16x8 va[2];
#pragma unroll
      for (int d2 = 0; d2 < 2; d2++) va[d2] = *(const bf16x8*)&Vs[cur][d2*16 + ln][k2*32 + g*8];
#pragma unroll
      for (int mi = 0; mi < 2; mi++){
        bf16x8 pf = *(const bf16x8*)&Ps[w][mi*16 + ln][k2*32 + g*8];
#pragma unroll
        for (int d2 = 0; d2 < 2; d2++) oacc[mi][d2] = mfma16(pf, va[d2], oacc[mi][d2]);
      }
    }
    __builtin_amdgcn_s_setprio(0);
    if (kt < 15){
      *(uint4*)&Ks[cur ^ 1][krow][kc] = kr2;
      *(uint4*)&Vs[cur ^ 1][vdim][vc] = vr2;
      __syncthreads();
    }
  }
#pragma unroll
  for (int mi = 0; mi < 2; mi++)
#pragma unroll
    for (int i = 0; i < 4; i++){
#pragma unroll
      for (int mk = 8; mk; mk >>= 1) lsum[mi][i] += __shfl_xor(lsum[mi][i], mk);
      lsum[mi][i] = 1.f / lsum[mi][i];
    }
#pragma unroll
  for (int mi = 0; mi < 2; mi++)
#pragma unroll
  for (int d2 = 0; d2 < 2; d2++)
#pragma unroll
  for (int i = 0; i < 4; i++){
    float v = oacc[mi][d2][i] * lsum[mi][i];
    int row = q0 + mi*16 + g*4 + i;
    ob[(size_t)(b*1024 + row)*CC + h*32 + d2*16 + ln] = f2bf(v);
  }
}

extern "C" void kernel_launch(void* const* d_in, const int* in_sizes, int n_in,
                              void* d_out, int out_size, void* d_ws, size_t ws_size,
                              hipStream_t stream)
{
  (void)in_sizes; (void)n_in; (void)out_size; (void)ws_size;
  const float* x     = (const float*)d_in[0];
  const float* ln1g  = (const float*)d_in[1];
  const float* ln1b  = (const float*)d_in[2];
  const float* Wq    = (const float*)d_in[3];
  const float* bq    = (const float*)d_in[4];
  const float* offk  = (const float*)d_in[5];
  const float* offkb = (const float*)d_in[6];
  const float* offg  = (const float*)d_in[7];
  const float* offb  = (const float*)d_in[8];
  const float* Woff  = (const float*)d_in[9];
  const float* boff  = (const float*)d_in[10];
  const float* Wk    = (const float*)d_in[11];
  const float* bk    = (const float*)d_in[12];
  const float* Wv    = (const float*)d_in[13];
  const float* bv    = (const float*)d_in[14];
  const float* Wo    = (const float*)d_in[15];
  const float* bo    = (const float*)d_in[16];
  const float* ln2g  = (const float*)d_in[17];
  const float* ln2b  = (const float*)d_in[18];
  const float* W1    = (const float*)d_in[19];
  const float* b1    = (const float*)d_in[20];
  const float* W2    = (const float*)d_in[21];
  const float* b2    = (const float*)d_in[22];

  char* ws = (char*)d_ws;
  // layout (bytes):
  //   [0, 12582912)          X2B bf16 (residual stream after attn)
  //   [25165824, 37748736)   XSB bf16      -+
  //   [37748736, 50331648)   KB bf16        |  reused as HB (50331648 B) in MLP
  //   [50331648, 62914560)   VT bf16        |
  //   [62914560, 75497472)   OB bf16       -+
  //   [75497472, 88080384)   XNB bf16
  //   [88080384, 100663296)  QSB bf16 -> reused as YB after attn
  //   [100663296, 104202240) weights bf16
  unsigned short* X2B = (unsigned short*)ws;
  unsigned short* XSB = (unsigned short*)(ws + 25165824);
  unsigned short* KB  = (unsigned short*)(ws + 37748736);
  unsigned short* VT  = (unsigned short*)(ws + 50331648);
  unsigned short* OB  = (unsigned short*)(ws + 62914560);
  unsigned short* XNB = (unsigned short*)(ws + 75497472);
  unsigned short* QSB = (unsigned short*)(ws + 88080384);
  unsigned short* YB  = QSB;
  unsigned short* HB  = (unsigned short*)(ws + 25165824);
  unsigned short* WQB = (unsigned short*)(ws + 100663296);
  unsigned short* WKB = WQB + 147456;   // Wk rows 0-383, Wv rows 384-767 (contiguous)
  unsigned short* WOB = WKB + 294912;
  unsigned short* W1B = WOB + 147456;
  unsigned short* W2B = W1B + 589824;

  k_cvt_all<<<1728, 256, 0, stream>>>(Wq, Wk, Wv, Wo, W1, W2, WQB);
  k_ln<0><<<4096, 256, 0, stream>>>(x, nullptr, ln1g, ln1b, XNB);
  k_gemm128<5><<<dim3(3,128), 256, 0, stream>>>(XNB, WQB, bq, nullptr, nullptr, nullptr, nullptr, QSB, nullptr, 384, 384);
  k_offset_sample<<<16384, 64, 0, stream>>>(QSB, XNB, offk, offkb, offg, offb, Woff, boff, XSB);
  k_gemm128<6><<<dim3(6,128), 256, 0, stream>>>(XSB, WKB, bk, bv, nullptr, nullptr, nullptr, KB, VT, 768, 384);
  k_attn<<<1536, 256, 0, stream>>>(QSB, KB, VT, OB);
  k_gemm128<2><<<dim3(3,128), 256, 0, stream>>>(OB, WOB, bo, nullptr, x, nullptr, nullptr, X2B, nullptr, 384, 384);
  k_ln<1><<<4096, 256, 0, stream>>>(nullptr, X2B, ln2g, ln2b, YB);
  k_gemm128<3><<<dim3(12,128), 256, 0, stream>>>(YB, W1B, b1, nullptr, nullptr, nullptr, nullptr, HB, nullptr, 1536, 384);
  k_gemm128<7><<<dim3(3,128), 256, 0, stream>>>(HB, W2B, b2, nullptr, nullptr, X2B, (float*)d_out, nullptr, nullptr, 384, 1536);
}

// Round 8
// 245.140 us; speedup vs baseline: 1.2967x; 1.0630x over previous
//
#include <hip/hip_runtime.h>
#include <math.h>

#define DI __device__ __forceinline__

typedef __attribute__((ext_vector_type(8))) short bf16x8;
typedef __attribute__((ext_vector_type(4))) float f32x4;

static constexpr int CC = 384;
// attn scale * log2(e): scores come out of QK^T already in log2 domain
static constexpr float QSCALE = 0.17677669529663687f * 1.4426950408889634f;
static constexpr float INVQS  = 1.0f / QSCALE;

DI unsigned short f2bf(float f){
  unsigned u = __float_as_uint(f);
  u += 0x7FFFu + ((u >> 16) & 1u);
  return (unsigned short)(u >> 16);
}
DI float bf2f(unsigned short u){ return __uint_as_float((unsigned)u << 16); }
DI float lo16(unsigned u){ return __uint_as_float(u << 16); }
DI float hi16(unsigned u){ return __uint_as_float(u & 0xFFFF0000u); }
DI float fexp2(float x){ return __builtin_amdgcn_exp2f(x); }
DI float frcp(float x){ return __builtin_amdgcn_rcpf(x); }
// tanh(z) = 1 - 2/(exp2(z*2*log2e)+1)
DI float tanh_fast(float z){ return 1.f - 2.f*frcp(fexp2(2.8853900817779268f*z) + 1.f); }
DI float gelu_fast(float v){
  float u = v*v;
  float z = 0.7978845608028654f * fmaf(0.044715f*u, v, v);
  return v - v*frcp(fexp2(2.8853900817779268f*z) + 1.f);
}
DI f32x4 mfma16(bf16x8 a, bf16x8 b, f32x4 c){
  return __builtin_amdgcn_mfma_f32_16x16x32_bf16(a, b, c, 0, 0, 0);
}
DI void gload16(const unsigned short* g, unsigned short* l){
  __builtin_amdgcn_global_load_lds(
      (const __attribute__((address_space(1))) unsigned int*)(const void*)g,
      (__attribute__((address_space(3))) unsigned int*)(void*)l, 16, 0, 0);
}

// ---------------- weight fp32 -> bf16 (6 matmul weights + offk), vectorized x4 ---
__global__ __launch_bounds__(256) void k_cvt_all(
    const float* __restrict__ wq, const float* __restrict__ wk,
    const float* __restrict__ wv, const float* __restrict__ wo,
    const float* __restrict__ w1, const float* __restrict__ w2,
    const float* __restrict__ ofk,
    unsigned short* __restrict__ dst)
{
  int i4 = (blockIdx.x*256 + threadIdx.x)*4;
  if (i4 >= 1779072) return;
  const float* src; int off;
  if (i4 < 147456){ src = wq; off = i4; }
  else if (i4 < 294912){ src = wk; off = i4 - 147456; }
  else if (i4 < 442368){ src = wv; off = i4 - 294912; }
  else if (i4 < 589824){ src = wo; off = i4 - 442368; }
  else if (i4 < 1179648){ src = w1; off = i4 - 589824; }
  else if (i4 < 1769472){ src = w2; off = i4 - 1179648; }
  else { src = ofk; off = i4 - 1769472; }
  float4 v = *(const float4*)(src + off);
  uint2 o;
  o.x = ((unsigned)f2bf(v.y) << 16) | f2bf(v.x);
  o.y = ((unsigned)f2bf(v.w) << 16) | f2bf(v.z);
  *(uint2*)(dst + i4) = o;
}

// ---------------- LayerNorm over C=384, one wave/row, 4 rows/block --------------
// BIN=0: f32 input (scalar loads)   BIN=1: bf16 input (vectorized 6 ch/lane)
template<int BIN>
__global__ __launch_bounds__(256) void k_ln(const float* __restrict__ xf,
    const unsigned short* __restrict__ xb,
    const float* __restrict__ g, const float* __restrict__ b,
    unsigned short* __restrict__ outb)
{
  int row = blockIdx.x*4 + (threadIdx.x >> 6);
  int l = threadIdx.x & 63;
  float v[6]; int ch[6];
  if constexpr (BIN){
    int cA = 4*l, cB = 256 + 2*l;
    ch[0]=cA; ch[1]=cA+1; ch[2]=cA+2; ch[3]=cA+3; ch[4]=cB; ch[5]=cB+1;
    const unsigned short* xp = xb + (size_t)row * CC;
    uint2 u2 = *(const uint2*)(xp + cA);
    unsigned u1 = *(const unsigned*)(xp + cB);
    v[0]=lo16(u2.x); v[1]=hi16(u2.x); v[2]=lo16(u2.y); v[3]=hi16(u2.y);
    v[4]=lo16(u1);   v[5]=hi16(u1);
  } else {
    const float* xp = xf + (size_t)row * CC;
#pragma unroll
    for (int p = 0; p < 6; p++){ ch[p] = l + 64*p; v[p] = xp[ch[p]]; }
  }
  float s = 0.f, s2 = 0.f;
#pragma unroll
  for (int p = 0; p < 6; p++){ s += v[p]; s2 += v[p]*v[p]; }
#pragma unroll
  for (int m = 32; m; m >>= 1){ s += __shfl_xor(s, m); s2 += __shfl_xor(s2, m); }
  float mu = s * (1.f/CC);
  float var = s2 * (1.f/CC) - mu*mu;
  float rs = rsqrtf(var + 1e-5f);
  float o[6];
#pragma unroll
  for (int p = 0; p < 6; p++) o[p] = (v[p] - mu) * rs * g[ch[p]] + b[ch[p]];
  unsigned short* op = outb + (size_t)row*CC;
  if constexpr (BIN){
    uint2 st;
    st.x = ((unsigned)f2bf(o[1]) << 16) | f2bf(o[0]);
    st.y = ((unsigned)f2bf(o[3]) << 16) | f2bf(o[2]);
    *(uint2*)(op + ch[0]) = st;
    *(unsigned*)(op + ch[4]) = ((unsigned)f2bf(o[5]) << 16) | f2bf(o[4]);
  } else {
#pragma unroll
    for (int p = 0; p < 6; p++) op[ch[p]] = f2bf(o[p]);
  }
}

// ---------------- 64x128 GEMM, BK=32, dbuf LDS + gload_lds + XCD swizzle ---------
// out(M,N) = A(M,K) @ W(N,K)^T + bias.  1D grid, ntn = N/128 tiles.
// EPI 0: f32   1: bf16   3: bf16 gelu   5: bf16 * QSCALE
// EPI 2: + f32 res -> bf16 out          7: + bf16 res -> f32 out
// EPI 6: fused K|V (N=768): col<384 -> KB; col>=384 -> VT transposed+key-permuted
template<int EPI>
__global__ __launch_bounds__(256) void k_gemm64(
    const unsigned short* __restrict__ A, const unsigned short* __restrict__ W,
    const float* __restrict__ bias, const float* __restrict__ bias2,
    const float* __restrict__ res, const unsigned short* __restrict__ resb,
    float* __restrict__ outf, unsigned short* __restrict__ outb,
    unsigned short* __restrict__ outb2, int ntn, int N, int K)
{
  __shared__ unsigned short As[2][2048];   // 64 rows x 32 cols, slot-swizzled
  __shared__ unsigned short Bs[2][4096];   // 128 rows x 32 cols
  int bid = blockIdx.x;
  int cpx = gridDim.x >> 3;
  int id = (bid & 7)*cpx + (bid >> 3);     // XCD-chunk swizzle
  int bn = (id % ntn) * 128;
  int bm = (id / ntn) * 64;
  int t = threadIdx.x;
  int w = t >> 6, l = t & 63;
  int g = l >> 4, ln = l & 15;
  int wm = w >> 1, wn = w & 1;             // wave: 32 rows x 64 cols
  f32x4 acc[2][4];
#pragma unroll
  for (int i = 0; i < 2; i++)
#pragma unroll
    for (int j = 0; j < 4; j++) acc[i][j] = (f32x4){0.f,0.f,0.f,0.f};
  int srow = t >> 2, slot = t & 3;
  int srowB = srow + 64;
  int cb0 = (slot ^ (srow  & 3) ^ ((srow  >> 2) & 3)) * 8;
  int cb1 = (slot ^ (srowB & 3) ^ ((srowB >> 2) & 3)) * 8;
  const unsigned short* Ap  = A + (size_t)(bm + srow)*K + cb0;
  const unsigned short* Wp0 = W + (size_t)(bn + srow)*K + cb0;
  const unsigned short* Wp1 = W + (size_t)(bn + srowB)*K + cb1;
  int NT = K >> 5;
  int wl = w*512;
  gload16(Ap,  &As[0][wl]);
  gload16(Wp0, &Bs[0][wl]);
  gload16(Wp1, &Bs[0][wl + 2048]);
  __syncthreads();
  for (int kt = 0; kt < NT; kt++){
    int cur = kt & 1;
    if (kt + 1 < NT){
      int k0 = (kt + 1) << 5;
      gload16(Ap  + k0, &As[cur ^ 1][wl]);
      gload16(Wp0 + k0, &Bs[cur ^ 1][wl]);
      gload16(Wp1 + k0, &Bs[cur ^ 1][wl + 2048]);
    }
    bf16x8 af[2], bf[4];
#pragma unroll
    for (int mi = 0; mi < 2; mi++){
      int row = wm*32 + mi*16 + ln;
      int sl = g ^ (row & 3) ^ ((row >> 2) & 3);
      af[mi] = *(const bf16x8*)((const char*)As[cur] + row*64 + sl*16);
    }
#pragma unroll
    for (int ni = 0; ni < 4; ni++){
      int row = wn*64 + ni*16 + ln;
      int sl = g ^ (row & 3) ^ ((row >> 2) & 3);
      bf[ni] = *(const bf16x8*)((const char*)Bs[cur] + row*64 + sl*16);
    }
#pragma unroll
    for (int mi = 0; mi < 2; mi++)
#pragma unroll
      for (int ni = 0; ni < 4; ni++)
        acc[mi][ni] = mfma16(af[mi], bf[ni], acc[mi][ni]);
    if (kt + 1 < NT) __syncthreads();
  }
#pragma unroll
  for (int mi = 0; mi < 2; mi++)
#pragma unroll
  for (int ni = 0; ni < 4; ni++){
    int col = bn + wn*64 + ni*16 + ln;
    float bv;
    if constexpr (EPI == 6) bv = col < 384 ? bias[col] : bias2[col - 384];
    else bv = bias[col];
#pragma unroll
    for (int i = 0; i < 4; i++){
      int row = bm + wm*32 + mi*16 + g*4 + i;
      float v = acc[mi][ni][i] + bv;
      if constexpr (EPI == 2){ v += res[(size_t)row*N + col]; outb[(size_t)row*N + col] = f2bf(v); }
      if constexpr (EPI == 7){ v += bf2f(resb[(size_t)row*N + col]); outf[(size_t)row*N + col] = v; }
      if constexpr (EPI == 3) v = gelu_fast(v);
      if constexpr (EPI == 0) outf[(size_t)row*N + col] = v;
      if constexpr (EPI == 1 || EPI == 3) outb[(size_t)row*N + col] = f2bf(v);
      if constexpr (EPI == 5) outb[(size_t)row*N + col] = f2bf(v * QSCALE);
      if constexpr (EPI == 6){
        if (col < 384){
          outb[(size_t)row*384 + col] = f2bf(v);
        } else {
          int c = col - 384;
          int bb = row >> 10, key = row & 1023, h = c >> 5, d = c & 31;
          int k6 = key & 63;
          int phys = (key & ~63) | ((k6 & 15) << 2) | (k6 >> 4);
          outb2[(size_t)(((bb*12 + h) << 5) + d)*1024 + phys] = f2bf(v);
        }
      }
    }
  }
}

// ---------------- fused offset net + grid sample: one WAVE per pixel -------------
// 8 channels/thread on 48 active lanes; all accesses are 16B uint4
__global__ __launch_bounds__(64) void k_offset_sample(
    const unsigned short* __restrict__ qs, const unsigned short* __restrict__ xnb,
    const unsigned short* __restrict__ okb,  // bf16 offk [25][384]
    const float* __restrict__ offkb,
    const float* __restrict__ offg, const float* __restrict__ offb,
    const float* __restrict__ Woff, const float* __restrict__ boff,
    unsigned short* __restrict__ xsb)
{
  int blk = blockIdx.x;
  int pix = (blk & 7)*2048 + (blk >> 3);   // each XCD gets 2 contiguous images
  int b = pix >> 10, n = pix & 1023;
  int y = n >> 5, x = n & 31;
  int t = threadIdx.x;
  int c8 = (t < 48 ? t : 47) * 8;          // clamped channel base (lanes 48+ idle)
  float act = t < 48 ? 1.f : 0.f;
  const unsigned short* qb = qs + (size_t)b*1024*CC;
  int ry[5], rx[5]; unsigned my[5], mx[5];
#pragma unroll
  for (int k = 0; k < 5; k++){
    int yy = y + k - 2, xx = x + k - 2;
    my[k] = (yy >= 0 && yy < 32) ? 0xFFFFFFFFu : 0u;
    mx[k] = (xx >= 0 && xx < 32) ? 0xFFFFFFFFu : 0u;
    int yc = yy < 0 ? 0 : (yy > 31 ? 31 : yy);
    int xc = xx < 0 ? 0 : (xx > 31 ? 31 : xx);
    ry[k] = yc*32*CC; rx[k] = xc*CC;
  }
  float a[8];
#pragma unroll
  for (int j = 0; j < 8; j++) a[j] = 0.f;
#pragma unroll
  for (int ky = 0; ky < 5; ky++)
#pragma unroll
  for (int kx = 0; kx < 5; kx++){
    int tap = ky*5 + kx;
    unsigned m = my[ky] & mx[kx];
    uint4 q4 = *(const uint4*)(qb + ry[ky] + rx[kx] + c8);
    uint4 w4 = *(const uint4*)(okb + tap*CC + c8);
    q4.x &= m; q4.y &= m; q4.z &= m; q4.w &= m;
    a[0] = fmaf(lo16(q4.x), lo16(w4.x), a[0]);
    a[1] = fmaf(hi16(q4.x), hi16(w4.x), a[1]);
    a[2] = fmaf(lo16(q4.y), lo16(w4.y), a[2]);
    a[3] = fmaf(hi16(q4.y), hi16(w4.y), a[3]);
    a[4] = fmaf(lo16(q4.z), lo16(w4.z), a[4]);
    a[5] = fmaf(hi16(q4.z), hi16(w4.z), a[5]);
    a[6] = fmaf(lo16(q4.w), lo16(w4.w), a[6]);
    a[7] = fmaf(hi16(q4.w), hi16(w4.w), a[7]);
  }
  float4 kbA = *(const float4*)(offkb + c8);
  float4 kbB = *(const float4*)(offkb + c8 + 4);
  float c[8];
  c[0] = act * fmaf(a[0], INVQS, kbA.x);
  c[1] = act * fmaf(a[1], INVQS, kbA.y);
  c[2] = act * fmaf(a[2], INVQS, kbA.z);
  c[3] = act * fmaf(a[3], INVQS, kbA.w);
  c[4] = act * fmaf(a[4], INVQS, kbB.x);
  c[5] = act * fmaf(a[5], INVQS, kbB.y);
  c[6] = act * fmaf(a[6], INVQS, kbB.z);
  c[7] = act * fmaf(a[7], INVQS, kbB.w);
  float s = 0.f, s2 = 0.f;
#pragma unroll
  for (int j = 0; j < 8; j++){ s += c[j]; s2 += c[j]*c[j]; }
#pragma unroll
  for (int m2 = 32; m2; m2 >>= 1){ s += __shfl_xor(s, m2); s2 += __shfl_xor(s2, m2); }
  float mu = s * (1.f/CC);
  float var = s2 * (1.f/CC) - mu*mu;
  float rs = rsqrtf(var + 1e-5f);
  float4 gA = *(const float4*)(offg + c8); float4 gB = *(const float4*)(offg + c8 + 4);
  float4 oA = *(const float4*)(offb + c8); float4 oB = *(const float4*)(offb + c8 + 4);
  float4 wA = *(const float4*)(Woff + c8); float4 wB = *(const float4*)(Woff + c8 + 4);
  float4 wC = *(const float4*)(Woff + CC + c8); float4 wD = *(const float4*)(Woff + CC + c8 + 4);
  float gg[8] = {gA.x,gA.y,gA.z,gA.w,gB.x,gB.y,gB.z,gB.w};
  float bb[8] = {oA.x,oA.y,oA.z,oA.w,oB.x,oB.y,oB.z,oB.w};
  float w0[8] = {wA.x,wA.y,wA.z,wA.w,wB.x,wB.y,wB.z,wB.w};
  float w1[8] = {wC.x,wC.y,wC.z,wC.w,wD.x,wD.y,wD.z,wD.w};
  float p0 = 0.f, p1 = 0.f;
#pragma unroll
  for (int j = 0; j < 8; j++){
    float v = gelu_fast((c[j] - mu)*rs*gg[j] + bb[j]) * act;
    p0 = fmaf(v, w0[j], p0);
    p1 = fmaf(v, w1[j], p1);
  }
#pragma unroll
  for (int m2 = 32; m2; m2 >>= 1){ p0 += __shfl_xor(p0, m2); p1 += __shfl_xor(p1, m2); }
  float offy = tanh_fast(p0 + boff[0]) * 0.125f;
  float offx = tanh_fast(p1 + boff[1]) * 0.125f;
  float py = ((y + 0.5f)/16.f - 1.f + offy + 1.f) * 0.5f * 31.f;
  float px = ((x + 0.5f)/16.f - 1.f + offx + 1.f) * 0.5f * 31.f;
  float y0f = floorf(py), x0f = floorf(px);
  float wy = py - y0f, wx = px - x0f;
  int y0 = (int)y0f, x0 = (int)x0f;
  y0 = y0 < 0 ? 0 : (y0 > 31 ? 31 : y0);
  x0 = x0 < 0 ? 0 : (x0 > 31 ? 31 : x0);
  int y1 = y0 + 1 > 31 ? 31 : y0 + 1;
  int x1 = x0 + 1 > 31 ? 31 : x0 + 1;
  const unsigned short* s00 = xnb + (size_t)(b*1024 + y0*32 + x0)*CC + c8;
  const unsigned short* s01 = xnb + (size_t)(b*1024 + y0*32 + x1)*CC + c8;
  const unsigned short* s10 = xnb + (size_t)(b*1024 + y1*32 + x0)*CC + c8;
  const unsigned short* s11 = xnb + (size_t)(b*1024 + y1*32 + x1)*CC + c8;
  float w00 = (1.f-wy)*(1.f-wx), w01 = (1.f-wy)*wx, w10 = wy*(1.f-wx), w11 = wy*wx;
  uint4 A0 = *(const uint4*)s00;
  uint4 A1 = *(const uint4*)s01;
  uint4 A2 = *(const uint4*)s10;
  uint4 A3 = *(const uint4*)s11;
  if (t < 48){
    float r[8];
    r[0] = w00*lo16(A0.x) + w01*lo16(A1.x) + w10*lo16(A2.x) + w11*lo16(A3.x);
    r[1] = w00*hi16(A0.x) + w01*hi16(A1.x) + w10*hi16(A2.x) + w11*hi16(A3.x);
    r[2] = w00*lo16(A0.y) + w01*lo16(A1.y) + w10*lo16(A2.y) + w11*lo16(A3.y);
    r[3] = w00*hi16(A0.y) + w01*hi16(A1.y) + w10*hi16(A2.y) + w11*hi16(A3.y);
    r[4] = w00*lo16(A0.z) + w01*lo16(A1.z) + w10*lo16(A2.z) + w11*lo16(A3.z);
    r[5] = w00*hi16(A0.z) + w01*hi16(A1.z) + w10*hi16(A2.z) + w11*hi16(A3.z);
    r[6] = w00*lo16(A0.w) + w01*lo16(A1.w) + w10*lo16(A2.w) + w11*lo16(A3.w);
    r[7] = w00*hi16(A0.w) + w01*hi16(A1.w) + w10*hi16(A2.w) + w11*hi16(A3.w);
    uint4 st;
    st.x = ((unsigned)f2bf(r[1]) << 16) | f2bf(r[0]);
    st.y = ((unsigned)f2bf(r[3]) << 16) | f2bf(r[2]);
    st.z = ((unsigned)f2bf(r[5]) << 16) | f2bf(r[4]);
    st.w = ((unsigned)f2bf(r[7]) << 16) | f2bf(r[6]);
    *(uint4*)(xsb + (size_t)(b*1024 + n)*CC + c8) = st;
  }
}

// ---------------- attention: dbuf K/V + async-stage split, base-2 softmax --------
// qs: bf16 Q scaled by QSCALE; kb row-major; vt: V^T [b][h][d][1024] key-permuted
__global__ __launch_bounds__(256) void k_attn(
    const unsigned short* __restrict__ qs, const unsigned short* __restrict__ kb,
    const unsigned short* __restrict__ vt, unsigned short* __restrict__ ob)
{
  __shared__ unsigned short Ks[2][64][40];   // [buf][key][dim]
  __shared__ unsigned short Vs[2][32][72];   // [buf][dim][physkey]
  __shared__ unsigned short Ps[4][32][72];   // [wave][qrow][physkey]
  int blk = blockIdx.x;
  int sw = (blk & 7)*192 + (blk >> 3);    // XCD-grouped
  int qt = sw & 7, h = (sw >> 3) % 12, b = sw / 96;
  int t = threadIdx.x;
  int w = t >> 6, l = t & 63;
  int g = l >> 4, ln = l & 15;
  int q0 = qt*128 + w*32;
  bf16x8 qa[2];
#pragma unroll
  for (int mi = 0; mi < 2; mi++)
    qa[mi] = *(const bf16x8*)&qs[(size_t)(b*1024 + q0 + mi*16 + ln)*CC + h*32 + g*8];
  f32x4 z = {0.f,0.f,0.f,0.f};
  f32x4 oacc[2][2]; oacc[0][0]=z; oacc[0][1]=z; oacc[1][0]=z; oacc[1][1]=z;
  float lsum[2][4] = {{0.f,0.f,0.f,0.f},{0.f,0.f,0.f,0.f}};
  int krow = t >> 2, kc = (t & 3)*8;
  int vdim = t >> 3, vc = (t & 7)*8;
  const unsigned short* kptr = kb + (size_t)(b*1024 + krow)*CC + h*32 + kc;
  const unsigned short* vptr = vt + (size_t)((b*12 + h)*32 + vdim)*1024 + vc;
  {
    uint4 kr = *(const uint4*)kptr;
    uint4 vr = *(const uint4*)vptr;
    *(uint4*)&Ks[0][krow][kc] = kr;
    *(uint4*)&Vs[0][vdim][vc] = vr;
  }
  __syncthreads();
  for (int kt = 0; kt < 16; kt++){
    int cur = kt & 1;
    uint4 kr2, vr2;
    if (kt < 15){
      int k0 = (kt + 1)*64;
      kr2 = *(const uint4*)(kptr + (size_t)k0*CC);
      vr2 = *(const uint4*)(vptr + k0);
    }
    bf16x8 kf[4];
#pragma unroll
    for (int nt = 0; nt < 4; nt++) kf[nt] = *(const bf16x8*)&Ks[cur][nt*16 + ln][g*8];
    f32x4 s[2][4];
    __builtin_amdgcn_s_setprio(1);
#pragma unroll
    for (int mi = 0; mi < 2; mi++)
#pragma unroll
      for (int nt = 0; nt < 4; nt++) s[mi][nt] = mfma16(qa[mi], kf[nt], z);
    __builtin_amdgcn_s_setprio(0);
#pragma unroll
    for (int mi = 0; mi < 2; mi++)
#pragma unroll
      for (int i = 0; i < 4; i++){
        float p0 = fexp2(s[mi][0][i]);
        float p1 = fexp2(s[mi][1][i]);
        float p2 = fexp2(s[mi][2][i]);
        float p3 = fexp2(s[mi][3][i]);
        lsum[mi][i] += (p0 + p1) + (p2 + p3);
        int prow = mi*16 + g*4 + i;
        uint2 pk;
        pk.x = __builtin_amdgcn_perm(__float_as_uint(p1), __float_as_uint(p0), 0x07060302u);
        pk.y = __builtin_amdgcn_perm(__float_as_uint(p3), __float_as_uint(p2), 0x07060302u);
        *(uint2*)&Ps[w][prow][ln*4] = pk;
      }
    __builtin_amdgcn_s_setprio(1);
#pragma unroll
    for (int k2 = 0; k2 < 2; k2++){
      bf16x8 va[2];
#pragma unroll
      for (int d2 = 0; d2 < 2; d2++) va[d2] = *(const bf16x8*)&Vs[cur][d2*16 + ln][k2*32 + g*8];
#pragma unroll
      for (int mi = 0; mi < 2; mi++){
        bf16x8 pf = *(const bf16x8*)&Ps[w][mi*16 + ln][k2*32 + g*8];
#pragma unroll
        for (int d2 = 0; d2 < 2; d2++) oacc[mi][d2] = mfma16(pf, va[d2], oacc[mi][d2]);
      }
    }
    __builtin_amdgcn_s_setprio(0);
    if (kt < 15){
      *(uint4*)&Ks[cur ^ 1][krow][kc] = kr2;
      *(uint4*)&Vs[cur ^ 1][vdim][vc] = vr2;
      __syncthreads();
    }
  }
#pragma unroll
  for (int mi = 0; mi < 2; mi++)
#pragma unroll
    for (int i = 0; i < 4; i++){
#pragma unroll
      for (int mk = 8; mk; mk >>= 1) lsum[mi][i] += __shfl_xor(lsum[mi][i], mk);
      lsum[mi][i] = 1.f / lsum[mi][i];
    }
#pragma unroll
  for (int mi = 0; mi < 2; mi++)
#pragma unroll
  for (int d2 = 0; d2 < 2; d2++)
#pragma unroll
  for (int i = 0; i < 4; i++){
    float v = oacc[mi][d2][i] * lsum[mi][i];
    int row = q0 + mi*16 + g*4 + i;
    ob[(size_t)(b*1024 + row)*CC + h*32 + d2*16 + ln] = f2bf(v);
  }
}

extern "C" void kernel_launch(void* const* d_in, const int* in_sizes, int n_in,
                              void* d_out, int out_size, void* d_ws, size_t ws_size,
                              hipStream_t stream)
{
  (void)in_sizes; (void)n_in; (void)out_size; (void)ws_size;
  const float* x     = (const float*)d_in[0];
  const float* ln1g  = (const float*)d_in[1];
  const float* ln1b  = (const float*)d_in[2];
  const float* Wq    = (const float*)d_in[3];
  const float* bq    = (const float*)d_in[4];
  const float* offk  = (const float*)d_in[5];
  const float* offkb = (const float*)d_in[6];
  const float* offg  = (const float*)d_in[7];
  const float* offb  = (const float*)d_in[8];
  const float* Woff  = (const float*)d_in[9];
  const float* boff  = (const float*)d_in[10];
  const float* Wk    = (const float*)d_in[11];
  const float* bk    = (const float*)d_in[12];
  const float* Wv    = (const float*)d_in[13];
  const float* bv    = (const float*)d_in[14];
  const float* Wo    = (const float*)d_in[15];
  const float* bo    = (const float*)d_in[16];
  const float* ln2g  = (const float*)d_in[17];
  const float* ln2b  = (const float*)d_in[18];
  const float* W1    = (const float*)d_in[19];
  const float* b1    = (const float*)d_in[20];
  const float* W2    = (const float*)d_in[21];
  const float* b2    = (const float*)d_in[22];

  char* ws = (char*)d_ws;
  // layout (bytes):
  //   [0, 12582912)          X2B bf16 (residual stream after attn)
  //   [25165824, 37748736)   XSB bf16      -+
  //   [37748736, 50331648)   KB bf16        |  reused as HB (50331648 B) in MLP
  //   [50331648, 62914560)   VT bf16        |
  //   [62914560, 75497472)   OB bf16       -+
  //   [75497472, 88080384)   XNB bf16
  //   [88080384, 100663296)  QSB bf16 -> reused as YB after attn
  //   [100663296, 104221440) weights bf16 (incl offk bf16 tail)
  unsigned short* X2B = (unsigned short*)ws;
  unsigned short* XSB = (unsigned short*)(ws + 25165824);
  unsigned short* KB  = (unsigned short*)(ws + 37748736);
  unsigned short* VT  = (unsigned short*)(ws + 50331648);
  unsigned short* OB  = (unsigned short*)(ws + 62914560);
  unsigned short* XNB = (unsigned short*)(ws + 75497472);
  unsigned short* QSB = (unsigned short*)(ws + 88080384);
  unsigned short* YB  = QSB;
  unsigned short* HB  = (unsigned short*)(ws + 25165824);
  unsigned short* WQB = (unsigned short*)(ws + 100663296);
  unsigned short* WKB = WQB + 147456;   // Wk rows 0-383, Wv rows 384-767 (contiguous)
  unsigned short* WOB = WKB + 294912;
  unsigned short* W1B = WOB + 147456;
  unsigned short* W2B = W1B + 589824;
  unsigned short* OKB = W2B + 589824;   // bf16 offk [25][384]

  k_cvt_all<<<1738, 256, 0, stream>>>(Wq, Wk, Wv, Wo, W1, W2, offk, WQB);
  k_ln<0><<<4096, 256, 0, stream>>>(x, nullptr, ln1g, ln1b, XNB);
  k_gemm64<5><<<768, 256, 0, stream>>>(XNB, WQB, bq, nullptr, nullptr, nullptr, nullptr, QSB, nullptr, 3, 384, 384);
  k_offset_sample<<<16384, 64, 0, stream>>>(QSB, XNB, OKB, offkb, offg, offb, Woff, boff, XSB);
  k_gemm64<6><<<1536, 256, 0, stream>>>(XSB, WKB, bk, bv, nullptr, nullptr, nullptr, KB, VT, 6, 768, 384);
  k_attn<<<1536, 256, 0, stream>>>(QSB, KB, VT, OB);
  k_gemm64<2><<<768, 256, 0, stream>>>(OB, WOB, bo, nullptr, x, nullptr, nullptr, X2B, nullptr, 3, 384, 384);
  k_ln<1><<<4096, 256, 0, stream>>>(nullptr, X2B, ln2g, ln2b, YB);
  k_gemm64<3><<<3072, 256, 0, stream>>>(YB, W1B, b1, nullptr, nullptr, nullptr, nullptr, HB, nullptr, 12, 1536, 384);
  k_gemm64<7><<<768, 256, 0, stream>>>(HB, W2B, b2, nullptr, nullptr, X2B, (float*)d_out, nullptr, nullptr, 3, 384, 1536);
}

// Round 9
// 240.254 us; speedup vs baseline: 1.3231x; 1.0203x over previous
//
#include <hip/hip_runtime.h>
#include <math.h>

#define DI __device__ __forceinline__

typedef __attribute__((ext_vector_type(8))) short bf16x8;
typedef __attribute__((ext_vector_type(4))) float f32x4;

static constexpr int CC = 384;
// attn scale * log2(e): scores come out of QK^T already in log2 domain
static constexpr float QSCALE = 0.17677669529663687f * 1.4426950408889634f;
static constexpr float INVQS  = 1.0f / QSCALE;

DI unsigned short f2bf(float f){
  unsigned u = __float_as_uint(f);
  u += 0x7FFFu + ((u >> 16) & 1u);
  return (unsigned short)(u >> 16);
}
DI float bf2f(unsigned short u){ return __uint_as_float((unsigned)u << 16); }
DI float lo16(unsigned u){ return __uint_as_float(u << 16); }
DI float hi16(unsigned u){ return __uint_as_float(u & 0xFFFF0000u); }
DI float fexp2(float x){ return __builtin_amdgcn_exp2f(x); }
DI float frcp(float x){ return __builtin_amdgcn_rcpf(x); }
// tanh(z) = 1 - 2/(exp2(z*2*log2e)+1)
DI float tanh_fast(float z){ return 1.f - 2.f*frcp(fexp2(2.8853900817779268f*z) + 1.f); }
DI float gelu_fast(float v){
  float u = v*v;
  float z = 0.7978845608028654f * fmaf(0.044715f*u, v, v);
  return v - v*frcp(fexp2(2.8853900817779268f*z) + 1.f);
}
DI f32x4 mfma16(bf16x8 a, bf16x8 b, f32x4 c){
  return __builtin_amdgcn_mfma_f32_16x16x32_bf16(a, b, c, 0, 0, 0);
}
DI void gload16(const unsigned short* g, unsigned short* l){
  __builtin_amdgcn_global_load_lds(
      (const __attribute__((address_space(1))) unsigned int*)(const void*)g,
      (__attribute__((address_space(3))) unsigned int*)(void*)l, 16, 0, 0);
}

// ---------------- weight fp32 -> bf16 (6 matmul weights + offk), vectorized x4 ---
__global__ __launch_bounds__(256) void k_cvt_all(
    const float* __restrict__ wq, const float* __restrict__ wk,
    const float* __restrict__ wv, const float* __restrict__ wo,
    const float* __restrict__ w1, const float* __restrict__ w2,
    const float* __restrict__ ofk,
    unsigned short* __restrict__ dst)
{
  int i4 = (blockIdx.x*256 + threadIdx.x)*4;
  if (i4 >= 1779072) return;
  const float* src; int off;
  if (i4 < 147456){ src = wq; off = i4; }
  else if (i4 < 294912){ src = wk; off = i4 - 147456; }
  else if (i4 < 442368){ src = wv; off = i4 - 294912; }
  else if (i4 < 589824){ src = wo; off = i4 - 442368; }
  else if (i4 < 1179648){ src = w1; off = i4 - 589824; }
  else if (i4 < 1769472){ src = w2; off = i4 - 1179648; }
  else { src = ofk; off = i4 - 1769472; }
  float4 v = *(const float4*)(src + off);
  uint2 o;
  o.x = ((unsigned)f2bf(v.y) << 16) | f2bf(v.x);
  o.y = ((unsigned)f2bf(v.w) << 16) | f2bf(v.z);
  *(uint2*)(dst + i4) = o;
}

// ---------------- LayerNorm over C=384, one wave/row, 4 rows/block --------------
// BIN=0: f32 input (scalar loads)   BIN=1: bf16 input (vectorized 6 ch/lane)
template<int BIN>
__global__ __launch_bounds__(256) void k_ln(const float* __restrict__ xf,
    const unsigned short* __restrict__ xb,
    const float* __restrict__ g, const float* __restrict__ b,
    unsigned short* __restrict__ outb)
{
  int row = blockIdx.x*4 + (threadIdx.x >> 6);
  int l = threadIdx.x & 63;
  float v[6]; int ch[6];
  if constexpr (BIN){
    int cA = 4*l, cB = 256 + 2*l;
    ch[0]=cA; ch[1]=cA+1; ch[2]=cA+2; ch[3]=cA+3; ch[4]=cB; ch[5]=cB+1;
    const unsigned short* xp = xb + (size_t)row * CC;
    uint2 u2 = *(const uint2*)(xp + cA);
    unsigned u1 = *(const unsigned*)(xp + cB);
    v[0]=lo16(u2.x); v[1]=hi16(u2.x); v[2]=lo16(u2.y); v[3]=hi16(u2.y);
    v[4]=lo16(u1);   v[5]=hi16(u1);
  } else {
    const float* xp = xf + (size_t)row * CC;
#pragma unroll
    for (int p = 0; p < 6; p++){ ch[p] = l + 64*p; v[p] = xp[ch[p]]; }
  }
  float s = 0.f, s2 = 0.f;
#pragma unroll
  for (int p = 0; p < 6; p++){ s += v[p]; s2 += v[p]*v[p]; }
#pragma unroll
  for (int m = 32; m; m >>= 1){ s += __shfl_xor(s, m); s2 += __shfl_xor(s2, m); }
  float mu = s * (1.f/CC);
  float var = s2 * (1.f/CC) - mu*mu;
  float rs = rsqrtf(var + 1e-5f);
  float o[6];
#pragma unroll
  for (int p = 0; p < 6; p++) o[p] = (v[p] - mu) * rs * g[ch[p]] + b[ch[p]];
  unsigned short* op = outb + (size_t)row*CC;
  if constexpr (BIN){
    uint2 st;
    st.x = ((unsigned)f2bf(o[1]) << 16) | f2bf(o[0]);
    st.y = ((unsigned)f2bf(o[3]) << 16) | f2bf(o[2]);
    *(uint2*)(op + ch[0]) = st;
    *(unsigned*)(op + ch[4]) = ((unsigned)f2bf(o[5]) << 16) | f2bf(o[4]);
  } else {
#pragma unroll
    for (int p = 0; p < 6; p++) op[ch[p]] = f2bf(o[p]);
  }
}

// ---------------- 64x128 GEMM, BK=32, dbuf LDS + gload_lds + XCD swizzle ---------
// out(M,N) = A(M,K) @ W(N,K)^T + bias.  1D grid, ntn = N/128 tiles.
// EPI 0: f32   1: bf16   3: bf16 gelu   5: bf16 * QSCALE
// EPI 2: + f32 res -> bf16 out          7: + bf16 res -> f32 out
// EPI 6: fused K|V (N=768): col<384 -> KB; col>=384 -> VT transposed+key-permuted
template<int EPI>
__global__ __launch_bounds__(256) void k_gemm64(
    const unsigned short* __restrict__ A, const unsigned short* __restrict__ W,
    const float* __restrict__ bias, const float* __restrict__ bias2,
    const float* __restrict__ res, const unsigned short* __restrict__ resb,
    float* __restrict__ outf, unsigned short* __restrict__ outb,
    unsigned short* __restrict__ outb2, int ntn, int N, int K)
{
  __shared__ unsigned short As[2][2048];   // 64 rows x 32 cols, slot-swizzled
  __shared__ unsigned short Bs[2][4096];   // 128 rows x 32 cols
  int bid = blockIdx.x;
  int cpx = gridDim.x >> 3;
  int id = (bid & 7)*cpx + (bid >> 3);     // XCD-chunk swizzle
  int bn = (id % ntn) * 128;
  int bm = (id / ntn) * 64;
  int t = threadIdx.x;
  int w = t >> 6, l = t & 63;
  int g = l >> 4, ln = l & 15;
  int wm = w >> 1, wn = w & 1;             // wave: 32 rows x 64 cols
  f32x4 acc[2][4];
#pragma unroll
  for (int i = 0; i < 2; i++)
#pragma unroll
    for (int j = 0; j < 4; j++) acc[i][j] = (f32x4){0.f,0.f,0.f,0.f};
  int srow = t >> 2, slot = t & 3;
  int srowB = srow + 64;
  int cb0 = (slot ^ (srow  & 3) ^ ((srow  >> 2) & 3)) * 8;
  int cb1 = (slot ^ (srowB & 3) ^ ((srowB >> 2) & 3)) * 8;
  const unsigned short* Ap  = A + (size_t)(bm + srow)*K + cb0;
  const unsigned short* Wp0 = W + (size_t)(bn + srow)*K + cb0;
  const unsigned short* Wp1 = W + (size_t)(bn + srowB)*K + cb1;
  int NT = K >> 5;
  int wl = w*512;
  gload16(Ap,  &As[0][wl]);
  gload16(Wp0, &Bs[0][wl]);
  gload16(Wp1, &Bs[0][wl + 2048]);
  __syncthreads();
  for (int kt = 0; kt < NT; kt++){
    int cur = kt & 1;
    if (kt + 1 < NT){
      int k0 = (kt + 1) << 5;
      gload16(Ap  + k0, &As[cur ^ 1][wl]);
      gload16(Wp0 + k0, &Bs[cur ^ 1][wl]);
      gload16(Wp1 + k0, &Bs[cur ^ 1][wl + 2048]);
    }
    bf16x8 af[2], bf[4];
#pragma unroll
    for (int mi = 0; mi < 2; mi++){
      int row = wm*32 + mi*16 + ln;
      int sl = g ^ (row & 3) ^ ((row >> 2) & 3);
      af[mi] = *(const bf16x8*)((const char*)As[cur] + row*64 + sl*16);
    }
#pragma unroll
    for (int ni = 0; ni < 4; ni++){
      int row = wn*64 + ni*16 + ln;
      int sl = g ^ (row & 3) ^ ((row >> 2) & 3);
      bf[ni] = *(const bf16x8*)((const char*)Bs[cur] + row*64 + sl*16);
    }
#pragma unroll
    for (int mi = 0; mi < 2; mi++)
#pragma unroll
      for (int ni = 0; ni < 4; ni++)
        acc[mi][ni] = mfma16(af[mi], bf[ni], acc[mi][ni]);
    if (kt + 1 < NT) __syncthreads();
  }
#pragma unroll
  for (int mi = 0; mi < 2; mi++)
#pragma unroll
  for (int ni = 0; ni < 4; ni++){
    int col = bn + wn*64 + ni*16 + ln;
    float bv;
    if constexpr (EPI == 6) bv = col < 384 ? bias[col] : bias2[col - 384];
    else bv = bias[col];
#pragma unroll
    for (int i = 0; i < 4; i++){
      int row = bm + wm*32 + mi*16 + g*4 + i;
      float v = acc[mi][ni][i] + bv;
      if constexpr (EPI == 2){ v += res[(size_t)row*N + col]; outb[(size_t)row*N + col] = f2bf(v); }
      if constexpr (EPI == 7){ v += bf2f(resb[(size_t)row*N + col]); outf[(size_t)row*N + col] = v; }
      if constexpr (EPI == 3) v = gelu_fast(v);
      if constexpr (EPI == 0) outf[(size_t)row*N + col] = v;
      if constexpr (EPI == 1 || EPI == 3) outb[(size_t)row*N + col] = f2bf(v);
      if constexpr (EPI == 5) outb[(size_t)row*N + col] = f2bf(v * QSCALE);
      if constexpr (EPI == 6){
        if (col < 384){
          outb[(size_t)row*384 + col] = f2bf(v);
        } else {
          int c = col - 384;
          int bb = row >> 10, key = row & 1023, h = c >> 5, d = c & 31;
          int k6 = key & 63;
          int phys = (key & ~63) | ((k6 & 15) << 2) | (k6 >> 4);
          outb2[(size_t)(((bb*12 + h) << 5) + d)*1024 + phys] = f2bf(v);
        }
      }
    }
  }
}

// ---------------- MLP1: 128x128 GEMM, BK=32, dbuf, gelu-bf16 epilogue ------------
// out(16384,1536) = A(16384,384) @ W1(1536,384)^T + b1, gelu
__global__ __launch_bounds__(256) void k_mlp1(
    const unsigned short* __restrict__ A, const unsigned short* __restrict__ W,
    const float* __restrict__ bias, unsigned short* __restrict__ outb)
{
  __shared__ unsigned short As[2][4096];   // 128 x 32, slot-swizzled
  __shared__ unsigned short Bs[2][4096];
  int bid = blockIdx.x;
  int cpx = gridDim.x >> 3;                // 192
  int id = (bid & 7)*cpx + (bid >> 3);     // XCD-chunk swizzle
  int bn = (id % 12) * 128;
  int bm = (id / 12) * 128;
  int t = threadIdx.x;
  int w = t >> 6, l = t & 63;
  int g = l >> 4, ln = l & 15;
  int wm = w >> 1, wn = w & 1;
  f32x4 acc[4][4];
#pragma unroll
  for (int i = 0; i < 4; i++)
#pragma unroll
    for (int j = 0; j < 4; j++) acc[i][j] = (f32x4){0.f,0.f,0.f,0.f};
  int srow0 = t >> 2, slot = t & 3;
  int srow1 = srow0 + 64;
  int cb0 = (slot ^ (srow0 & 3) ^ ((srow0 >> 2) & 3)) * 8;
  int cb1 = (slot ^ (srow1 & 3) ^ ((srow1 >> 2) & 3)) * 8;
  const unsigned short* Ap0 = A + (size_t)(bm + srow0)*384 + cb0;
  const unsigned short* Ap1 = A + (size_t)(bm + srow1)*384 + cb1;
  const unsigned short* Wp0 = W + (size_t)(bn + srow0)*384 + cb0;
  const unsigned short* Wp1 = W + (size_t)(bn + srow1)*384 + cb1;
  int wl = w*512;
  gload16(Ap0, &As[0][wl]);
  gload16(Ap1, &As[0][wl + 2048]);
  gload16(Wp0, &Bs[0][wl]);
  gload16(Wp1, &Bs[0][wl + 2048]);
  __syncthreads();
  for (int kt = 0; kt < 12; kt++){
    int cur = kt & 1;
    if (kt < 11){
      int k0 = (kt + 1) << 5;
      gload16(Ap0 + k0, &As[cur ^ 1][wl]);
      gload16(Ap1 + k0, &As[cur ^ 1][wl + 2048]);
      gload16(Wp0 + k0, &Bs[cur ^ 1][wl]);
      gload16(Wp1 + k0, &Bs[cur ^ 1][wl + 2048]);
    }
    bf16x8 af[4], bf[4];
#pragma unroll
    for (int mi = 0; mi < 4; mi++){
      int row = wm*64 + mi*16 + ln;
      int sl = g ^ (row & 3) ^ ((row >> 2) & 3);
      af[mi] = *(const bf16x8*)((const char*)As[cur] + row*64 + sl*16);
    }
#pragma unroll
    for (int ni = 0; ni < 4; ni++){
      int row = wn*64 + ni*16 + ln;
      int sl = g ^ (row & 3) ^ ((row >> 2) & 3);
      bf[ni] = *(const bf16x8*)((const char*)Bs[cur] + row*64 + sl*16);
    }
#pragma unroll
    for (int mi = 0; mi < 4; mi++)
#pragma unroll
      for (int ni = 0; ni < 4; ni++)
        acc[mi][ni] = mfma16(af[mi], bf[ni], acc[mi][ni]);
    if (kt < 11) __syncthreads();
  }
#pragma unroll
  for (int mi = 0; mi < 4; mi++)
#pragma unroll
  for (int ni = 0; ni < 4; ni++){
    int col = bn + wn*64 + ni*16 + ln;
    float bv = bias[col];
#pragma unroll
    for (int i = 0; i < 4; i++){
      int row = bm + wm*64 + mi*16 + g*4 + i;
      float v = gelu_fast(acc[mi][ni][i] + bv);
      outb[(size_t)row*1536 + col] = f2bf(v);
    }
  }
}

// ---------------- fused offset net + grid sample: one WAVE per pixel -------------
// 8 channels/thread on 48 active lanes; all accesses are 16B uint4
__global__ __launch_bounds__(64) void k_offset_sample(
    const unsigned short* __restrict__ qs, const unsigned short* __restrict__ xnb,
    const unsigned short* __restrict__ okb,  // bf16 offk [25][384]
    const float* __restrict__ offkb,
    const float* __restrict__ offg, const float* __restrict__ offb,
    const float* __restrict__ Woff, const float* __restrict__ boff,
    unsigned short* __restrict__ xsb)
{
  int blk = blockIdx.x;
  int pix = (blk & 7)*2048 + (blk >> 3);   // each XCD gets 2 contiguous images
  int b = pix >> 10, n = pix & 1023;
  int y = n >> 5, x = n & 31;
  int t = threadIdx.x;
  int c8 = (t < 48 ? t : 47) * 8;          // clamped channel base (lanes 48+ idle)
  float act = t < 48 ? 1.f : 0.f;
  const unsigned short* qb = qs + (size_t)b*1024*CC;
  int ry[5], rx[5]; unsigned my[5], mx[5];
#pragma unroll
  for (int k = 0; k < 5; k++){
    int yy = y + k - 2, xx = x + k - 2;
    my[k] = (yy >= 0 && yy < 32) ? 0xFFFFFFFFu : 0u;
    mx[k] = (xx >= 0 && xx < 32) ? 0xFFFFFFFFu : 0u;
    int yc = yy < 0 ? 0 : (yy > 31 ? 31 : yy);
    int xc = xx < 0 ? 0 : (xx > 31 ? 31 : xx);
    ry[k] = yc*32*CC; rx[k] = xc*CC;
  }
  float a[8];
#pragma unroll
  for (int j = 0; j < 8; j++) a[j] = 0.f;
#pragma unroll
  for (int ky = 0; ky < 5; ky++)
#pragma unroll
  for (int kx = 0; kx < 5; kx++){
    int tap = ky*5 + kx;
    unsigned m = my[ky] & mx[kx];
    uint4 q4 = *(const uint4*)(qb + ry[ky] + rx[kx] + c8);
    uint4 w4 = *(const uint4*)(okb + tap*CC + c8);
    q4.x &= m; q4.y &= m; q4.z &= m; q4.w &= m;
    a[0] = fmaf(lo16(q4.x), lo16(w4.x), a[0]);
    a[1] = fmaf(hi16(q4.x), hi16(w4.x), a[1]);
    a[2] = fmaf(lo16(q4.y), lo16(w4.y), a[2]);
    a[3] = fmaf(hi16(q4.y), hi16(w4.y), a[3]);
    a[4] = fmaf(lo16(q4.z), lo16(w4.z), a[4]);
    a[5] = fmaf(hi16(q4.z), hi16(w4.z), a[5]);
    a[6] = fmaf(lo16(q4.w), lo16(w4.w), a[6]);
    a[7] = fmaf(hi16(q4.w), hi16(w4.w), a[7]);
  }
  float4 kbA = *(const float4*)(offkb + c8);
  float4 kbB = *(const float4*)(offkb + c8 + 4);
  float c[8];
  c[0] = act * fmaf(a[0], INVQS, kbA.x);
  c[1] = act * fmaf(a[1], INVQS, kbA.y);
  c[2] = act * fmaf(a[2], INVQS, kbA.z);
  c[3] = act * fmaf(a[3], INVQS, kbA.w);
  c[4] = act * fmaf(a[4], INVQS, kbB.x);
  c[5] = act * fmaf(a[5], INVQS, kbB.y);
  c[6] = act * fmaf(a[6], INVQS, kbB.z);
  c[7] = act * fmaf(a[7], INVQS, kbB.w);
  float s = 0.f, s2 = 0.f;
#pragma unroll
  for (int j = 0; j < 8; j++){ s += c[j]; s2 += c[j]*c[j]; }
#pragma unroll
  for (int m2 = 32; m2; m2 >>= 1){ s += __shfl_xor(s, m2); s2 += __shfl_xor(s2, m2); }
  float mu = s * (1.f/CC);
  float var = s2 * (1.f/CC) - mu*mu;
  float rs = rsqrtf(var + 1e-5f);
  float4 gA = *(const float4*)(offg + c8); float4 gB = *(const float4*)(offg + c8 + 4);
  float4 oA = *(const float4*)(offb + c8); float4 oB = *(const float4*)(offb + c8 + 4);
  float4 wA = *(const float4*)(Woff + c8); float4 wB = *(const float4*)(Woff + c8 + 4);
  float4 wC = *(const float4*)(Woff + CC + c8); float4 wD = *(const float4*)(Woff + CC + c8 + 4);
  float gg[8] = {gA.x,gA.y,gA.z,gA.w,gB.x,gB.y,gB.z,gB.w};
  float bb[8] = {oA.x,oA.y,oA.z,oA.w,oB.x,oB.y,oB.z,oB.w};
  float w0[8] = {wA.x,wA.y,wA.z,wA.w,wB.x,wB.y,wB.z,wB.w};
  float w1[8] = {wC.x,wC.y,wC.z,wC.w,wD.x,wD.y,wD.z,wD.w};
  float p0 = 0.f, p1 = 0.f;
#pragma unroll
  for (int j = 0; j < 8; j++){
    float v = gelu_fast((c[j] - mu)*rs*gg[j] + bb[j]) * act;
    p0 = fmaf(v, w0[j], p0);
    p1 = fmaf(v, w1[j], p1);
  }
#pragma unroll
  for (int m2 = 32; m2; m2 >>= 1){ p0 += __shfl_xor(p0, m2); p1 += __shfl_xor(p1, m2); }
  float offy = tanh_fast(p0 + boff[0]) * 0.125f;
  float offx = tanh_fast(p1 + boff[1]) * 0.125f;
  float py = ((y + 0.5f)/16.f - 1.f + offy + 1.f) * 0.5f * 31.f;
  float px = ((x + 0.5f)/16.f - 1.f + offx + 1.f) * 0.5f * 31.f;
  float y0f = floorf(py), x0f = floorf(px);
  float wy = py - y0f, wx = px - x0f;
  int y0 = (int)y0f, x0 = (int)x0f;
  y0 = y0 < 0 ? 0 : (y0 > 31 ? 31 : y0);
  x0 = x0 < 0 ? 0 : (x0 > 31 ? 31 : x0);
  int y1 = y0 + 1 > 31 ? 31 : y0 + 1;
  int x1 = x0 + 1 > 31 ? 31 : x0 + 1;
  const unsigned short* s00 = xnb + (size_t)(b*1024 + y0*32 + x0)*CC + c8;
  const unsigned short* s01 = xnb + (size_t)(b*1024 + y0*32 + x1)*CC + c8;
  const unsigned short* s10 = xnb + (size_t)(b*1024 + y1*32 + x0)*CC + c8;
  const unsigned short* s11 = xnb + (size_t)(b*1024 + y1*32 + x1)*CC + c8;
  float w00 = (1.f-wy)*(1.f-wx), w01 = (1.f-wy)*wx, w10 = wy*(1.f-wx), w11 = wy*wx;
  uint4 A0 = *(const uint4*)s00;
  uint4 A1 = *(const uint4*)s01;
  uint4 A2 = *(const uint4*)s10;
  uint4 A3 = *(const uint4*)s11;
  if (t < 48){
    float r[8];
    r[0] = w00*lo16(A0.x) + w01*lo16(A1.x) + w10*lo16(A2.x) + w11*lo16(A3.x);
    r[1] = w00*hi16(A0.x) + w01*hi16(A1.x) + w10*hi16(A2.x) + w11*hi16(A3.x);
    r[2] = w00*lo16(A0.y) + w01*lo16(A1.y) + w10*lo16(A2.y) + w11*lo16(A3.y);
    r[3] = w00*hi16(A0.y) + w01*hi16(A1.y) + w10*hi16(A2.y) + w11*hi16(A3.y);
    r[4] = w00*lo16(A0.z) + w01*lo16(A1.z) + w10*lo16(A2.z) + w11*lo16(A3.z);
    r[5] = w00*hi16(A0.z) + w01*hi16(A1.z) + w10*hi16(A2.z) + w11*hi16(A3.z);
    r[6] = w00*lo16(A0.w) + w01*lo16(A1.w) + w10*lo16(A2.w) + w11*lo16(A3.w);
    r[7] = w00*hi16(A0.w) + w01*hi16(A1.w) + w10*hi16(A2.w) + w11*hi16(A3.w);
    uint4 st;
    st.x = ((unsigned)f2bf(r[1]) << 16) | f2bf(r[0]);
    st.y = ((unsigned)f2bf(r[3]) << 16) | f2bf(r[2]);
    st.z = ((unsigned)f2bf(r[5]) << 16) | f2bf(r[4]);
    st.w = ((unsigned)f2bf(r[7]) << 16) | f2bf(r[6]);
    *(uint4*)(xsb + (size_t)(b*1024 + n)*CC + c8) = st;
  }
}

// ---------------- attention: dbuf K/V, base-2 softmax, lsum via ones-MFMA --------
// qs: bf16 Q scaled by QSCALE; kb row-major; vt: V^T [b][h][d][1024] key-permuted
__global__ __launch_bounds__(256) void k_attn(
    const unsigned short* __restrict__ qs, const unsigned short* __restrict__ kb,
    const unsigned short* __restrict__ vt, unsigned short* __restrict__ ob)
{
  __shared__ unsigned short Ks[2][64][40];   // [buf][key][dim]
  __shared__ unsigned short Vs[2][32][72];   // [buf][dim][physkey]
  __shared__ unsigned short Ps[4][32][72];   // [wave][qrow][physkey]
  int blk = blockIdx.x;
  int sw = (blk & 7)*192 + (blk >> 3);    // XCD-grouped
  int qt = sw & 7, h = (sw >> 3) % 12, b = sw / 96;
  int t = threadIdx.x;
  int w = t >> 6, l = t & 63;
  int g = l >> 4, ln = l & 15;
  int q0 = qt*128 + w*32;
  bf16x8 qa[2];
#pragma unroll
  for (int mi = 0; mi < 2; mi++)
    qa[mi] = *(const bf16x8*)&qs[(size_t)(b*1024 + q0 + mi*16 + ln)*CC + h*32 + g*8];
  bf16x8 vones;
#pragma unroll
  for (int j = 0; j < 8; j++) vones[j] = (short)0x3F80;   // bf16 1.0
  f32x4 z = {0.f,0.f,0.f,0.f};
  f32x4 oacc[2][2]; oacc[0][0]=z; oacc[0][1]=z; oacc[1][0]=z; oacc[1][1]=z;
  f32x4 lacc[2]; lacc[0]=z; lacc[1]=z;    // row-sum of P via ones-MFMA
  int krow = t >> 2, kc = (t & 3)*8;
  int vdim = t >> 3, vc = (t & 7)*8;
  const unsigned short* kptr = kb + (size_t)(b*1024 + krow)*CC + h*32 + kc;
  const unsigned short* vptr = vt + (size_t)((b*12 + h)*32 + vdim)*1024 + vc;
  {
    uint4 kr = *(const uint4*)kptr;
    uint4 vr = *(const uint4*)vptr;
    *(uint4*)&Ks[0][krow][kc] = kr;
    *(uint4*)&Vs[0][vdim][vc] = vr;
  }
  __syncthreads();
  for (int kt = 0; kt < 16; kt++){
    int cur = kt & 1;
    uint4 kr2, vr2;
    if (kt < 15){
      int k0 = (kt + 1)*64;
      kr2 = *(const uint4*)(kptr + (size_t)k0*CC);
      vr2 = *(const uint4*)(vptr + k0);
    }
    bf16x8 kf[4];
#pragma unroll
    for (int nt = 0; nt < 4; nt++) kf[nt] = *(const bf16x8*)&Ks[cur][nt*16 + ln][g*8];
    f32x4 s[2][4];
    __builtin_amdgcn_s_setprio(1);
#pragma unroll
    for (int mi = 0; mi < 2; mi++)
#pragma unroll
      for (int nt = 0; nt < 4; nt++) s[mi][nt] = mfma16(qa[mi], kf[nt], z);
    __builtin_amdgcn_s_setprio(0);
#pragma unroll
    for (int mi = 0; mi < 2; mi++)
#pragma unroll
      for (int i = 0; i < 4; i++){
        float p0 = fexp2(s[mi][0][i]);
        float p1 = fexp2(s[mi][1][i]);
        float p2 = fexp2(s[mi][2][i]);
        float p3 = fexp2(s[mi][3][i]);
        int prow = mi*16 + g*4 + i;
        uint2 pk;
        pk.x = __builtin_amdgcn_perm(__float_as_uint(p1), __float_as_uint(p0), 0x07060302u);
        pk.y = __builtin_amdgcn_perm(__float_as_uint(p3), __float_as_uint(p2), 0x07060302u);
        *(uint2*)&Ps[w][prow][ln*4] = pk;
      }
    __builtin_amdgcn_s_setprio(1);
#pragma unroll
    for (int k2 = 0; k2 < 2; k2++){
      bf16x8 va[2];
#pragma unroll
      for (int d2 = 0; d2 < 2; d2++) va[d2] = *(const bf16x8*)&Vs[cur][d2*16 + ln][k2*32 + g*8];
#pragma unroll
      for (int mi = 0; mi < 2; mi++){
        bf16x8 pf = *(const bf16x8*)&Ps[w][mi*16 + ln][k2*32 + g*8];
#pragma unroll
        for (int d2 = 0; d2 < 2; d2++) oacc[mi][d2] = mfma16(pf, va[d2], oacc[mi][d2]);
        lacc[mi] = mfma16(pf, vones, lacc[mi]);
      }
    }
    __builtin_amdgcn_s_setprio(0);
    if (kt < 15){
      *(uint4*)&Ks[cur ^ 1][krow][kc] = kr2;
      *(uint4*)&Vs[cur ^ 1][vdim][vc] = vr2;
      __syncthreads();
    }
  }
  // lacc[mi][i] = full row-sum of bf16 P (replicated across lanes)
  float rinv[2][4];
#pragma unroll
  for (int mi = 0; mi < 2; mi++)
#pragma unroll
    for (int i = 0; i < 4; i++) rinv[mi][i] = frcp(lacc[mi][i]);
#pragma unroll
  for (int mi = 0; mi < 2; mi++)
#pragma unroll
  for (int d2 = 0; d2 < 2; d2++)
#pragma unroll
  for (int i = 0; i < 4; i++){
    float v = oacc[mi][d2][i] * rinv[mi][i];
    int row = q0 + mi*16 + g*4 + i;
    ob[(size_t)(b*1024 + row)*CC + h*32 + d2*16 + ln] = f2bf(v);
  }
}

extern "C" void kernel_launch(void* const* d_in, const int* in_sizes, int n_in,
                              void* d_out, int out_size, void* d_ws, size_t ws_size,
                              hipStream_t stream)
{
  (void)in_sizes; (void)n_in; (void)out_size; (void)ws_size;
  const float* x     = (const float*)d_in[0];
  const float* ln1g  = (const float*)d_in[1];
  const float* ln1b  = (const float*)d_in[2];
  const float* Wq    = (const float*)d_in[3];
  const float* bq    = (const float*)d_in[4];
  const float* offk  = (const float*)d_in[5];
  const float* offkb = (const float*)d_in[6];
  const float* offg  = (const float*)d_in[7];
  const float* offb  = (const float*)d_in[8];
  const float* Woff  = (const float*)d_in[9];
  const float* boff  = (const float*)d_in[10];
  const float* Wk    = (const float*)d_in[11];
  const float* bk    = (const float*)d_in[12];
  const float* Wv    = (const float*)d_in[13];
  const float* bv    = (const float*)d_in[14];
  const float* Wo    = (const float*)d_in[15];
  const float* bo    = (const float*)d_in[16];
  const float* ln2g  = (const float*)d_in[17];
  const float* ln2b  = (const float*)d_in[18];
  const float* W1    = (const float*)d_in[19];
  const float* b1    = (const float*)d_in[20];
  const float* W2    = (const float*)d_in[21];
  const float* b2    = (const float*)d_in[22];

  char* ws = (char*)d_ws;
  // layout (bytes):
  //   [0, 12582912)          X2B bf16 (residual stream after attn)
  //   [25165824, 37748736)   XSB bf16      -+
  //   [37748736, 50331648)   KB bf16        |  reused as HB (50331648 B) in MLP
  //   [50331648, 62914560)   VT bf16        |
  //   [62914560, 75497472)   OB bf16       -+
  //   [75497472, 88080384)   XNB bf16
  //   [88080384, 100663296)  QSB bf16 -> reused as YB after attn
  //   [100663296, 104221440) weights bf16 (incl offk bf16 tail)
  unsigned short* X2B = (unsigned short*)ws;
  unsigned short* XSB = (unsigned short*)(ws + 25165824);
  unsigned short* KB  = (unsigned short*)(ws + 37748736);
  unsigned short* VT  = (unsigned short*)(ws + 50331648);
  unsigned short* OB  = (unsigned short*)(ws + 62914560);
  unsigned short* XNB = (unsigned short*)(ws + 75497472);
  unsigned short* QSB = (unsigned short*)(ws + 88080384);
  unsigned short* YB  = QSB;
  unsigned short* HB  = (unsigned short*)(ws + 25165824);
  unsigned short* WQB = (unsigned short*)(ws + 100663296);
  unsigned short* WKB = WQB + 147456;   // Wk rows 0-383, Wv rows 384-767 (contiguous)
  unsigned short* WOB = WKB + 294912;
  unsigned short* W1B = WOB + 147456;
  unsigned short* W2B = W1B + 589824;
  unsigned short* OKB = W2B + 589824;   // bf16 offk [25][384]

  k_cvt_all<<<1738, 256, 0, stream>>>(Wq, Wk, Wv, Wo, W1, W2, offk, WQB);
  k_ln<0><<<4096, 256, 0, stream>>>(x, nullptr, ln1g, ln1b, XNB);
  k_gemm64<5><<<768, 256, 0, stream>>>(XNB, WQB, bq, nullptr, nullptr, nullptr, nullptr, QSB, nullptr, 3, 384, 384);
  k_offset_sample<<<16384, 64, 0, stream>>>(QSB, XNB, OKB, offkb, offg, offb, Woff, boff, XSB);
  k_gemm64<6><<<1536, 256, 0, stream>>>(XSB, WKB, bk, bv, nullptr, nullptr, nullptr, KB, VT, 6, 768, 384);
  k_attn<<<1536, 256, 0, stream>>>(QSB, KB, VT, OB);
  k_gemm64<2><<<768, 256, 0, stream>>>(OB, WOB, bo, nullptr, x, nullptr, nullptr, X2B, nullptr, 3, 384, 384);
  k_ln<1><<<4096, 256, 0, stream>>>(nullptr, X2B, ln2g, ln2b, YB);
  k_mlp1<<<1536, 256, 0, stream>>>(YB, W1B, b1, HB);
  k_gemm64<7><<<768, 256, 0, stream>>>(HB, W2B, b2, nullptr, nullptr, X2B, (float*)d_out, nullptr, nullptr, 3, 384, 1536);
}

// Round 10
// 235.263 us; speedup vs baseline: 1.3512x; 1.0212x over previous
//
#include <hip/hip_runtime.h>
#include <math.h>

#define DI __device__ __forceinline__

typedef __attribute__((ext_vector_type(8))) short bf16x8;
typedef __attribute__((ext_vector_type(4))) float f32x4;

static constexpr int CC = 384;
// attn scale * log2(e): scores come out of QK^T already in log2 domain
static constexpr float QSCALE = 0.17677669529663687f * 1.4426950408889634f;
static constexpr float INVQS  = 1.0f / QSCALE;

DI unsigned short f2bf(float f){
  unsigned u = __float_as_uint(f);
  u += 0x7FFFu + ((u >> 16) & 1u);
  return (unsigned short)(u >> 16);
}
DI float bf2f(unsigned short u){ return __uint_as_float((unsigned)u << 16); }
DI float lo16(unsigned u){ return __uint_as_float(u << 16); }
DI float hi16(unsigned u){ return __uint_as_float(u & 0xFFFF0000u); }
DI float fexp2(float x){ return __builtin_amdgcn_exp2f(x); }
DI float frcp(float x){ return __builtin_amdgcn_rcpf(x); }
// tanh(z) = 1 - 2/(exp2(z*2*log2e)+1)
DI float tanh_fast(float z){ return 1.f - 2.f*frcp(fexp2(2.8853900817779268f*z) + 1.f); }
DI float gelu_fast(float v){
  float u = v*v;
  float z = 0.7978845608028654f * fmaf(0.044715f*u, v, v);
  return v - v*frcp(fexp2(2.8853900817779268f*z) + 1.f);
}
DI f32x4 mfma16(bf16x8 a, bf16x8 b, f32x4 c){
  return __builtin_amdgcn_mfma_f32_16x16x32_bf16(a, b, c, 0, 0, 0);
}
DI void gload16(const unsigned short* g, unsigned short* l){
  __builtin_amdgcn_global_load_lds(
      (const __attribute__((address_space(1))) unsigned int*)(const void*)g,
      (__attribute__((address_space(3))) unsigned int*)(void*)l, 16, 0, 0);
}
// pack truncated hi16 of (pb, pa) -> (hi:pb, lo:pa)
DI unsigned packbf(float pa, float pb){
  return __builtin_amdgcn_perm(__float_as_uint(pb), __float_as_uint(pa), 0x07060302u);
}

// ---------------- weight fp32 -> bf16 (6 matmul weights + offk), vectorized x4 ---
__global__ __launch_bounds__(256) void k_cvt_all(
    const float* __restrict__ wq, const float* __restrict__ wk,
    const float* __restrict__ wv, const float* __restrict__ wo,
    const float* __restrict__ w1, const float* __restrict__ w2,
    const float* __restrict__ ofk,
    unsigned short* __restrict__ dst)
{
  int i4 = (blockIdx.x*256 + threadIdx.x)*4;
  if (i4 >= 1779072) return;
  const float* src; int off;
  if (i4 < 147456){ src = wq; off = i4; }
  else if (i4 < 294912){ src = wk; off = i4 - 147456; }
  else if (i4 < 442368){ src = wv; off = i4 - 294912; }
  else if (i4 < 589824){ src = wo; off = i4 - 442368; }
  else if (i4 < 1179648){ src = w1; off = i4 - 589824; }
  else if (i4 < 1769472){ src = w2; off = i4 - 1179648; }
  else { src = ofk; off = i4 - 1769472; }
  float4 v = *(const float4*)(src + off);
  uint2 o;
  o.x = ((unsigned)f2bf(v.y) << 16) | f2bf(v.x);
  o.y = ((unsigned)f2bf(v.w) << 16) | f2bf(v.z);
  *(uint2*)(dst + i4) = o;
}

// ---------------- LayerNorm over C=384, one wave/row, 4 rows/block --------------
// BIN=0: f32 input (scalar loads)   BIN=1: bf16 input (vectorized 6 ch/lane)
template<int BIN>
__global__ __launch_bounds__(256) void k_ln(const float* __restrict__ xf,
    const unsigned short* __restrict__ xb,
    const float* __restrict__ g, const float* __restrict__ b,
    unsigned short* __restrict__ outb)
{
  int row = blockIdx.x*4 + (threadIdx.x >> 6);
  int l = threadIdx.x & 63;
  float v[6]; int ch[6];
  if constexpr (BIN){
    int cA = 4*l, cB = 256 + 2*l;
    ch[0]=cA; ch[1]=cA+1; ch[2]=cA+2; ch[3]=cA+3; ch[4]=cB; ch[5]=cB+1;
    const unsigned short* xp = xb + (size_t)row * CC;
    uint2 u2 = *(const uint2*)(xp + cA);
    unsigned u1 = *(const unsigned*)(xp + cB);
    v[0]=lo16(u2.x); v[1]=hi16(u2.x); v[2]=lo16(u2.y); v[3]=hi16(u2.y);
    v[4]=lo16(u1);   v[5]=hi16(u1);
  } else {
    const float* xp = xf + (size_t)row * CC;
#pragma unroll
    for (int p = 0; p < 6; p++){ ch[p] = l + 64*p; v[p] = xp[ch[p]]; }
  }
  float s = 0.f, s2 = 0.f;
#pragma unroll
  for (int p = 0; p < 6; p++){ s += v[p]; s2 += v[p]*v[p]; }
#pragma unroll
  for (int m = 32; m; m >>= 1){ s += __shfl_xor(s, m); s2 += __shfl_xor(s2, m); }
  float mu = s * (1.f/CC);
  float var = s2 * (1.f/CC) - mu*mu;
  float rs = rsqrtf(var + 1e-5f);
  float o[6];
#pragma unroll
  for (int p = 0; p < 6; p++) o[p] = (v[p] - mu) * rs * g[ch[p]] + b[ch[p]];
  unsigned short* op = outb + (size_t)row*CC;
  if constexpr (BIN){
    uint2 st;
    st.x = ((unsigned)f2bf(o[1]) << 16) | f2bf(o[0]);
    st.y = ((unsigned)f2bf(o[3]) << 16) | f2bf(o[2]);
    *(uint2*)(op + ch[0]) = st;
    *(unsigned*)(op + ch[4]) = ((unsigned)f2bf(o[5]) << 16) | f2bf(o[4]);
  } else {
#pragma unroll
    for (int p = 0; p < 6; p++) op[ch[p]] = f2bf(o[p]);
  }
}

// ---------------- 64x128 GEMM, BK=32, dbuf LDS + gload_lds + XCD swizzle ---------
// out(M,N) = A(M,K) @ W(N,K)^T + bias.  1D grid, ntn = N/128 tiles.
// EPI 0: f32   1: bf16   3: bf16 gelu   5: bf16 * QSCALE
// EPI 2: + f32 res -> bf16 out          7: + bf16 res -> f32 out
// EPI 6: fused K|V (N=768): col<384 -> KB; col>=384 -> VT transposed+key-permuted
// VT phys key order (per 64-block): phys = (k6&0x23)|((k6&0xC)<<1)|((k6&0x10)>>2)
// so that swapped-QK^T P registers feed PV's A-fragment directly.
template<int EPI>
__global__ __launch_bounds__(256) void k_gemm64(
    const unsigned short* __restrict__ A, const unsigned short* __restrict__ W,
    const float* __restrict__ bias, const float* __restrict__ bias2,
    const float* __restrict__ res, const unsigned short* __restrict__ resb,
    float* __restrict__ outf, unsigned short* __restrict__ outb,
    unsigned short* __restrict__ outb2, int ntn, int N, int K)
{
  __shared__ unsigned short As[2][2048];   // 64 rows x 32 cols, slot-swizzled
  __shared__ unsigned short Bs[2][4096];   // 128 rows x 32 cols
  int bid = blockIdx.x;
  int cpx = gridDim.x >> 3;
  int id = (bid & 7)*cpx + (bid >> 3);     // XCD-chunk swizzle
  int bn = (id % ntn) * 128;
  int bm = (id / ntn) * 64;
  int t = threadIdx.x;
  int w = t >> 6, l = t & 63;
  int g = l >> 4, ln = l & 15;
  int wm = w >> 1, wn = w & 1;             // wave: 32 rows x 64 cols
  f32x4 acc[2][4];
#pragma unroll
  for (int i = 0; i < 2; i++)
#pragma unroll
    for (int j = 0; j < 4; j++) acc[i][j] = (f32x4){0.f,0.f,0.f,0.f};
  int srow = t >> 2, slot = t & 3;
  int srowB = srow + 64;
  int cb0 = (slot ^ (srow  & 3) ^ ((srow  >> 2) & 3)) * 8;
  int cb1 = (slot ^ (srowB & 3) ^ ((srowB >> 2) & 3)) * 8;
  const unsigned short* Ap  = A + (size_t)(bm + srow)*K + cb0;
  const unsigned short* Wp0 = W + (size_t)(bn + srow)*K + cb0;
  const unsigned short* Wp1 = W + (size_t)(bn + srowB)*K + cb1;
  int NT = K >> 5;
  int wl = w*512;
  gload16(Ap,  &As[0][wl]);
  gload16(Wp0, &Bs[0][wl]);
  gload16(Wp1, &Bs[0][wl + 2048]);
  __syncthreads();
  for (int kt = 0; kt < NT; kt++){
    int cur = kt & 1;
    if (kt + 1 < NT){
      int k0 = (kt + 1) << 5;
      gload16(Ap  + k0, &As[cur ^ 1][wl]);
      gload16(Wp0 + k0, &Bs[cur ^ 1][wl]);
      gload16(Wp1 + k0, &Bs[cur ^ 1][wl + 2048]);
    }
    bf16x8 af[2], bf[4];
#pragma unroll
    for (int mi = 0; mi < 2; mi++){
      int row = wm*32 + mi*16 + ln;
      int sl = g ^ (row & 3) ^ ((row >> 2) & 3);
      af[mi] = *(const bf16x8*)((const char*)As[cur] + row*64 + sl*16);
    }
#pragma unroll
    for (int ni = 0; ni < 4; ni++){
      int row = wn*64 + ni*16 + ln;
      int sl = g ^ (row & 3) ^ ((row >> 2) & 3);
      bf[ni] = *(const bf16x8*)((const char*)Bs[cur] + row*64 + sl*16);
    }
#pragma unroll
    for (int mi = 0; mi < 2; mi++)
#pragma unroll
      for (int ni = 0; ni < 4; ni++)
        acc[mi][ni] = mfma16(af[mi], bf[ni], acc[mi][ni]);
    if (kt + 1 < NT) __syncthreads();
  }
#pragma unroll
  for (int mi = 0; mi < 2; mi++)
#pragma unroll
  for (int ni = 0; ni < 4; ni++){
    int col = bn + wn*64 + ni*16 + ln;
    float bv;
    if constexpr (EPI == 6) bv = col < 384 ? bias[col] : bias2[col - 384];
    else bv = bias[col];
#pragma unroll
    for (int i = 0; i < 4; i++){
      int row = bm + wm*32 + mi*16 + g*4 + i;
      float v = acc[mi][ni][i] + bv;
      if constexpr (EPI == 2){ v += res[(size_t)row*N + col]; outb[(size_t)row*N + col] = f2bf(v); }
      if constexpr (EPI == 7){ v += bf2f(resb[(size_t)row*N + col]); outf[(size_t)row*N + col] = v; }
      if constexpr (EPI == 3) v = gelu_fast(v);
      if constexpr (EPI == 0) outf[(size_t)row*N + col] = v;
      if constexpr (EPI == 1 || EPI == 3) outb[(size_t)row*N + col] = f2bf(v);
      if constexpr (EPI == 5) outb[(size_t)row*N + col] = f2bf(v * QSCALE);
      if constexpr (EPI == 6){
        if (col < 384){
          outb[(size_t)row*384 + col] = f2bf(v);
        } else {
          int c = col - 384;
          int bb = row >> 10, key = row & 1023, h = c >> 5, d = c & 31;
          int k6 = key & 63;
          int phys = (key & ~63) | (k6 & 0x23) | ((k6 & 0xC) << 1) | ((k6 & 0x10) >> 2);
          outb2[(size_t)(((bb*12 + h) << 5) + d)*1024 + phys] = f2bf(v);
        }
      }
    }
  }
}

// ---------------- MLP1: 128x128 GEMM, BK=32, dbuf, gelu-bf16 epilogue ------------
__global__ __launch_bounds__(256) void k_mlp1(
    const unsigned short* __restrict__ A, const unsigned short* __restrict__ W,
    const float* __restrict__ bias, unsigned short* __restrict__ outb)
{
  __shared__ unsigned short As[2][4096];   // 128 x 32, slot-swizzled
  __shared__ unsigned short Bs[2][4096];
  int bid = blockIdx.x;
  int cpx = gridDim.x >> 3;                // 192
  int id = (bid & 7)*cpx + (bid >> 3);     // XCD-chunk swizzle
  int bn = (id % 12) * 128;
  int bm = (id / 12) * 128;
  int t = threadIdx.x;
  int w = t >> 6, l = t & 63;
  int g = l >> 4, ln = l & 15;
  int wm = w >> 1, wn = w & 1;
  f32x4 acc[4][4];
#pragma unroll
  for (int i = 0; i < 4; i++)
#pragma unroll
    for (int j = 0; j < 4; j++) acc[i][j] = (f32x4){0.f,0.f,0.f,0.f};
  int srow0 = t >> 2, slot = t & 3;
  int srow1 = srow0 + 64;
  int cb0 = (slot ^ (srow0 & 3) ^ ((srow0 >> 2) & 3)) * 8;
  int cb1 = (slot ^ (srow1 & 3) ^ ((srow1 >> 2) & 3)) * 8;
  const unsigned short* Ap0 = A + (size_t)(bm + srow0)*384 + cb0;
  const unsigned short* Ap1 = A + (size_t)(bm + srow1)*384 + cb1;
  const unsigned short* Wp0 = W + (size_t)(bn + srow0)*384 + cb0;
  const unsigned short* Wp1 = W + (size_t)(bn + srow1)*384 + cb1;
  int wl = w*512;
  gload16(Ap0, &As[0][wl]);
  gload16(Ap1, &As[0][wl + 2048]);
  gload16(Wp0, &Bs[0][wl]);
  gload16(Wp1, &Bs[0][wl + 2048]);
  __syncthreads();
  for (int kt = 0; kt < 12; kt++){
    int cur = kt & 1;
    if (kt < 11){
      int k0 = (kt + 1) << 5;
      gload16(Ap0 + k0, &As[cur ^ 1][wl]);
      gload16(Ap1 + k0, &As[cur ^ 1][wl + 2048]);
      gload16(Wp0 + k0, &Bs[cur ^ 1][wl]);
      gload16(Wp1 + k0, &Bs[cur ^ 1][wl + 2048]);
    }
    bf16x8 af[4], bf[4];
#pragma unroll
    for (int mi = 0; mi < 4; mi++){
      int row = wm*64 + mi*16 + ln;
      int sl = g ^ (row & 3) ^ ((row >> 2) & 3);
      af[mi] = *(const bf16x8*)((const char*)As[cur] + row*64 + sl*16);
    }
#pragma unroll
    for (int ni = 0; ni < 4; ni++){
      int row = wn*64 + ni*16 + ln;
      int sl = g ^ (row & 3) ^ ((row >> 2) & 3);
      bf[ni] = *(const bf16x8*)((const char*)Bs[cur] + row*64 + sl*16);
    }
#pragma unroll
    for (int mi = 0; mi < 4; mi++)
#pragma unroll
      for (int ni = 0; ni < 4; ni++)
        acc[mi][ni] = mfma16(af[mi], bf[ni], acc[mi][ni]);
    if (kt < 11) __syncthreads();
  }
#pragma unroll
  for (int mi = 0; mi < 4; mi++)
#pragma unroll
  for (int ni = 0; ni < 4; ni++){
    int col = bn + wn*64 + ni*16 + ln;
    float bv = bias[col];
#pragma unroll
    for (int i = 0; i < 4; i++){
      int row = bm + wm*64 + mi*16 + g*4 + i;
      float v = gelu_fast(acc[mi][ni][i] + bv);
      outb[(size_t)row*1536 + col] = f2bf(v);
    }
  }
}

// ---------------- fused offset net + grid sample: one WAVE per pixel -------------
// 8 channels/thread on 48 active lanes; all accesses are 16B uint4
__global__ __launch_bounds__(64) void k_offset_sample(
    const unsigned short* __restrict__ qs, const unsigned short* __restrict__ xnb,
    const unsigned short* __restrict__ okb,  // bf16 offk [25][384]
    const float* __restrict__ offkb,
    const float* __restrict__ offg, const float* __restrict__ offb,
    const float* __restrict__ Woff, const float* __restrict__ boff,
    unsigned short* __restrict__ xsb)
{
  int blk = blockIdx.x;
  int pix = (blk & 7)*2048 + (blk >> 3);   // each XCD gets 2 contiguous images
  int b = pix >> 10, n = pix & 1023;
  int y = n >> 5, x = n & 31;
  int t = threadIdx.x;
  int c8 = (t < 48 ? t : 47) * 8;          // clamped channel base (lanes 48+ idle)
  float act = t < 48 ? 1.f : 0.f;
  const unsigned short* qb = qs + (size_t)b*1024*CC;
  int ry[5], rx[5]; unsigned my[5], mx[5];
#pragma unroll
  for (int k = 0; k < 5; k++){
    int yy = y + k - 2, xx = x + k - 2;
    my[k] = (yy >= 0 && yy < 32) ? 0xFFFFFFFFu : 0u;
    mx[k] = (xx >= 0 && xx < 32) ? 0xFFFFFFFFu : 0u;
    int yc = yy < 0 ? 0 : (yy > 31 ? 31 : yy);
    int xc = xx < 0 ? 0 : (xx > 31 ? 31 : xx);
    ry[k] = yc*32*CC; rx[k] = xc*CC;
  }
  float a[8];
#pragma unroll
  for (int j = 0; j < 8; j++) a[j] = 0.f;
#pragma unroll
  for (int ky = 0; ky < 5; ky++)
#pragma unroll
  for (int kx = 0; kx < 5; kx++){
    int tap = ky*5 + kx;
    unsigned m = my[ky] & mx[kx];
    uint4 q4 = *(const uint4*)(qb + ry[ky] + rx[kx] + c8);
    uint4 w4 = *(const uint4*)(okb + tap*CC + c8);
    q4.x &= m; q4.y &= m; q4.z &= m; q4.w &= m;
    a[0] = fmaf(lo16(q4.x), lo16(w4.x), a[0]);
    a[1] = fmaf(hi16(q4.x), hi16(w4.x), a[1]);
    a[2] = fmaf(lo16(q4.y), lo16(w4.y), a[2]);
    a[3] = fmaf(hi16(q4.y), hi16(w4.y), a[3]);
    a[4] = fmaf(lo16(q4.z), lo16(w4.z), a[4]);
    a[5] = fmaf(hi16(q4.z), hi16(w4.z), a[5]);
    a[6] = fmaf(lo16(q4.w), lo16(w4.w), a[6]);
    a[7] = fmaf(hi16(q4.w), hi16(w4.w), a[7]);
  }
  float4 kbA = *(const float4*)(offkb + c8);
  float4 kbB = *(const float4*)(offkb + c8 + 4);
  float c[8];
  c[0] = act * fmaf(a[0], INVQS, kbA.x);
  c[1] = act * fmaf(a[1], INVQS, kbA.y);
  c[2] = act * fmaf(a[2], INVQS, kbA.z);
  c[3] = act * fmaf(a[3], INVQS, kbA.w);
  c[4] = act * fmaf(a[4], INVQS, kbB.x);
  c[5] = act * fmaf(a[5], INVQS, kbB.y);
  c[6] = act * fmaf(a[6], INVQS, kbB.z);
  c[7] = act * fmaf(a[7], INVQS, kbB.w);
  float s = 0.f, s2 = 0.f;
#pragma unroll
  for (int j = 0; j < 8; j++){ s += c[j]; s2 += c[j]*c[j]; }
#pragma unroll
  for (int m2 = 32; m2; m2 >>= 1){ s += __shfl_xor(s, m2); s2 += __shfl_xor(s2, m2); }
  float mu = s * (1.f/CC);
  float var = s2 * (1.f/CC) - mu*mu;
  float rs = rsqrtf(var + 1e-5f);
  float4 gA = *(const float4*)(offg + c8); float4 gB = *(const float4*)(offg + c8 + 4);
  float4 oA = *(const float4*)(offb + c8); float4 oB = *(const float4*)(offb + c8 + 4);
  float4 wA = *(const float4*)(Woff + c8); float4 wB = *(const float4*)(Woff + c8 + 4);
  float4 wC = *(const float4*)(Woff + CC + c8); float4 wD = *(const float4*)(Woff + CC + c8 + 4);
  float gg[8] = {gA.x,gA.y,gA.z,gA.w,gB.x,gB.y,gB.z,gB.w};
  float bb[8] = {oA.x,oA.y,oA.z,oA.w,oB.x,oB.y,oB.z,oB.w};
  float w0[8] = {wA.x,wA.y,wA.z,wA.w,wB.x,wB.y,wB.z,wB.w};
  float w1[8] = {wC.x,wC.y,wC.z,wC.w,wD.x,wD.y,wD.z,wD.w};
  float p0 = 0.f, p1 = 0.f;
#pragma unroll
  for (int j = 0; j < 8; j++){
    float v = gelu_fast((c[j] - mu)*rs*gg[j] + bb[j]) * act;
    p0 = fmaf(v, w0[j], p0);
    p1 = fmaf(v, w1[j], p1);
  }
#pragma unroll
  for (int m2 = 32; m2; m2 >>= 1){ p0 += __shfl_xor(p0, m2); p1 += __shfl_xor(p1, m2); }
  float offy = tanh_fast(p0 + boff[0]) * 0.125f;
  float offx = tanh_fast(p1 + boff[1]) * 0.125f;
  float py = ((y + 0.5f)/16.f - 1.f + offy + 1.f) * 0.5f * 31.f;
  float px = ((x + 0.5f)/16.f - 1.f + offx + 1.f) * 0.5f * 31.f;
  float y0f = floorf(py), x0f = floorf(px);
  float wy = py - y0f, wx = px - x0f;
  int y0 = (int)y0f, x0 = (int)x0f;
  y0 = y0 < 0 ? 0 : (y0 > 31 ? 31 : y0);
  x0 = x0 < 0 ? 0 : (x0 > 31 ? 31 : x0);
  int y1 = y0 + 1 > 31 ? 31 : y0 + 1;
  int x1 = x0 + 1 > 31 ? 31 : x0 + 1;
  const unsigned short* s00 = xnb + (size_t)(b*1024 + y0*32 + x0)*CC + c8;
  const unsigned short* s01 = xnb + (size_t)(b*1024 + y0*32 + x1)*CC + c8;
  const unsigned short* s10 = xnb + (size_t)(b*1024 + y1*32 + x0)*CC + c8;
  const unsigned short* s11 = xnb + (size_t)(b*1024 + y1*32 + x1)*CC + c8;
  float w00 = (1.f-wy)*(1.f-wx), w01 = (1.f-wy)*wx, w10 = wy*(1.f-wx), w11 = wy*wx;
  uint4 A0 = *(const uint4*)s00;
  uint4 A1 = *(const uint4*)s01;
  uint4 A2 = *(const uint4*)s10;
  uint4 A3 = *(const uint4*)s11;
  if (t < 48){
    float r[8];
    r[0] = w00*lo16(A0.x) + w01*lo16(A1.x) + w10*lo16(A2.x) + w11*lo16(A3.x);
    r[1] = w00*hi16(A0.x) + w01*hi16(A1.x) + w10*hi16(A2.x) + w11*hi16(A3.x);
    r[2] = w00*lo16(A0.y) + w01*lo16(A1.y) + w10*lo16(A2.y) + w11*lo16(A3.y);
    r[3] = w00*hi16(A0.y) + w01*hi16(A1.y) + w10*hi16(A2.y) + w11*hi16(A3.y);
    r[4] = w00*lo16(A0.z) + w01*lo16(A1.z) + w10*lo16(A2.z) + w11*lo16(A3.z);
    r[5] = w00*hi16(A0.z) + w01*hi16(A1.z) + w10*hi16(A2.z) + w11*hi16(A3.z);
    r[6] = w00*lo16(A0.w) + w01*lo16(A1.w) + w10*lo16(A2.w) + w11*lo16(A3.w);
    r[7] = w00*hi16(A0.w) + w01*hi16(A1.w) + w10*hi16(A2.w) + w11*hi16(A3.w);
    uint4 st;
    st.x = ((unsigned)f2bf(r[1]) << 16) | f2bf(r[0]);
    st.y = ((unsigned)f2bf(r[3]) << 16) | f2bf(r[2]);
    st.z = ((unsigned)f2bf(r[5]) << 16) | f2bf(r[4]);
    st.w = ((unsigned)f2bf(r[7]) << 16) | f2bf(r[6]);
    *(uint4*)(xsb + (size_t)(b*1024 + n)*CC + c8) = st;
  }
}

// ---------------- attention: swapped QK^T, in-register P, dbuf K/V ---------------
// qs: bf16 Q scaled by QSCALE; kb row-major; vt: V^T [b][h][d][1024] key-permuted
// S^T = mfma(K, Q): lane holds P for q-row ln, keys nt*16+g*4+i -> packs straight
// into PV's A-fragment thanks to the VT key permutation. No P through LDS.
__global__ __launch_bounds__(256) void k_attn(
    const unsigned short* __restrict__ qs, const unsigned short* __restrict__ kb,
    const unsigned short* __restrict__ vt, unsigned short* __restrict__ ob)
{
  __shared__ unsigned short Ks[2][64][40];   // [buf][key][dim]
  __shared__ unsigned short Vs[2][32][72];   // [buf][dim][physkey]
  int blk = blockIdx.x;
  int sw = (blk & 7)*192 + (blk >> 3);    // XCD-grouped
  int qt = sw & 7, h = (sw >> 3) % 12, b = sw / 96;
  int t = threadIdx.x;
  int w = t >> 6, l = t & 63;
  int g = l >> 4, ln = l & 15;
  int q0 = qt*128 + w*32;
  bf16x8 qa[2];
#pragma unroll
  for (int mi = 0; mi < 2; mi++)
    qa[mi] = *(const bf16x8*)&qs[(size_t)(b*1024 + q0 + mi*16 + ln)*CC + h*32 + g*8];
  bf16x8 vones;
#pragma unroll
  for (int j = 0; j < 8; j++) vones[j] = (short)0x3F80;   // bf16 1.0
  f32x4 z = {0.f,0.f,0.f,0.f};
  f32x4 oacc[2][2]; oacc[0][0]=z; oacc[0][1]=z; oacc[1][0]=z; oacc[1][1]=z;
  f32x4 lacc[2]; lacc[0]=z; lacc[1]=z;    // row-sum of P via ones-MFMA
  int krow = t >> 2, kc = (t & 3)*8;
  int vdim = t >> 3, vc = (t & 7)*8;
  const unsigned short* kptr = kb + (size_t)(b*1024 + krow)*CC + h*32 + kc;
  const unsigned short* vptr = vt + (size_t)((b*12 + h)*32 + vdim)*1024 + vc;
  {
    uint4 kr = *(const uint4*)kptr;
    uint4 vr = *(const uint4*)vptr;
    *(uint4*)&Ks[0][krow][kc] = kr;
    *(uint4*)&Vs[0][vdim][vc] = vr;
  }
  __syncthreads();
  for (int kt = 0; kt < 16; kt++){
    int cur = kt & 1;
    uint4 kr2, vr2;
    if (kt < 15){
      int k0 = (kt + 1)*64;
      kr2 = *(const uint4*)(kptr + (size_t)k0*CC);
      vr2 = *(const uint4*)(vptr + k0);
    }
    bf16x8 kf[4];
#pragma unroll
    for (int nt = 0; nt < 4; nt++) kf[nt] = *(const bf16x8*)&Ks[cur][nt*16 + ln][g*8];
    f32x4 st[2][4];
    __builtin_amdgcn_s_setprio(1);
#pragma unroll
    for (int mi = 0; mi < 2; mi++)
#pragma unroll
      for (int nt = 0; nt < 4; nt++) st[mi][nt] = mfma16(kf[nt], qa[mi], z);  // S^T
    __builtin_amdgcn_s_setprio(0);
    // P = exp2(S^T), packed in-register into PV A-fragments
    bf16x8 pa[2][2];
#pragma unroll
    for (int mi = 0; mi < 2; mi++){
#pragma unroll
      for (int k2 = 0; k2 < 2; k2++){
        float e0 = fexp2(st[mi][2*k2][0]),   e1 = fexp2(st[mi][2*k2][1]);
        float e2 = fexp2(st[mi][2*k2][2]),   e3 = fexp2(st[mi][2*k2][3]);
        float f0 = fexp2(st[mi][2*k2+1][0]), f1 = fexp2(st[mi][2*k2+1][1]);
        float f2 = fexp2(st[mi][2*k2+1][2]), f3 = fexp2(st[mi][2*k2+1][3]);
        uint4 pw;
        pw.x = packbf(e0, e1);
        pw.y = packbf(e2, e3);
        pw.z = packbf(f0, f1);
        pw.w = packbf(f2, f3);
        pa[mi][k2] = *(bf16x8*)&pw;
      }
    }
    __builtin_amdgcn_s_setprio(1);
#pragma unroll
    for (int k2 = 0; k2 < 2; k2++){
      bf16x8 va[2];
#pragma unroll
      for (int d2 = 0; d2 < 2; d2++) va[d2] = *(const bf16x8*)&Vs[cur][d2*16 + ln][k2*32 + g*8];
#pragma unroll
      for (int mi = 0; mi < 2; mi++){
#pragma unroll
        for (int d2 = 0; d2 < 2; d2++) oacc[mi][d2] = mfma16(pa[mi][k2], va[d2], oacc[mi][d2]);
        lacc[mi] = mfma16(pa[mi][k2], vones, lacc[mi]);
      }
    }
    __builtin_amdgcn_s_setprio(0);
    if (kt < 15){
      *(uint4*)&Ks[cur ^ 1][krow][kc] = kr2;
      *(uint4*)&Vs[cur ^ 1][vdim][vc] = vr2;
      __syncthreads();
    }
  }
  // lacc[mi][i] = full row-sum of bf16 P for q-row mi*16+g*4+i (matches oacc rows)
  float rinv[2][4];
#pragma unroll
  for (int mi = 0; mi < 2; mi++)
#pragma unroll
    for (int i = 0; i < 4; i++) rinv[mi][i] = frcp(lacc[mi][i]);
#pragma unroll
  for (int mi = 0; mi < 2; mi++)
#pragma unroll
  for (int d2 = 0; d2 < 2; d2++)
#pragma unroll
  for (int i = 0; i < 4; i++){
    float v = oacc[mi][d2][i] * rinv[mi][i];
    int row = q0 + mi*16 + g*4 + i;
    ob[(size_t)(b*1024 + row)*CC + h*32 + d2*16 + ln] = f2bf(v);
  }
}

extern "C" void kernel_launch(void* const* d_in, const int* in_sizes, int n_in,
                              void* d_out, int out_size, void* d_ws, size_t ws_size,
                              hipStream_t stream)
{
  (void)in_sizes; (void)n_in; (void)out_size; (void)ws_size;
  const float* x     = (const float*)d_in[0];
  const float* ln1g  = (const float*)d_in[1];
  const float* ln1b  = (const float*)d_in[2];
  const float* Wq    = (const float*)d_in[3];
  const float* bq    = (const float*)d_in[4];
  const float* offk  = (const float*)d_in[5];
  const float* offkb = (const float*)d_in[6];
  const float* offg  = (const float*)d_in[7];
  const float* offb  = (const float*)d_in[8];
  const float* Woff  = (const float*)d_in[9];
  const float* boff  = (const float*)d_in[10];
  const float* Wk    = (const float*)d_in[11];
  const float* bk    = (const float*)d_in[12];
  const float* Wv    = (const float*)d_in[13];
  const float* bv    = (const float*)d_in[14];
  const float* Wo    = (const float*)d_in[15];
  const float* bo    = (const float*)d_in[16];
  const float* ln2g  = (const float*)d_in[17];
  const float* ln2b  = (const float*)d_in[18];
  const float* W1    = (const float*)d_in[19];
  const float* b1    = (const float*)d_in[20];
  const float* W2    = (const float*)d_in[21];
  const float* b2    = (const float*)d_in[22];

  char* ws = (char*)d_ws;
  unsigned short* X2B = (unsigned short*)ws;
  unsigned short* XSB = (unsigned short*)(ws + 25165824);
  unsigned short* KB  = (unsigned short*)(ws + 37748736);
  unsigned short* VT  = (unsigned short*)(ws + 50331648);
  unsigned short* OB  = (unsigned short*)(ws + 62914560);
  unsigned short* XNB = (unsigned short*)(ws + 75497472);
  unsigned short* QSB = (unsigned short*)(ws + 88080384);
  unsigned short* YB  = QSB;
  unsigned short* HB  = (unsigned short*)(ws + 25165824);
  unsigned short* WQB = (unsigned short*)(ws + 100663296);
  unsigned short* WKB = WQB + 147456;   // Wk rows 0-383, Wv rows 384-767 (contiguous)
  unsigned short* WOB = WKB + 294912;
  unsigned short* W1B = WOB + 147456;
  unsigned short* W2B = W1B + 589824;
  unsigned short* OKB = W2B + 589824;   // bf16 offk [25][384]

  k_cvt_all<<<1738, 256, 0, stream>>>(Wq, Wk, Wv, Wo, W1, W2, offk, WQB);
  k_ln<0><<<4096, 256, 0, stream>>>(x, nullptr, ln1g, ln1b, XNB);
  k_gemm64<5><<<768, 256, 0, stream>>>(XNB, WQB, bq, nullptr, nullptr, nullptr, nullptr, QSB, nullptr, 3, 384, 384);
  k_offset_sample<<<16384, 64, 0, stream>>>(QSB, XNB, OKB, offkb, offg, offb, Woff, boff, XSB);
  k_gemm64<6><<<1536, 256, 0, stream>>>(XSB, WKB, bk, bv, nullptr, nullptr, nullptr, KB, VT, 6, 768, 384);
  k_attn<<<1536, 256, 0, stream>>>(QSB, KB, VT, OB);
  k_gemm64<2><<<768, 256, 0, stream>>>(OB, WOB, bo, nullptr, x, nullptr, nullptr, X2B, nullptr, 3, 384, 384);
  k_ln<1><<<4096, 256, 0, stream>>>(nullptr, X2B, ln2g, ln2b, YB);
  k_mlp1<<<1536, 256, 0, stream>>>(YB, W1B, b1, HB);
  k_gemm64<7><<<768, 256, 0, stream>>>(HB, W2B, b2, nullptr, nullptr, X2B, (float*)d_out, nullptr, nullptr, 3, 384, 1536);
}

// Round 11
// 222.955 us; speedup vs baseline: 1.4258x; 1.0552x over previous
//
#include <hip/hip_runtime.h>
#include <math.h>

#define DI __device__ __forceinline__

typedef __attribute__((ext_vector_type(8))) short bf16x8;
typedef __attribute__((ext_vector_type(4))) float f32x4;

static constexpr int CC = 384;
// attn scale * log2(e): scores come out of QK^T already in log2 domain
static constexpr float QSCALE = 0.17677669529663687f * 1.4426950408889634f;
static constexpr float INVQS  = 1.0f / QSCALE;

DI unsigned short f2bf(float f){
  unsigned u = __float_as_uint(f);
  u += 0x7FFFu + ((u >> 16) & 1u);
  return (unsigned short)(u >> 16);
}
DI float bf2f(unsigned short u){ return __uint_as_float((unsigned)u << 16); }
DI float lo16(unsigned u){ return __uint_as_float(u << 16); }
DI float hi16(unsigned u){ return __uint_as_float(u & 0xFFFF0000u); }
DI float fexp2(float x){ return __builtin_amdgcn_exp2f(x); }
DI float frcp(float x){ return __builtin_amdgcn_rcpf(x); }
// tanh(z) = 1 - 2/(exp2(z*2*log2e)+1)
DI float tanh_fast(float z){ return 1.f - 2.f*frcp(fexp2(2.8853900817779268f*z) + 1.f); }
DI float gelu_fast(float v){
  float u = v*v;
  float z = 0.7978845608028654f * fmaf(0.044715f*u, v, v);
  return v - v*frcp(fexp2(2.8853900817779268f*z) + 1.f);
}
DI f32x4 mfma16(bf16x8 a, bf16x8 b, f32x4 c){
  return __builtin_amdgcn_mfma_f32_16x16x32_bf16(a, b, c, 0, 0, 0);
}
DI void gload16(const unsigned short* g, unsigned short* l){
  __builtin_amdgcn_global_load_lds(
      (const __attribute__((address_space(1))) unsigned int*)(const void*)g,
      (__attribute__((address_space(3))) unsigned int*)(void*)l, 16, 0, 0);
}
// pack truncated hi16 of (pb, pa) -> (hi:pb, lo:pa)
DI unsigned packbf(float pa, float pb){
  return __builtin_amdgcn_perm(__float_as_uint(pb), __float_as_uint(pa), 0x07060302u);
}

// ---------------- weight fp32 -> bf16 (6 matmul weights + offk), vectorized x4 ---
__global__ __launch_bounds__(256) void k_cvt_all(
    const float* __restrict__ wq, const float* __restrict__ wk,
    const float* __restrict__ wv, const float* __restrict__ wo,
    const float* __restrict__ w1, const float* __restrict__ w2,
    const float* __restrict__ ofk,
    unsigned short* __restrict__ dst)
{
  int i4 = (blockIdx.x*256 + threadIdx.x)*4;
  if (i4 >= 1779072) return;
  const float* src; int off;
  if (i4 < 147456){ src = wq; off = i4; }
  else if (i4 < 294912){ src = wk; off = i4 - 147456; }
  else if (i4 < 442368){ src = wv; off = i4 - 294912; }
  else if (i4 < 589824){ src = wo; off = i4 - 442368; }
  else if (i4 < 1179648){ src = w1; off = i4 - 589824; }
  else if (i4 < 1769472){ src = w2; off = i4 - 1179648; }
  else { src = ofk; off = i4 - 1769472; }
  float4 v = *(const float4*)(src + off);
  uint2 o;
  o.x = ((unsigned)f2bf(v.y) << 16) | f2bf(v.x);
  o.y = ((unsigned)f2bf(v.w) << 16) | f2bf(v.z);
  *(uint2*)(dst + i4) = o;
}

// ---------------- LayerNorm over C=384, one wave/row, 4 rows/block --------------
// BIN=0: f32 input (scalar loads)   BIN=1: bf16 input (vectorized 6 ch/lane)
template<int BIN>
__global__ __launch_bounds__(256) void k_ln(const float* __restrict__ xf,
    const unsigned short* __restrict__ xb,
    const float* __restrict__ g, const float* __restrict__ b,
    unsigned short* __restrict__ outb)
{
  int row = blockIdx.x*4 + (threadIdx.x >> 6);
  int l = threadIdx.x & 63;
  float v[6]; int ch[6];
  if constexpr (BIN){
    int cA = 4*l, cB = 256 + 2*l;
    ch[0]=cA; ch[1]=cA+1; ch[2]=cA+2; ch[3]=cA+3; ch[4]=cB; ch[5]=cB+1;
    const unsigned short* xp = xb + (size_t)row * CC;
    uint2 u2 = *(const uint2*)(xp + cA);
    unsigned u1 = *(const unsigned*)(xp + cB);
    v[0]=lo16(u2.x); v[1]=hi16(u2.x); v[2]=lo16(u2.y); v[3]=hi16(u2.y);
    v[4]=lo16(u1);   v[5]=hi16(u1);
  } else {
    const float* xp = xf + (size_t)row * CC;
#pragma unroll
    for (int p = 0; p < 6; p++){ ch[p] = l + 64*p; v[p] = xp[ch[p]]; }
  }
  float s = 0.f, s2 = 0.f;
#pragma unroll
  for (int p = 0; p < 6; p++){ s += v[p]; s2 += v[p]*v[p]; }
#pragma unroll
  for (int m = 32; m; m >>= 1){ s += __shfl_xor(s, m); s2 += __shfl_xor(s2, m); }
  float mu = s * (1.f/CC);
  float var = s2 * (1.f/CC) - mu*mu;
  float rs = rsqrtf(var + 1e-5f);
  float o[6];
#pragma unroll
  for (int p = 0; p < 6; p++) o[p] = (v[p] - mu) * rs * g[ch[p]] + b[ch[p]];
  unsigned short* op = outb + (size_t)row*CC;
  if constexpr (BIN){
    uint2 st;
    st.x = ((unsigned)f2bf(o[1]) << 16) | f2bf(o[0]);
    st.y = ((unsigned)f2bf(o[3]) << 16) | f2bf(o[2]);
    *(uint2*)(op + ch[0]) = st;
    *(unsigned*)(op + ch[4]) = ((unsigned)f2bf(o[5]) << 16) | f2bf(o[4]);
  } else {
#pragma unroll
    for (int p = 0; p < 6; p++) op[ch[p]] = f2bf(o[p]);
  }
}

// ---------------- 64x128 GEMM, BK=32, dbuf LDS + gload_lds + XCD swizzle ---------
// out(M,N) = A(M,K) @ W(N,K)^T + bias.  1D grid, ntn = N/128 tiles.
// EPI 0: f32   1: bf16   3: bf16 gelu   5: bf16 * QSCALE
// EPI 2: + f32 res -> bf16 out          7: + bf16 res -> f32 out
// EPI 6: fused K|V (N=768): col<384 -> KB; col>=384 -> VT transposed+key-permuted
// VT phys key order (per 64-block): phys = (k6&0x23)|((k6&0xC)<<1)|((k6&0x10)>>2)
// so that swapped-QK^T P registers feed PV's A-fragment directly.
template<int EPI>
__global__ __launch_bounds__(256) void k_gemm64(
    const unsigned short* __restrict__ A, const unsigned short* __restrict__ W,
    const float* __restrict__ bias, const float* __restrict__ bias2,
    const float* __restrict__ res, const unsigned short* __restrict__ resb,
    float* __restrict__ outf, unsigned short* __restrict__ outb,
    unsigned short* __restrict__ outb2, int ntn, int N, int K)
{
  __shared__ unsigned short As[2][2048];   // 64 rows x 32 cols, slot-swizzled
  __shared__ unsigned short Bs[2][4096];   // 128 rows x 32 cols
  int bid = blockIdx.x;
  int cpx = gridDim.x >> 3;
  int id = (bid & 7)*cpx + (bid >> 3);     // XCD-chunk swizzle
  int bn = (id % ntn) * 128;
  int bm = (id / ntn) * 64;
  int t = threadIdx.x;
  int w = t >> 6, l = t & 63;
  int g = l >> 4, ln = l & 15;
  int wm = w >> 1, wn = w & 1;             // wave: 32 rows x 64 cols
  f32x4 acc[2][4];
#pragma unroll
  for (int i = 0; i < 2; i++)
#pragma unroll
    for (int j = 0; j < 4; j++) acc[i][j] = (f32x4){0.f,0.f,0.f,0.f};
  int srow = t >> 2, slot = t & 3;
  int srowB = srow + 64;
  int cb0 = (slot ^ (srow  & 3) ^ ((srow  >> 2) & 3)) * 8;
  int cb1 = (slot ^ (srowB & 3) ^ ((srowB >> 2) & 3)) * 8;
  const unsigned short* Ap  = A + (size_t)(bm + srow)*K + cb0;
  const unsigned short* Wp0 = W + (size_t)(bn + srow)*K + cb0;
  const unsigned short* Wp1 = W + (size_t)(bn + srowB)*K + cb1;
  int NT = K >> 5;
  int wl = w*512;
  gload16(Ap,  &As[0][wl]);
  gload16(Wp0, &Bs[0][wl]);
  gload16(Wp1, &Bs[0][wl + 2048]);
  __syncthreads();
  for (int kt = 0; kt < NT; kt++){
    int cur = kt & 1;
    if (kt + 1 < NT){
      int k0 = (kt + 1) << 5;
      gload16(Ap  + k0, &As[cur ^ 1][wl]);
      gload16(Wp0 + k0, &Bs[cur ^ 1][wl]);
      gload16(Wp1 + k0, &Bs[cur ^ 1][wl + 2048]);
    }
    bf16x8 af[2], bf[4];
#pragma unroll
    for (int mi = 0; mi < 2; mi++){
      int row = wm*32 + mi*16 + ln;
      int sl = g ^ (row & 3) ^ ((row >> 2) & 3);
      af[mi] = *(const bf16x8*)((const char*)As[cur] + row*64 + sl*16);
    }
#pragma unroll
    for (int ni = 0; ni < 4; ni++){
      int row = wn*64 + ni*16 + ln;
      int sl = g ^ (row & 3) ^ ((row >> 2) & 3);
      bf[ni] = *(const bf16x8*)((const char*)Bs[cur] + row*64 + sl*16);
    }
#pragma unroll
    for (int mi = 0; mi < 2; mi++)
#pragma unroll
      for (int ni = 0; ni < 4; ni++)
        acc[mi][ni] = mfma16(af[mi], bf[ni], acc[mi][ni]);
    if (kt + 1 < NT) __syncthreads();
  }
#pragma unroll
  for (int mi = 0; mi < 2; mi++)
#pragma unroll
  for (int ni = 0; ni < 4; ni++){
    int col = bn + wn*64 + ni*16 + ln;
    float bv;
    if constexpr (EPI == 6) bv = col < 384 ? bias[col] : bias2[col - 384];
    else bv = bias[col];
#pragma unroll
    for (int i = 0; i < 4; i++){
      int row = bm + wm*32 + mi*16 + g*4 + i;
      float v = acc[mi][ni][i] + bv;
      if constexpr (EPI == 2){ v += res[(size_t)row*N + col]; outb[(size_t)row*N + col] = f2bf(v); }
      if constexpr (EPI == 7){ v += bf2f(resb[(size_t)row*N + col]); outf[(size_t)row*N + col] = v; }
      if constexpr (EPI == 3) v = gelu_fast(v);
      if constexpr (EPI == 0) outf[(size_t)row*N + col] = v;
      if constexpr (EPI == 1 || EPI == 3) outb[(size_t)row*N + col] = f2bf(v);
      if constexpr (EPI == 5) outb[(size_t)row*N + col] = f2bf(v * QSCALE);
      if constexpr (EPI == 6){
        if (col < 384){
          outb[(size_t)row*384 + col] = f2bf(v);
        } else {
          int c = col - 384;
          int bb = row >> 10, key = row & 1023, h = c >> 5, d = c & 31;
          int k6 = key & 63;
          int phys = (key & ~63) | (k6 & 0x23) | ((k6 & 0xC) << 1) | ((k6 & 0x10) >> 2);
          outb2[(size_t)(((bb*12 + h) << 5) + d)*1024 + phys] = f2bf(v);
        }
      }
    }
  }
}

// ---------------- MLP1: 128x128 GEMM, BK=32, dbuf, gelu-bf16 epilogue ------------
__global__ __launch_bounds__(256) void k_mlp1(
    const unsigned short* __restrict__ A, const unsigned short* __restrict__ W,
    const float* __restrict__ bias, unsigned short* __restrict__ outb)
{
  __shared__ unsigned short As[2][4096];   // 128 x 32, slot-swizzled
  __shared__ unsigned short Bs[2][4096];
  int bid = blockIdx.x;
  int cpx = gridDim.x >> 3;                // 192
  int id = (bid & 7)*cpx + (bid >> 3);     // XCD-chunk swizzle
  int bn = (id % 12) * 128;
  int bm = (id / 12) * 128;
  int t = threadIdx.x;
  int w = t >> 6, l = t & 63;
  int g = l >> 4, ln = l & 15;
  int wm = w >> 1, wn = w & 1;
  f32x4 acc[4][4];
#pragma unroll
  for (int i = 0; i < 4; i++)
#pragma unroll
    for (int j = 0; j < 4; j++) acc[i][j] = (f32x4){0.f,0.f,0.f,0.f};
  int srow0 = t >> 2, slot = t & 3;
  int srow1 = srow0 + 64;
  int cb0 = (slot ^ (srow0 & 3) ^ ((srow0 >> 2) & 3)) * 8;
  int cb1 = (slot ^ (srow1 & 3) ^ ((srow1 >> 2) & 3)) * 8;
  const unsigned short* Ap0 = A + (size_t)(bm + srow0)*384 + cb0;
  const unsigned short* Ap1 = A + (size_t)(bm + srow1)*384 + cb1;
  const unsigned short* Wp0 = W + (size_t)(bn + srow0)*384 + cb0;
  const unsigned short* Wp1 = W + (size_t)(bn + srow1)*384 + cb1;
  int wl = w*512;
  gload16(Ap0, &As[0][wl]);
  gload16(Ap1, &As[0][wl + 2048]);
  gload16(Wp0, &Bs[0][wl]);
  gload16(Wp1, &Bs[0][wl + 2048]);
  __syncthreads();
  for (int kt = 0; kt < 12; kt++){
    int cur = kt & 1;
    if (kt < 11){
      int k0 = (kt + 1) << 5;
      gload16(Ap0 + k0, &As[cur ^ 1][wl]);
      gload16(Ap1 + k0, &As[cur ^ 1][wl + 2048]);
      gload16(Wp0 + k0, &Bs[cur ^ 1][wl]);
      gload16(Wp1 + k0, &Bs[cur ^ 1][wl + 2048]);
    }
    bf16x8 af[4], bf[4];
#pragma unroll
    for (int mi = 0; mi < 4; mi++){
      int row = wm*64 + mi*16 + ln;
      int sl = g ^ (row & 3) ^ ((row >> 2) & 3);
      af[mi] = *(const bf16x8*)((const char*)As[cur] + row*64 + sl*16);
    }
#pragma unroll
    for (int ni = 0; ni < 4; ni++){
      int row = wn*64 + ni*16 + ln;
      int sl = g ^ (row & 3) ^ ((row >> 2) & 3);
      bf[ni] = *(const bf16x8*)((const char*)Bs[cur] + row*64 + sl*16);
    }
#pragma unroll
    for (int mi = 0; mi < 4; mi++)
#pragma unroll
      for (int ni = 0; ni < 4; ni++)
        acc[mi][ni] = mfma16(af[mi], bf[ni], acc[mi][ni]);
    if (kt < 11) __syncthreads();
  }
#pragma unroll
  for (int mi = 0; mi < 4; mi++)
#pragma unroll
  for (int ni = 0; ni < 4; ni++){
    int col = bn + wn*64 + ni*16 + ln;
    float bv = bias[col];
#pragma unroll
    for (int i = 0; i < 4; i++){
      int row = bm + wm*64 + mi*16 + g*4 + i;
      float v = gelu_fast(acc[mi][ni][i] + bv);
      outb[(size_t)row*1536 + col] = f2bf(v);
    }
  }
}

// ---------------- MLP2: 64x128 GEMM, BK=64, dbuf, +bf16 res -> f32 out -----------
// out(16384,384) = H(16384,1536) @ W2(384,1536)^T + b2 + X2B
__global__ __launch_bounds__(256) void k_mlp2(
    const unsigned short* __restrict__ A, const unsigned short* __restrict__ W,
    const float* __restrict__ bias, const unsigned short* __restrict__ resb,
    float* __restrict__ outf)
{
  __shared__ unsigned short As[2][4096];   // 64 rows x 64 cols, slot-swizzled (8 slots)
  __shared__ unsigned short Bs[2][8192];   // 128 rows x 64 cols
  int bid = blockIdx.x;
  int cpx = gridDim.x >> 3;                // 96
  int id = (bid & 7)*cpx + (bid >> 3);     // XCD-chunk swizzle
  int bn = (id % 3) * 128;
  int bm = (id / 3) * 64;
  int t = threadIdx.x;
  int w = t >> 6, l = t & 63;
  int g = l >> 4, ln = l & 15;
  int wm = w >> 1, wn = w & 1;             // wave: 32 rows x 64 cols
  f32x4 acc[2][4];
#pragma unroll
  for (int i = 0; i < 2; i++)
#pragma unroll
    for (int j = 0; j < 4; j++) acc[i][j] = (f32x4){0.f,0.f,0.f,0.f};
  // staging round j covers LDS shorts [j*2048, j*2048+2048): row = j*32 + (t>>3), slot = t&7
  // src col slot = (t&7) ^ (row&7) = (t&7) ^ ((t>>3)&7)  (j*32 = 0 mod 8)
  int srcoff = ((t & 7) ^ ((t >> 3) & 7)) * 8;
  int srowA = t >> 3;                       // + j*32
  const unsigned short* Ap0 = A + (size_t)(bm + srowA)*1536 + srcoff;
  const unsigned short* Ap1 = A + (size_t)(bm + 32 + srowA)*1536 + srcoff;
  const unsigned short* Wp0 = W + (size_t)(bn + srowA)*1536 + srcoff;
  const unsigned short* Wp1 = W + (size_t)(bn + 32 + srowA)*1536 + srcoff;
  const unsigned short* Wp2 = W + (size_t)(bn + 64 + srowA)*1536 + srcoff;
  const unsigned short* Wp3 = W + (size_t)(bn + 96 + srowA)*1536 + srcoff;
  int wl = w*512;
  gload16(Ap0, &As[0][wl]);
  gload16(Ap1, &As[0][wl + 2048]);
  gload16(Wp0, &Bs[0][wl]);
  gload16(Wp1, &Bs[0][wl + 2048]);
  gload16(Wp2, &Bs[0][wl + 4096]);
  gload16(Wp3, &Bs[0][wl + 6144]);
  __syncthreads();
  for (int kt = 0; kt < 24; kt++){
    int cur = kt & 1;
    if (kt < 23){
      int k0 = (kt + 1) << 6;
      gload16(Ap0 + k0, &As[cur ^ 1][wl]);
      gload16(Ap1 + k0, &As[cur ^ 1][wl + 2048]);
      gload16(Wp0 + k0, &Bs[cur ^ 1][wl]);
      gload16(Wp1 + k0, &Bs[cur ^ 1][wl + 2048]);
      gload16(Wp2 + k0, &Bs[cur ^ 1][wl + 4096]);
      gload16(Wp3 + k0, &Bs[cur ^ 1][wl + 6144]);
    }
#pragma unroll
    for (int kk = 0; kk < 2; kk++){
      bf16x8 af[2], bf[4];
#pragma unroll
      for (int mi = 0; mi < 2; mi++){
        int row = wm*32 + mi*16 + ln;
        int sl = (kk*4 + g) ^ (row & 7);
        af[mi] = *(const bf16x8*)((const char*)As[cur] + row*128 + sl*16);
      }
#pragma unroll
      for (int ni = 0; ni < 4; ni++){
        int row = wn*64 + ni*16 + ln;
        int sl = (kk*4 + g) ^ (row & 7);
        bf[ni] = *(const bf16x8*)((const char*)Bs[cur] + row*128 + sl*16);
      }
#pragma unroll
      for (int mi = 0; mi < 2; mi++)
#pragma unroll
        for (int ni = 0; ni < 4; ni++)
          acc[mi][ni] = mfma16(af[mi], bf[ni], acc[mi][ni]);
    }
    if (kt < 23) __syncthreads();
  }
#pragma unroll
  for (int mi = 0; mi < 2; mi++)
#pragma unroll
  for (int ni = 0; ni < 4; ni++){
    int col = bn + wn*64 + ni*16 + ln;
    float bv = bias[col];
#pragma unroll
    for (int i = 0; i < 4; i++){
      int row = bm + wm*32 + mi*16 + g*4 + i;
      float v = acc[mi][ni][i] + bv + bf2f(resb[(size_t)row*384 + col]);
      outf[(size_t)row*384 + col] = v;
    }
  }
}

// ---------------- fused offset net + grid sample: one WAVE per pixel -------------
// 8 channels/thread on 48 active lanes; all accesses are 16B uint4
__global__ __launch_bounds__(64) void k_offset_sample(
    const unsigned short* __restrict__ qs, const unsigned short* __restrict__ xnb,
    const unsigned short* __restrict__ okb,  // bf16 offk [25][384]
    const float* __restrict__ offkb,
    const float* __restrict__ offg, const float* __restrict__ offb,
    const float* __restrict__ Woff, const float* __restrict__ boff,
    unsigned short* __restrict__ xsb)
{
  int blk = blockIdx.x;
  int pix = (blk & 7)*2048 + (blk >> 3);   // each XCD gets 2 contiguous images
  int b = pix >> 10, n = pix & 1023;
  int y = n >> 5, x = n & 31;
  int t = threadIdx.x;
  int c8 = (t < 48 ? t : 47) * 8;          // clamped channel base (lanes 48+ idle)
  float act = t < 48 ? 1.f : 0.f;
  const unsigned short* qb = qs + (size_t)b*1024*CC;
  int ry[5], rx[5]; unsigned my[5], mx[5];
#pragma unroll
  for (int k = 0; k < 5; k++){
    int yy = y + k - 2, xx = x + k - 2;
    my[k] = (yy >= 0 && yy < 32) ? 0xFFFFFFFFu : 0u;
    mx[k] = (xx >= 0 && xx < 32) ? 0xFFFFFFFFu : 0u;
    int yc = yy < 0 ? 0 : (yy > 31 ? 31 : yy);
    int xc = xx < 0 ? 0 : (xx > 31 ? 31 : xx);
    ry[k] = yc*32*CC; rx[k] = xc*CC;
  }
  float a[8];
#pragma unroll
  for (int j = 0; j < 8; j++) a[j] = 0.f;
#pragma unroll
  for (int ky = 0; ky < 5; ky++)
#pragma unroll
  for (int kx = 0; kx < 5; kx++){
    int tap = ky*5 + kx;
    unsigned m = my[ky] & mx[kx];
    uint4 q4 = *(const uint4*)(qb + ry[ky] + rx[kx] + c8);
    uint4 w4 = *(const uint4*)(okb + tap*CC + c8);
    q4.x &= m; q4.y &= m; q4.z &= m; q4.w &= m;
    a[0] = fmaf(lo16(q4.x), lo16(w4.x), a[0]);
    a[1] = fmaf(hi16(q4.x), hi16(w4.x), a[1]);
    a[2] = fmaf(lo16(q4.y), lo16(w4.y), a[2]);
    a[3] = fmaf(hi16(q4.y), hi16(w4.y), a[3]);
    a[4] = fmaf(lo16(q4.z), lo16(w4.z), a[4]);
    a[5] = fmaf(hi16(q4.z), hi16(w4.z), a[5]);
    a[6] = fmaf(lo16(q4.w), lo16(w4.w), a[6]);
    a[7] = fmaf(hi16(q4.w), hi16(w4.w), a[7]);
  }
  float4 kbA = *(const float4*)(offkb + c8);
  float4 kbB = *(const float4*)(offkb + c8 + 4);
  float c[8];
  c[0] = act * fmaf(a[0], INVQS, kbA.x);
  c[1] = act * fmaf(a[1], INVQS, kbA.y);
  c[2] = act * fmaf(a[2], INVQS, kbA.z);
  c[3] = act * fmaf(a[3], INVQS, kbA.w);
  c[4] = act * fmaf(a[4], INVQS, kbB.x);
  c[5] = act * fmaf(a[5], INVQS, kbB.y);
  c[6] = act * fmaf(a[6], INVQS, kbB.z);
  c[7] = act * fmaf(a[7], INVQS, kbB.w);
  float s = 0.f, s2 = 0.f;
#pragma unroll
  for (int j = 0; j < 8; j++){ s += c[j]; s2 += c[j]*c[j]; }
#pragma unroll
  for (int m2 = 32; m2; m2 >>= 1){ s += __shfl_xor(s, m2); s2 += __shfl_xor(s2, m2); }
  float mu = s * (1.f/CC);
  float var = s2 * (1.f/CC) - mu*mu;
  float rs = rsqrtf(var + 1e-5f);
  float4 gA = *(const float4*)(offg + c8); float4 gB = *(const float4*)(offg + c8 + 4);
  float4 oA = *(const float4*)(offb + c8); float4 oB = *(const float4*)(offb + c8 + 4);
  float4 wA = *(const float4*)(Woff + c8); float4 wB = *(const float4*)(Woff + c8 + 4);
  float4 wC = *(const float4*)(Woff + CC + c8); float4 wD = *(const float4*)(Woff + CC + c8 + 4);
  float gg[8] = {gA.x,gA.y,gA.z,gA.w,gB.x,gB.y,gB.z,gB.w};
  float bb[8] = {oA.x,oA.y,oA.z,oA.w,oB.x,oB.y,oB.z,oB.w};
  float w0[8] = {wA.x,wA.y,wA.z,wA.w,wB.x,wB.y,wB.z,wB.w};
  float w1[8] = {wC.x,wC.y,wC.z,wC.w,wD.x,wD.y,wD.z,wD.w};
  float p0 = 0.f, p1 = 0.f;
#pragma unroll
  for (int j = 0; j < 8; j++){
    float v = gelu_fast((c[j] - mu)*rs*gg[j] + bb[j]) * act;
    p0 = fmaf(v, w0[j], p0);
    p1 = fmaf(v, w1[j], p1);
  }
#pragma unroll
  for (int m2 = 32; m2; m2 >>= 1){ p0 += __shfl_xor(p0, m2); p1 += __shfl_xor(p1, m2); }
  float offy = tanh_fast(p0 + boff[0]) * 0.125f;
  float offx = tanh_fast(p1 + boff[1]) * 0.125f;
  float py = ((y + 0.5f)/16.f - 1.f + offy + 1.f) * 0.5f * 31.f;
  float px = ((x + 0.5f)/16.f - 1.f + offx + 1.f) * 0.5f * 31.f;
  float y0f = floorf(py), x0f = floorf(px);
  float wy = py - y0f, wx = px - x0f;
  int y0 = (int)y0f, x0 = (int)x0f;
  y0 = y0 < 0 ? 0 : (y0 > 31 ? 31 : y0);
  x0 = x0 < 0 ? 0 : (x0 > 31 ? 31 : x0);
  int y1 = y0 + 1 > 31 ? 31 : y0 + 1;
  int x1 = x0 + 1 > 31 ? 31 : x0 + 1;
  const unsigned short* s00 = xnb + (size_t)(b*1024 + y0*32 + x0)*CC + c8;
  const unsigned short* s01 = xnb + (size_t)(b*1024 + y0*32 + x1)*CC + c8;
  const unsigned short* s10 = xnb + (size_t)(b*1024 + y1*32 + x0)*CC + c8;
  const unsigned short* s11 = xnb + (size_t)(b*1024 + y1*32 + x1)*CC + c8;
  float w00 = (1.f-wy)*(1.f-wx), w01 = (1.f-wy)*wx, w10 = wy*(1.f-wx), w11 = wy*wx;
  uint4 A0 = *(const uint4*)s00;
  uint4 A1 = *(const uint4*)s01;
  uint4 A2 = *(const uint4*)s10;
  uint4 A3 = *(const uint4*)s11;
  if (t < 48){
    float r[8];
    r[0] = w00*lo16(A0.x) + w01*lo16(A1.x) + w10*lo16(A2.x) + w11*lo16(A3.x);
    r[1] = w00*hi16(A0.x) + w01*hi16(A1.x) + w10*hi16(A2.x) + w11*hi16(A3.x);
    r[2] = w00*lo16(A0.y) + w01*lo16(A1.y) + w10*lo16(A2.y) + w11*lo16(A3.y);
    r[3] = w00*hi16(A0.y) + w01*hi16(A1.y) + w10*hi16(A2.y) + w11*hi16(A3.y);
    r[4] = w00*lo16(A0.z) + w01*lo16(A1.z) + w10*lo16(A2.z) + w11*lo16(A3.z);
    r[5] = w00*hi16(A0.z) + w01*hi16(A1.z) + w10*hi16(A2.z) + w11*hi16(A3.z);
    r[6] = w00*lo16(A0.w) + w01*lo16(A1.w) + w10*lo16(A2.w) + w11*lo16(A3.w);
    r[7] = w00*hi16(A0.w) + w01*hi16(A1.w) + w10*hi16(A2.w) + w11*hi16(A3.w);
    uint4 st;
    st.x = ((unsigned)f2bf(r[1]) << 16) | f2bf(r[0]);
    st.y = ((unsigned)f2bf(r[3]) << 16) | f2bf(r[2]);
    st.z = ((unsigned)f2bf(r[5]) << 16) | f2bf(r[4]);
    st.w = ((unsigned)f2bf(r[7]) << 16) | f2bf(r[6]);
    *(uint4*)(xsb + (size_t)(b*1024 + n)*CC + c8) = st;
  }
}

// ---------------- attention: swapped QK^T, 64 q-rows/wave, in-register P ---------
// qs: bf16 Q scaled by QSCALE; kb row-major; vt: V^T [b][h][d][1024] key-permuted
// Block covers 256 q-rows (4 waves x 64); grid 768 = 4 qt x 12 h x 16 b.
__global__ __launch_bounds__(256) void k_attn(
    const unsigned short* __restrict__ qs, const unsigned short* __restrict__ kb,
    const unsigned short* __restrict__ vt, unsigned short* __restrict__ ob)
{
  __shared__ unsigned short Ks[2][64][40];   // [buf][key][dim]
  __shared__ unsigned short Vs[2][32][72];   // [buf][dim][physkey]
  int blk = blockIdx.x;
  int sw = (blk & 7)*96 + (blk >> 3);     // XCD-grouped
  int qt = sw & 3, h = (sw >> 2) % 12, b = sw / 48;
  int t = threadIdx.x;
  int w = t >> 6, l = t & 63;
  int g = l >> 4, ln = l & 15;
  int q0 = qt*256 + w*64;
  bf16x8 qa[4];
#pragma unroll
  for (int mi = 0; mi < 4; mi++)
    qa[mi] = *(const bf16x8*)&qs[(size_t)(b*1024 + q0 + mi*16 + ln)*CC + h*32 + g*8];
  bf16x8 vones;
#pragma unroll
  for (int j = 0; j < 8; j++) vones[j] = (short)0x3F80;   // bf16 1.0
  f32x4 z = {0.f,0.f,0.f,0.f};
  f32x4 oacc[4][2];
#pragma unroll
  for (int mi = 0; mi < 4; mi++){ oacc[mi][0]=z; oacc[mi][1]=z; }
  f32x4 lacc[4]; lacc[0]=z; lacc[1]=z; lacc[2]=z; lacc[3]=z;
  int krow = t >> 2, kc = (t & 3)*8;
  int vdim = t >> 3, vc = (t & 7)*8;
  const unsigned short* kptr = kb + (size_t)(b*1024 + krow)*CC + h*32 + kc;
  const unsigned short* vptr = vt + (size_t)((b*12 + h)*32 + vdim)*1024 + vc;
  {
    uint4 kr = *(const uint4*)kptr;
    uint4 vr = *(const uint4*)vptr;
    *(uint4*)&Ks[0][krow][kc] = kr;
    *(uint4*)&Vs[0][vdim][vc] = vr;
  }
  __syncthreads();
  for (int kt = 0; kt < 16; kt++){
    int cur = kt & 1;
    uint4 kr2, vr2;
    if (kt < 15){
      int k0 = (kt + 1)*64;
      kr2 = *(const uint4*)(kptr + (size_t)k0*CC);
      vr2 = *(const uint4*)(vptr + k0);
    }
#pragma unroll
    for (int k2 = 0; k2 < 2; k2++){
      bf16x8 kf0 = *(const bf16x8*)&Ks[cur][(2*k2)*16 + ln][g*8];
      bf16x8 kf1 = *(const bf16x8*)&Ks[cur][(2*k2+1)*16 + ln][g*8];
      bf16x8 va0 = *(const bf16x8*)&Vs[cur][ln][k2*32 + g*8];
      bf16x8 va1 = *(const bf16x8*)&Vs[cur][16 + ln][k2*32 + g*8];
      __builtin_amdgcn_s_setprio(1);
#pragma unroll
      for (int mi = 0; mi < 4; mi++){
        f32x4 s0 = mfma16(kf0, qa[mi], z);     // S^T keys (2k2)*16..+16
        f32x4 s1 = mfma16(kf1, qa[mi], z);     // S^T keys (2k2+1)*16..+16
        float e0 = fexp2(s0[0]), e1 = fexp2(s0[1]);
        float e2 = fexp2(s0[2]), e3 = fexp2(s0[3]);
        float f0 = fexp2(s1[0]), f1 = fexp2(s1[1]);
        float f2 = fexp2(s1[2]), f3 = fexp2(s1[3]);
        uint4 pw;
        pw.x = packbf(e0, e1);
        pw.y = packbf(e2, e3);
        pw.z = packbf(f0, f1);
        pw.w = packbf(f2, f3);
        bf16x8 pa = *(bf16x8*)&pw;
        oacc[mi][0] = mfma16(pa, va0, oacc[mi][0]);
        oacc[mi][1] = mfma16(pa, va1, oacc[mi][1]);
        lacc[mi] = mfma16(pa, vones, lacc[mi]);
      }
      __builtin_amdgcn_s_setprio(0);
    }
    if (kt < 15){
      *(uint4*)&Ks[cur ^ 1][krow][kc] = kr2;
      *(uint4*)&Vs[cur ^ 1][vdim][vc] = vr2;
      __syncthreads();
    }
  }
  // lacc[mi][i] = full row-sum of bf16 P for q-row mi*16+g*4+i (matches oacc rows)
  float rinv[4][4];
#pragma unroll
  for (int mi = 0; mi < 4; mi++)
#pragma unroll
    for (int i = 0; i < 4; i++) rinv[mi][i] = frcp(lacc[mi][i]);
#pragma unroll
  for (int mi = 0; mi < 4; mi++)
#pragma unroll
  for (int d2 = 0; d2 < 2; d2++)
#pragma unroll
  for (int i = 0; i < 4; i++){
    float v = oacc[mi][d2][i] * rinv[mi][i];
    int row = q0 + mi*16 + g*4 + i;
    ob[(size_t)(b*1024 + row)*CC + h*32 + d2*16 + ln] = f2bf(v);
  }
}

extern "C" void kernel_launch(void* const* d_in, const int* in_sizes, int n_in,
                              void* d_out, int out_size, void* d_ws, size_t ws_size,
                              hipStream_t stream)
{
  (void)in_sizes; (void)n_in; (void)out_size; (void)ws_size;
  const float* x     = (const float*)d_in[0];
  const float* ln1g  = (const float*)d_in[1];
  const float* ln1b  = (const float*)d_in[2];
  const float* Wq    = (const float*)d_in[3];
  const float* bq    = (const float*)d_in[4];
  const float* offk  = (const float*)d_in[5];
  const float* offkb = (const float*)d_in[6];
  const float* offg  = (const float*)d_in[7];
  const float* offb  = (const float*)d_in[8];
  const float* Woff  = (const float*)d_in[9];
  const float* boff  = (const float*)d_in[10];
  const float* Wk    = (const float*)d_in[11];
  const float* bk    = (const float*)d_in[12];
  const float* Wv    = (const float*)d_in[13];
  const float* bv    = (const float*)d_in[14];
  const float* Wo    = (const float*)d_in[15];
  const float* bo    = (const float*)d_in[16];
  const float* ln2g  = (const float*)d_in[17];
  const float* ln2b  = (const float*)d_in[18];
  const float* W1    = (const float*)d_in[19];
  const float* b1    = (const float*)d_in[20];
  const float* W2    = (const float*)d_in[21];
  const float* b2    = (const float*)d_in[22];

  char* ws = (char*)d_ws;
  unsigned short* X2B = (unsigned short*)ws;
  unsigned short* XSB = (unsigned short*)(ws + 25165824);
  unsigned short* KB  = (unsigned short*)(ws + 37748736);
  unsigned short* VT  = (unsigned short*)(ws + 50331648);
  unsigned short* OB  = (unsigned short*)(ws + 62914560);
  unsigned short* XNB = (unsigned short*)(ws + 75497472);
  unsigned short* QSB = (unsigned short*)(ws + 88080384);
  unsigned short* YB  = QSB;
  unsigned short* HB  = (unsigned short*)(ws + 25165824);
  unsigned short* WQB = (unsigned short*)(ws + 100663296);
  unsigned short* WKB = WQB + 147456;   // Wk rows 0-383, Wv rows 384-767 (contiguous)
  unsigned short* WOB = WKB + 294912;
  unsigned short* W1B = WOB + 147456;
  unsigned short* W2B = W1B + 589824;
  unsigned short* OKB = W2B + 589824;   // bf16 offk [25][384]

  k_cvt_all<<<1738, 256, 0, stream>>>(Wq, Wk, Wv, Wo, W1, W2, offk, WQB);
  k_ln<0><<<4096, 256, 0, stream>>>(x, nullptr, ln1g, ln1b, XNB);
  k_gemm64<5><<<768, 256, 0, stream>>>(XNB, WQB, bq, nullptr, nullptr, nullptr, nullptr, QSB, nullptr, 3, 384, 384);
  k_offset_sample<<<16384, 64, 0, stream>>>(QSB, XNB, OKB, offkb, offg, offb, Woff, boff, XSB);
  k_gemm64<6><<<1536, 256, 0, stream>>>(XSB, WKB, bk, bv, nullptr, nullptr, nullptr, KB, VT, 6, 768, 384);
  k_attn<<<768, 256, 0, stream>>>(QSB, KB, VT, OB);
  k_gemm64<2><<<768, 256, 0, stream>>>(OB, WOB, bo, nullptr, x, nullptr, nullptr, X2B, nullptr, 3, 384, 384);
  k_ln<1><<<4096, 256, 0, stream>>>(nullptr, X2B, ln2g, ln2b, YB);
  k_mlp1<<<1536, 256, 0, stream>>>(YB, W1B, b1, HB);
  k_mlp2<<<768, 256, 0, stream>>>(HB, W2B, b2, X2B, (float*)d_out);
}

// Round 12
// 209.981 us; speedup vs baseline: 1.5139x; 1.0618x over previous
//
#include <hip/hip_runtime.h>
#include <math.h>

#define DI __device__ __forceinline__

typedef __attribute__((ext_vector_type(8))) short bf16x8;
typedef __attribute__((ext_vector_type(4))) float f32x4;

static constexpr int CC = 384;
// attn scale * log2(e): scores come out of QK^T already in log2 domain
static constexpr float QSCALE = 0.17677669529663687f * 1.4426950408889634f;
static constexpr float INVQS  = 1.0f / QSCALE;

DI unsigned short f2bf(float f){
  unsigned u = __float_as_uint(f);
  u += 0x7FFFu + ((u >> 16) & 1u);
  return (unsigned short)(u >> 16);
}
DI float bf2f(unsigned short u){ return __uint_as_float((unsigned)u << 16); }
DI float lo16(unsigned u){ return __uint_as_float(u << 16); }
DI float hi16(unsigned u){ return __uint_as_float(u & 0xFFFF0000u); }
DI float fexp2(float x){ return __builtin_amdgcn_exp2f(x); }
DI float frcp(float x){ return __builtin_amdgcn_rcpf(x); }
// tanh(z) = 1 - 2/(exp2(z*2*log2e)+1)
DI float tanh_fast(float z){ return 1.f - 2.f*frcp(fexp2(2.8853900817779268f*z) + 1.f); }
DI float gelu_fast(float v){
  float u = v*v;
  float z = 0.7978845608028654f * fmaf(0.044715f*u, v, v);
  return v - v*frcp(fexp2(2.8853900817779268f*z) + 1.f);
}
DI f32x4 mfma16(bf16x8 a, bf16x8 b, f32x4 c){
  return __builtin_amdgcn_mfma_f32_16x16x32_bf16(a, b, c, 0, 0, 0);
}
DI void gload16(const unsigned short* g, unsigned short* l){
  __builtin_amdgcn_global_load_lds(
      (const __attribute__((address_space(1))) unsigned int*)(const void*)g,
      (__attribute__((address_space(3))) unsigned int*)(void*)l, 16, 0, 0);
}
// pack truncated hi16 of (pb, pa) -> (hi:pb, lo:pa)
DI unsigned packbf(float pa, float pb){
  return __builtin_amdgcn_perm(__float_as_uint(pb), __float_as_uint(pa), 0x07060302u);
}

// ---------------- weight fp32 -> bf16 (6 matmul weights + offk), vectorized x4 ---
__global__ __launch_bounds__(256) void k_cvt_all(
    const float* __restrict__ wq, const float* __restrict__ wk,
    const float* __restrict__ wv, const float* __restrict__ wo,
    const float* __restrict__ w1, const float* __restrict__ w2,
    const float* __restrict__ ofk,
    unsigned short* __restrict__ dst)
{
  int i4 = (blockIdx.x*256 + threadIdx.x)*4;
  if (i4 >= 1779072) return;
  const float* src; int off;
  if (i4 < 147456){ src = wq; off = i4; }
  else if (i4 < 294912){ src = wk; off = i4 - 147456; }
  else if (i4 < 442368){ src = wv; off = i4 - 294912; }
  else if (i4 < 589824){ src = wo; off = i4 - 442368; }
  else if (i4 < 1179648){ src = w1; off = i4 - 589824; }
  else if (i4 < 1769472){ src = w2; off = i4 - 1179648; }
  else { src = ofk; off = i4 - 1769472; }
  float4 v = *(const float4*)(src + off);
  uint2 o;
  o.x = ((unsigned)f2bf(v.y) << 16) | f2bf(v.x);
  o.y = ((unsigned)f2bf(v.w) << 16) | f2bf(v.z);
  *(uint2*)(dst + i4) = o;
}

// ---------------- LayerNorm over C=384, one wave/row, 4 rows/block --------------
// BIN=0: f32 input (scalar loads); optional outb2 = bf16 copy of raw input
// BIN=1: bf16 input (vectorized 6 ch/lane)
template<int BIN>
__global__ __launch_bounds__(256) void k_ln(const float* __restrict__ xf,
    const unsigned short* __restrict__ xb,
    const float* __restrict__ g, const float* __restrict__ b,
    unsigned short* __restrict__ outb, unsigned short* __restrict__ outb2)
{
  int row = blockIdx.x*4 + (threadIdx.x >> 6);
  int l = threadIdx.x & 63;
  float v[6]; int ch[6];
  if constexpr (BIN){
    int cA = 4*l, cB = 256 + 2*l;
    ch[0]=cA; ch[1]=cA+1; ch[2]=cA+2; ch[3]=cA+3; ch[4]=cB; ch[5]=cB+1;
    const unsigned short* xp = xb + (size_t)row * CC;
    uint2 u2 = *(const uint2*)(xp + cA);
    unsigned u1 = *(const unsigned*)(xp + cB);
    v[0]=lo16(u2.x); v[1]=hi16(u2.x); v[2]=lo16(u2.y); v[3]=hi16(u2.y);
    v[4]=lo16(u1);   v[5]=hi16(u1);
  } else {
    const float* xp = xf + (size_t)row * CC;
#pragma unroll
    for (int p = 0; p < 6; p++){ ch[p] = l + 64*p; v[p] = xp[ch[p]]; }
  }
  float s = 0.f, s2 = 0.f;
#pragma unroll
  for (int p = 0; p < 6; p++){ s += v[p]; s2 += v[p]*v[p]; }
#pragma unroll
  for (int m = 32; m; m >>= 1){ s += __shfl_xor(s, m); s2 += __shfl_xor(s2, m); }
  float mu = s * (1.f/CC);
  float var = s2 * (1.f/CC) - mu*mu;
  float rs = rsqrtf(var + 1e-5f);
  float o[6];
#pragma unroll
  for (int p = 0; p < 6; p++) o[p] = (v[p] - mu) * rs * g[ch[p]] + b[ch[p]];
  unsigned short* op = outb + (size_t)row*CC;
  if constexpr (BIN){
    uint2 st;
    st.x = ((unsigned)f2bf(o[1]) << 16) | f2bf(o[0]);
    st.y = ((unsigned)f2bf(o[3]) << 16) | f2bf(o[2]);
    *(uint2*)(op + ch[0]) = st;
    *(unsigned*)(op + ch[4]) = ((unsigned)f2bf(o[5]) << 16) | f2bf(o[4]);
  } else {
#pragma unroll
    for (int p = 0; p < 6; p++) op[ch[p]] = f2bf(o[p]);
    if (outb2){
      unsigned short* op2 = outb2 + (size_t)row*CC;
#pragma unroll
      for (int p = 0; p < 6; p++) op2[ch[p]] = f2bf(v[p]);
    }
  }
}

// ---------------- unified 64x128 GEMM, BK=64, dbuf LDS + gload_lds + XCD swizzle -
// out(M,N) = A(M,K) @ W(N,K)^T + bias.  1D grid, ntn = N/128 tiles. K % 64 == 0.
// EPI 5: bf16 * QSCALE out
// EPI 6: fused K|V (N=768): col<384 -> KB row-major; col>=384 -> VT key-permuted
// EPI 7: + bf16 res -> f32 out
// EPI 8: + bf16 res -> bf16 out
// VT phys key order (per 64-block): phys = (k6&0x23)|((k6&0xC)<<1)|((k6&0x10)>>2)
template<int EPI>
__global__ __launch_bounds__(256) void k_g64(
    const unsigned short* __restrict__ A, const unsigned short* __restrict__ W,
    const float* __restrict__ bias, const float* __restrict__ bias2,
    const unsigned short* __restrict__ resb,
    float* __restrict__ outf, unsigned short* __restrict__ outb,
    unsigned short* __restrict__ outb2, int ntn, int N, int K)
{
  __shared__ unsigned short As[2][4096];   // 64 rows x 64 cols, 8-slot swizzled
  __shared__ unsigned short Bs[2][8192];   // 128 rows x 64 cols
  int bid = blockIdx.x;
  int cpx = gridDim.x >> 3;
  int id = (bid & 7)*cpx + (bid >> 3);     // XCD-chunk swizzle
  int bn = (id % ntn) * 128;
  int bm = (id / ntn) * 64;
  int t = threadIdx.x;
  int w = t >> 6, l = t & 63;
  int g = l >> 4, ln = l & 15;
  int wm = w >> 1, wn = w & 1;             // wave: 32 rows x 64 cols
  f32x4 acc[2][4];
#pragma unroll
  for (int i = 0; i < 2; i++)
#pragma unroll
    for (int j = 0; j < 4; j++) acc[i][j] = (f32x4){0.f,0.f,0.f,0.f};
  // staging round j: rows j*32 + (t>>3), slot t&7; src col slot = (t&7)^((t>>3)&7)
  int srcoff = ((t & 7) ^ ((t >> 3) & 7)) * 8;
  int srowA = t >> 3;
  const unsigned short* Ap0 = A + (size_t)(bm + srowA)*K + srcoff;
  const unsigned short* Ap1 = A + (size_t)(bm + 32 + srowA)*K + srcoff;
  const unsigned short* Wp0 = W + (size_t)(bn + srowA)*K + srcoff;
  const unsigned short* Wp1 = W + (size_t)(bn + 32 + srowA)*K + srcoff;
  const unsigned short* Wp2 = W + (size_t)(bn + 64 + srowA)*K + srcoff;
  const unsigned short* Wp3 = W + (size_t)(bn + 96 + srowA)*K + srcoff;
  int NT = K >> 6;
  int wl = w*512;
  gload16(Ap0, &As[0][wl]);
  gload16(Ap1, &As[0][wl + 2048]);
  gload16(Wp0, &Bs[0][wl]);
  gload16(Wp1, &Bs[0][wl + 2048]);
  gload16(Wp2, &Bs[0][wl + 4096]);
  gload16(Wp3, &Bs[0][wl + 6144]);
  __syncthreads();
  for (int kt = 0; kt < NT; kt++){
    int cur = kt & 1;
    if (kt + 1 < NT){
      int k0 = (kt + 1) << 6;
      gload16(Ap0 + k0, &As[cur ^ 1][wl]);
      gload16(Ap1 + k0, &As[cur ^ 1][wl + 2048]);
      gload16(Wp0 + k0, &Bs[cur ^ 1][wl]);
      gload16(Wp1 + k0, &Bs[cur ^ 1][wl + 2048]);
      gload16(Wp2 + k0, &Bs[cur ^ 1][wl + 4096]);
      gload16(Wp3 + k0, &Bs[cur ^ 1][wl + 6144]);
    }
#pragma unroll
    for (int kk = 0; kk < 2; kk++){
      bf16x8 af[2], bf[4];
#pragma unroll
      for (int mi = 0; mi < 2; mi++){
        int row = wm*32 + mi*16 + ln;
        int sl = (kk*4 + g) ^ (row & 7);
        af[mi] = *(const bf16x8*)((const char*)As[cur] + row*128 + sl*16);
      }
#pragma unroll
      for (int ni = 0; ni < 4; ni++){
        int row = wn*64 + ni*16 + ln;
        int sl = (kk*4 + g) ^ (row & 7);
        bf[ni] = *(const bf16x8*)((const char*)Bs[cur] + row*128 + sl*16);
      }
#pragma unroll
      for (int mi = 0; mi < 2; mi++)
#pragma unroll
        for (int ni = 0; ni < 4; ni++)
          acc[mi][ni] = mfma16(af[mi], bf[ni], acc[mi][ni]);
    }
    if (kt + 1 < NT) __syncthreads();
  }
#pragma unroll
  for (int mi = 0; mi < 2; mi++)
#pragma unroll
  for (int ni = 0; ni < 4; ni++){
    int col = bn + wn*64 + ni*16 + ln;
    float bv;
    if constexpr (EPI == 6) bv = col < 384 ? bias[col] : bias2[col - 384];
    else bv = bias[col];
#pragma unroll
    for (int i = 0; i < 4; i++){
      int row = bm + wm*32 + mi*16 + g*4 + i;
      float v = acc[mi][ni][i] + bv;
      if constexpr (EPI == 5) outb[(size_t)row*N + col] = f2bf(v * QSCALE);
      if constexpr (EPI == 7){ v += bf2f(resb[(size_t)row*N + col]); outf[(size_t)row*N + col] = v; }
      if constexpr (EPI == 8){ v += bf2f(resb[(size_t)row*N + col]); outb[(size_t)row*N + col] = f2bf(v); }
      if constexpr (EPI == 6){
        if (col < 384){
          outb[(size_t)row*384 + col] = f2bf(v);
        } else {
          int c = col - 384;
          int bb = row >> 10, key = row & 1023, h = c >> 5, d = c & 31;
          int k6 = key & 63;
          int phys = (key & ~63) | (k6 & 0x23) | ((k6 & 0xC) << 1) | ((k6 & 0x10) >> 2);
          outb2[(size_t)(((bb*12 + h) << 5) + d)*1024 + phys] = f2bf(v);
        }
      }
    }
  }
}

// ---------------- MLP1: 128x128 GEMM, BK=32, dbuf, gelu-bf16 epilogue ------------
__global__ __launch_bounds__(256) void k_mlp1(
    const unsigned short* __restrict__ A, const unsigned short* __restrict__ W,
    const float* __restrict__ bias, unsigned short* __restrict__ outb)
{
  __shared__ unsigned short As[2][4096];   // 128 x 32, slot-swizzled
  __shared__ unsigned short Bs[2][4096];
  int bid = blockIdx.x;
  int cpx = gridDim.x >> 3;                // 192
  int id = (bid & 7)*cpx + (bid >> 3);     // XCD-chunk swizzle
  int bn = (id % 12) * 128;
  int bm = (id / 12) * 128;
  int t = threadIdx.x;
  int w = t >> 6, l = t & 63;
  int g = l >> 4, ln = l & 15;
  int wm = w >> 1, wn = w & 1;
  f32x4 acc[4][4];
#pragma unroll
  for (int i = 0; i < 4; i++)
#pragma unroll
    for (int j = 0; j < 4; j++) acc[i][j] = (f32x4){0.f,0.f,0.f,0.f};
  int srow0 = t >> 2, slot = t & 3;
  int srow1 = srow0 + 64;
  int cb0 = (slot ^ (srow0 & 3) ^ ((srow0 >> 2) & 3)) * 8;
  int cb1 = (slot ^ (srow1 & 3) ^ ((srow1 >> 2) & 3)) * 8;
  const unsigned short* Ap0 = A + (size_t)(bm + srow0)*384 + cb0;
  const unsigned short* Ap1 = A + (size_t)(bm + srow1)*384 + cb1;
  const unsigned short* Wp0 = W + (size_t)(bn + srow0)*384 + cb0;
  const unsigned short* Wp1 = W + (size_t)(bn + srow1)*384 + cb1;
  int wl = w*512;
  gload16(Ap0, &As[0][wl]);
  gload16(Ap1, &As[0][wl + 2048]);
  gload16(Wp0, &Bs[0][wl]);
  gload16(Wp1, &Bs[0][wl + 2048]);
  __syncthreads();
  for (int kt = 0; kt < 12; kt++){
    int cur = kt & 1;
    if (kt < 11){
      int k0 = (kt + 1) << 5;
      gload16(Ap0 + k0, &As[cur ^ 1][wl]);
      gload16(Ap1 + k0, &As[cur ^ 1][wl + 2048]);
      gload16(Wp0 + k0, &Bs[cur ^ 1][wl]);
      gload16(Wp1 + k0, &Bs[cur ^ 1][wl + 2048]);
    }
    bf16x8 af[4], bf[4];
#pragma unroll
    for (int mi = 0; mi < 4; mi++){
      int row = wm*64 + mi*16 + ln;
      int sl = g ^ (row & 3) ^ ((row >> 2) & 3);
      af[mi] = *(const bf16x8*)((const char*)As[cur] + row*64 + sl*16);
    }
#pragma unroll
    for (int ni = 0; ni < 4; ni++){
      int row = wn*64 + ni*16 + ln;
      int sl = g ^ (row & 3) ^ ((row >> 2) & 3);
      bf[ni] = *(const bf16x8*)((const char*)Bs[cur] + row*64 + sl*16);
    }
#pragma unroll
    for (int mi = 0; mi < 4; mi++)
#pragma unroll
      for (int ni = 0; ni < 4; ni++)
        acc[mi][ni] = mfma16(af[mi], bf[ni], acc[mi][ni]);
    if (kt < 11) __syncthreads();
  }
#pragma unroll
  for (int mi = 0; mi < 4; mi++)
#pragma unroll
  for (int ni = 0; ni < 4; ni++){
    int col = bn + wn*64 + ni*16 + ln;
    float bv = bias[col];
#pragma unroll
    for (int i = 0; i < 4; i++){
      int row = bm + wm*64 + mi*16 + g*4 + i;
      float v = gelu_fast(acc[mi][ni][i] + bv);
      outb[(size_t)row*1536 + col] = f2bf(v);
    }
  }
}

// ---------------- fused offset net + grid sample: one WAVE per pixel -------------
// 8 channels/thread on 48 active lanes; all accesses are 16B uint4
__global__ __launch_bounds__(64) void k_offset_sample(
    const unsigned short* __restrict__ qs, const unsigned short* __restrict__ xnb,
    const unsigned short* __restrict__ okb,  // bf16 offk [25][384]
    const float* __restrict__ offkb,
    const float* __restrict__ offg, const float* __restrict__ offb,
    const float* __restrict__ Woff, const float* __restrict__ boff,
    unsigned short* __restrict__ xsb)
{
  int blk = blockIdx.x;
  int pix = (blk & 7)*2048 + (blk >> 3);   // each XCD gets 2 contiguous images
  int b = pix >> 10, n = pix & 1023;
  int y = n >> 5, x = n & 31;
  int t = threadIdx.x;
  int c8 = (t < 48 ? t : 47) * 8;          // clamped channel base (lanes 48+ idle)
  float act = t < 48 ? 1.f : 0.f;
  const unsigned short* qb = qs + (size_t)b*1024*CC;
  int ry[5], rx[5]; unsigned my[5], mx[5];
#pragma unroll
  for (int k = 0; k < 5; k++){
    int yy = y + k - 2, xx = x + k - 2;
    my[k] = (yy >= 0 && yy < 32) ? 0xFFFFFFFFu : 0u;
    mx[k] = (xx >= 0 && xx < 32) ? 0xFFFFFFFFu : 0u;
    int yc = yy < 0 ? 0 : (yy > 31 ? 31 : yy);
    int xc = xx < 0 ? 0 : (xx > 31 ? 31 : xx);
    ry[k] = yc*32*CC; rx[k] = xc*CC;
  }
  float a[8];
#pragma unroll
  for (int j = 0; j < 8; j++) a[j] = 0.f;
#pragma unroll
  for (int ky = 0; ky < 5; ky++)
#pragma unroll
  for (int kx = 0; kx < 5; kx++){
    int tap = ky*5 + kx;
    unsigned m = my[ky] & mx[kx];
    uint4 q4 = *(const uint4*)(qb + ry[ky] + rx[kx] + c8);
    uint4 w4 = *(const uint4*)(okb + tap*CC + c8);
    q4.x &= m; q4.y &= m; q4.z &= m; q4.w &= m;
    a[0] = fmaf(lo16(q4.x), lo16(w4.x), a[0]);
    a[1] = fmaf(hi16(q4.x), hi16(w4.x), a[1]);
    a[2] = fmaf(lo16(q4.y), lo16(w4.y), a[2]);
    a[3] = fmaf(hi16(q4.y), hi16(w4.y), a[3]);
    a[4] = fmaf(lo16(q4.z), lo16(w4.z), a[4]);
    a[5] = fmaf(hi16(q4.z), hi16(w4.z), a[5]);
    a[6] = fmaf(lo16(q4.w), lo16(w4.w), a[6]);
    a[7] = fmaf(hi16(q4.w), hi16(w4.w), a[7]);
  }
  float4 kbA = *(const float4*)(offkb + c8);
  float4 kbB = *(const float4*)(offkb + c8 + 4);
  float c[8];
  c[0] = act * fmaf(a[0], INVQS, kbA.x);
  c[1] = act * fmaf(a[1], INVQS, kbA.y);
  c[2] = act * fmaf(a[2], INVQS, kbA.z);
  c[3] = act * fmaf(a[3], INVQS, kbA.w);
  c[4] = act * fmaf(a[4], INVQS, kbB.x);
  c[5] = act * fmaf(a[5], INVQS, kbB.y);
  c[6] = act * fmaf(a[6], INVQS, kbB.z);
  c[7] = act * fmaf(a[7], INVQS, kbB.w);
  float s = 0.f, s2 = 0.f;
#pragma unroll
  for (int j = 0; j < 8; j++){ s += c[j]; s2 += c[j]*c[j]; }
#pragma unroll
  for (int m2 = 32; m2; m2 >>= 1){ s += __shfl_xor(s, m2); s2 += __shfl_xor(s2, m2); }
  float mu = s * (1.f/CC);
  float var = s2 * (1.f/CC) - mu*mu;
  float rs = rsqrtf(var + 1e-5f);
  float4 gA = *(const float4*)(offg + c8); float4 gB = *(const float4*)(offg + c8 + 4);
  float4 oA = *(const float4*)(offb + c8); float4 oB = *(const float4*)(offb + c8 + 4);
  float4 wA = *(const float4*)(Woff + c8); float4 wB = *(const float4*)(Woff + c8 + 4);
  float4 wC = *(const float4*)(Woff + CC + c8); float4 wD = *(const float4*)(Woff + CC + c8 + 4);
  float gg[8] = {gA.x,gA.y,gA.z,gA.w,gB.x,gB.y,gB.z,gB.w};
  float bb[8] = {oA.x,oA.y,oA.z,oA.w,oB.x,oB.y,oB.z,oB.w};
  float w0[8] = {wA.x,wA.y,wA.z,wA.w,wB.x,wB.y,wB.z,wB.w};
  float w1[8] = {wC.x,wC.y,wC.z,wC.w,wD.x,wD.y,wD.z,wD.w};
  float p0 = 0.f, p1 = 0.f;
#pragma unroll
  for (int j = 0; j < 8; j++){
    float v = gelu_fast((c[j] - mu)*rs*gg[j] + bb[j]) * act;
    p0 = fmaf(v, w0[j], p0);
    p1 = fmaf(v, w1[j], p1);
  }
#pragma unroll
  for (int m2 = 32; m2; m2 >>= 1){ p0 += __shfl_xor(p0, m2); p1 += __shfl_xor(p1, m2); }
  float offy = tanh_fast(p0 + boff[0]) * 0.125f;
  float offx = tanh_fast(p1 + boff[1]) * 0.125f;
  float py = ((y + 0.5f)/16.f - 1.f + offy + 1.f) * 0.5f * 31.f;
  float px = ((x + 0.5f)/16.f - 1.f + offx + 1.f) * 0.5f * 31.f;
  float y0f = floorf(py), x0f = floorf(px);
  float wy = py - y0f, wx = px - x0f;
  int y0 = (int)y0f, x0 = (int)x0f;
  y0 = y0 < 0 ? 0 : (y0 > 31 ? 31 : y0);
  x0 = x0 < 0 ? 0 : (x0 > 31 ? 31 : x0);
  int y1 = y0 + 1 > 31 ? 31 : y0 + 1;
  int x1 = x0 + 1 > 31 ? 31 : x0 + 1;
  const unsigned short* s00 = xnb + (size_t)(b*1024 + y0*32 + x0)*CC + c8;
  const unsigned short* s01 = xnb + (size_t)(b*1024 + y0*32 + x1)*CC + c8;
  const unsigned short* s10 = xnb + (size_t)(b*1024 + y1*32 + x0)*CC + c8;
  const unsigned short* s11 = xnb + (size_t)(b*1024 + y1*32 + x1)*CC + c8;
  float w00 = (1.f-wy)*(1.f-wx), w01 = (1.f-wy)*wx, w10 = wy*(1.f-wx), w11 = wy*wx;
  uint4 A0 = *(const uint4*)s00;
  uint4 A1 = *(const uint4*)s01;
  uint4 A2 = *(const uint4*)s10;
  uint4 A3 = *(const uint4*)s11;
  if (t < 48){
    float r[8];
    r[0] = w00*lo16(A0.x) + w01*lo16(A1.x) + w10*lo16(A2.x) + w11*lo16(A3.x);
    r[1] = w00*hi16(A0.x) + w01*hi16(A1.x) + w10*hi16(A2.x) + w11*hi16(A3.x);
    r[2] = w00*lo16(A0.y) + w01*lo16(A1.y) + w10*lo16(A2.y) + w11*lo16(A3.y);
    r[3] = w00*hi16(A0.y) + w01*hi16(A1.y) + w10*hi16(A2.y) + w11*hi16(A3.y);
    r[4] = w00*lo16(A0.z) + w01*lo16(A1.z) + w10*lo16(A2.z) + w11*lo16(A3.z);
    r[5] = w00*hi16(A0.z) + w01*hi16(A1.z) + w10*hi16(A2.z) + w11*hi16(A3.z);
    r[6] = w00*lo16(A0.w) + w01*lo16(A1.w) + w10*lo16(A2.w) + w11*lo16(A3.w);
    r[7] = w00*hi16(A0.w) + w01*hi16(A1.w) + w10*hi16(A2.w) + w11*hi16(A3.w);
    uint4 st;
    st.x = ((unsigned)f2bf(r[1]) << 16) | f2bf(r[0]);
    st.y = ((unsigned)f2bf(r[3]) << 16) | f2bf(r[2]);
    st.z = ((unsigned)f2bf(r[5]) << 16) | f2bf(r[4]);
    st.w = ((unsigned)f2bf(r[7]) << 16) | f2bf(r[6]);
    *(uint4*)(xsb + (size_t)(b*1024 + n)*CC + c8) = st;
  }
}

// ---------------- attention: swapped QK^T, 64 q-rows/wave, in-register P ---------
// qs: bf16 Q scaled by QSCALE; kb row-major; vt: V^T [b][h][d][1024] key-permuted
// Block covers 256 q-rows (4 waves x 64); grid 768 = 4 qt x 12 h x 16 b.
__global__ __launch_bounds__(256) void k_attn(
    const unsigned short* __restrict__ qs, const unsigned short* __restrict__ kb,
    const unsigned short* __restrict__ vt, unsigned short* __restrict__ ob)
{
  __shared__ unsigned short Ks[2][64][40];   // [buf][key][dim]
  __shared__ unsigned short Vs[2][32][72];   // [buf][dim][physkey]
  int blk = blockIdx.x;
  int sw = (blk & 7)*96 + (blk >> 3);     // XCD-grouped
  int qt = sw & 3, h = (sw >> 2) % 12, b = sw / 48;
  int t = threadIdx.x;
  int w = t >> 6, l = t & 63;
  int g = l >> 4, ln = l & 15;
  int q0 = qt*256 + w*64;
  bf16x8 qa[4];
#pragma unroll
  for (int mi = 0; mi < 4; mi++)
    qa[mi] = *(const bf16x8*)&qs[(size_t)(b*1024 + q0 + mi*16 + ln)*CC + h*32 + g*8];
  bf16x8 vones;
#pragma unroll
  for (int j = 0; j < 8; j++) vones[j] = (short)0x3F80;   // bf16 1.0
  f32x4 z = {0.f,0.f,0.f,0.f};
  f32x4 oacc[4][2];
#pragma unroll
  for (int mi = 0; mi < 4; mi++){ oacc[mi][0]=z; oacc[mi][1]=z; }
  f32x4 lacc[4]; lacc[0]=z; lacc[1]=z; lacc[2]=z; lacc[3]=z;
  int krow = t >> 2, kc = (t & 3)*8;
  int vdim = t >> 3, vc = (t & 7)*8;
  const unsigned short* kptr = kb + (size_t)(b*1024 + krow)*CC + h*32 + kc;
  const unsigned short* vptr = vt + (size_t)((b*12 + h)*32 + vdim)*1024 + vc;
  {
    uint4 kr = *(const uint4*)kptr;
    uint4 vr = *(const uint4*)vptr;
    *(uint4*)&Ks[0][krow][kc] = kr;
    *(uint4*)&Vs[0][vdim][vc] = vr;
  }
  __syncthreads();
  for (int kt = 0; kt < 16; kt++){
    int cur = kt & 1;
    uint4 kr2, vr2;
    if (kt < 15){
      int k0 = (kt + 1)*64;
      kr2 = *(const uint4*)(kptr + (size_t)k0*CC);
      vr2 = *(const uint4*)(vptr + k0);
    }
#pragma unroll
    for (int k2 = 0; k2 < 2; k2++){
      bf16x8 kf0 = *(const bf16x8*)&Ks[cur][(2*k2)*16 + ln][g*8];
      bf16x8 kf1 = *(const bf16x8*)&Ks[cur][(2*k2+1)*16 + ln][g*8];
      bf16x8 va0 = *(const bf16x8*)&Vs[cur][ln][k2*32 + g*8];
      bf16x8 va1 = *(const bf16x8*)&Vs[cur][16 + ln][k2*32 + g*8];
      __builtin_amdgcn_s_setprio(1);
#pragma unroll
      for (int mi = 0; mi < 4; mi++){
        f32x4 s0 = mfma16(kf0, qa[mi], z);     // S^T keys (2k2)*16..+16
        f32x4 s1 = mfma16(kf1, qa[mi], z);     // S^T keys (2k2+1)*16..+16
        float e0 = fexp2(s0[0]), e1 = fexp2(s0[1]);
        float e2 = fexp2(s0[2]), e3 = fexp2(s0[3]);
        float f0 = fexp2(s1[0]), f1 = fexp2(s1[1]);
        float f2 = fexp2(s1[2]), f3 = fexp2(s1[3]);
        uint4 pw;
        pw.x = packbf(e0, e1);
        pw.y = packbf(e2, e3);
        pw.z = packbf(f0, f1);
        pw.w = packbf(f2, f3);
        bf16x8 pa = *(bf16x8*)&pw;
        oacc[mi][0] = mfma16(pa, va0, oacc[mi][0]);
        oacc[mi][1] = mfma16(pa, va1, oacc[mi][1]);
        lacc[mi] = mfma16(pa, vones, lacc[mi]);
      }
      __builtin_amdgcn_s_setprio(0);
    }
    if (kt < 15){
      *(uint4*)&Ks[cur ^ 1][krow][kc] = kr2;
      *(uint4*)&Vs[cur ^ 1][vdim][vc] = vr2;
      __syncthreads();
    }
  }
  float rinv[4][4];
#pragma unroll
  for (int mi = 0; mi < 4; mi++)
#pragma unroll
    for (int i = 0; i < 4; i++) rinv[mi][i] = frcp(lacc[mi][i]);
#pragma unroll
  for (int mi = 0; mi < 4; mi++)
#pragma unroll
  for (int d2 = 0; d2 < 2; d2++)
#pragma unroll
  for (int i = 0; i < 4; i++){
    float v = oacc[mi][d2][i] * rinv[mi][i];
    int row = q0 + mi*16 + g*4 + i;
    ob[(size_t)(b*1024 + row)*CC + h*32 + d2*16 + ln] = f2bf(v);
  }
}

extern "C" void kernel_launch(void* const* d_in, const int* in_sizes, int n_in,
                              void* d_out, int out_size, void* d_ws, size_t ws_size,
                              hipStream_t stream)
{
  (void)in_sizes; (void)n_in; (void)out_size; (void)ws_size;
  const float* x     = (const float*)d_in[0];
  const float* ln1g  = (const float*)d_in[1];
  const float* ln1b  = (const float*)d_in[2];
  const float* Wq    = (const float*)d_in[3];
  const float* bq    = (const float*)d_in[4];
  const float* offk  = (const float*)d_in[5];
  const float* offkb = (const float*)d_in[6];
  const float* offg  = (const float*)d_in[7];
  const float* offb  = (const float*)d_in[8];
  const float* Woff  = (const float*)d_in[9];
  const float* boff  = (const float*)d_in[10];
  const float* Wk    = (const float*)d_in[11];
  const float* bk    = (const float*)d_in[12];
  const float* Wv    = (const float*)d_in[13];
  const float* bv    = (const float*)d_in[14];
  const float* Wo    = (const float*)d_in[15];
  const float* bo    = (const float*)d_in[16];
  const float* ln2g  = (const float*)d_in[17];
  const float* ln2b  = (const float*)d_in[18];
  const float* W1    = (const float*)d_in[19];
  const float* b1    = (const float*)d_in[20];
  const float* W2    = (const float*)d_in[21];
  const float* b2    = (const float*)d_in[22];

  char* ws = (char*)d_ws;
  // layout (bytes):
  //   [0, 12582912)          X2B bf16 (residual stream after attn)
  //   [12582912, 25165824)   XB bf16 (bf16 copy of input x)
  //   [25165824, 37748736)   XSB bf16      -+
  //   [37748736, 50331648)   KB bf16        |  reused as HB (50331648 B) in MLP
  //   [50331648, 62914560)   VT bf16        |
  //   [62914560, 75497472)   OB bf16       -+
  //   [75497472, 88080384)   XNB bf16
  //   [88080384, 100663296)  QSB bf16 -> reused as YB after attn
  //   [100663296, 104221440) weights bf16 (incl offk bf16 tail)
  unsigned short* X2B = (unsigned short*)ws;
  unsigned short* XB  = (unsigned short*)(ws + 12582912);
  unsigned short* XSB = (unsigned short*)(ws + 25165824);
  unsigned short* KB  = (unsigned short*)(ws + 37748736);
  unsigned short* VT  = (unsigned short*)(ws + 50331648);
  unsigned short* OB  = (unsigned short*)(ws + 62914560);
  unsigned short* XNB = (unsigned short*)(ws + 75497472);
  unsigned short* QSB = (unsigned short*)(ws + 88080384);
  unsigned short* YB  = QSB;
  unsigned short* HB  = (unsigned short*)(ws + 25165824);
  unsigned short* WQB = (unsigned short*)(ws + 100663296);
  unsigned short* WKB = WQB + 147456;   // Wk rows 0-383, Wv rows 384-767 (contiguous)
  unsigned short* WOB = WKB + 294912;
  unsigned short* W1B = WOB + 147456;
  unsigned short* W2B = W1B + 589824;
  unsigned short* OKB = W2B + 589824;   // bf16 offk [25][384]

  k_cvt_all<<<1738, 256, 0, stream>>>(Wq, Wk, Wv, Wo, W1, W2, offk, WQB);
  k_ln<0><<<4096, 256, 0, stream>>>(x, nullptr, ln1g, ln1b, XNB, XB);
  k_g64<5><<<768, 256, 0, stream>>>(XNB, WQB, bq, nullptr, nullptr, nullptr, QSB, nullptr, 3, 384, 384);
  k_offset_sample<<<16384, 64, 0, stream>>>(QSB, XNB, OKB, offkb, offg, offb, Woff, boff, XSB);
  k_g64<6><<<1536, 256, 0, stream>>>(XSB, WKB, bk, bv, nullptr, nullptr, KB, VT, 6, 768, 384);
  k_attn<<<768, 256, 0, stream>>>(QSB, KB, VT, OB);
  k_g64<8><<<768, 256, 0, stream>>>(OB, WOB, bo, nullptr, XB, nullptr, X2B, nullptr, 3, 384, 384);
  k_ln<1><<<4096, 256, 0, stream>>>(nullptr, X2B, ln2g, ln2b, YB, nullptr);
  k_mlp1<<<1536, 256, 0, stream>>>(YB, W1B, b1, HB);
  k_g64<7><<<768, 256, 0, stream>>>(HB, W2B, b2, nullptr, X2B, (float*)d_out, nullptr, nullptr, 3, 384, 1536);
}

// Round 13
// 208.080 us; speedup vs baseline: 1.5277x; 1.0091x over previous
//
#include <hip/hip_runtime.h>
#include <math.h>

#define DI __device__ __forceinline__

typedef __attribute__((ext_vector_type(8))) short bf16x8;
typedef __attribute__((ext_vector_type(4))) float f32x4;

static constexpr int CC = 384;
// attn scale * log2(e): scores come out of QK^T already in log2 domain
static constexpr float QSCALE = 0.17677669529663687f * 1.4426950408889634f;
static constexpr float INVQS  = 1.0f / QSCALE;

DI unsigned short f2bf(float f){
  unsigned u = __float_as_uint(f);
  u += 0x7FFFu + ((u >> 16) & 1u);
  return (unsigned short)(u >> 16);
}
DI float bf2f(unsigned short u){ return __uint_as_float((unsigned)u << 16); }
DI float lo16(unsigned u){ return __uint_as_float(u << 16); }
DI float hi16(unsigned u){ return __uint_as_float(u & 0xFFFF0000u); }
DI float fexp2(float x){ return __builtin_amdgcn_exp2f(x); }
DI float frcp(float x){ return __builtin_amdgcn_rcpf(x); }
// tanh(z) = 1 - 2/(exp2(z*2*log2e)+1)
DI float tanh_fast(float z){ return 1.f - 2.f*frcp(fexp2(2.8853900817779268f*z) + 1.f); }
DI float gelu_fast(float v){
  float u = v*v;
  float z = 0.7978845608028654f * fmaf(0.044715f*u, v, v);
  return v - v*frcp(fexp2(2.8853900817779268f*z) + 1.f);
}
DI f32x4 mfma16(bf16x8 a, bf16x8 b, f32x4 c){
  return __builtin_amdgcn_mfma_f32_16x16x32_bf16(a, b, c, 0, 0, 0);
}
DI void gload16(const unsigned short* g, unsigned short* l){
  __builtin_amdgcn_global_load_lds(
      (const __attribute__((address_space(1))) unsigned int*)(const void*)g,
      (__attribute__((address_space(3))) unsigned int*)(void*)l, 16, 0, 0);
}
// pack truncated hi16 of (pb, pa) -> (hi:pb, lo:pa)
DI unsigned packbf(float pa, float pb){
  return __builtin_amdgcn_perm(__float_as_uint(pb), __float_as_uint(pa), 0x07060302u);
}

// ---------------- weight fp32 -> bf16 (6 matmul weights + offk), vectorized x4 ---
__global__ __launch_bounds__(256) void k_cvt_all(
    const float* __restrict__ wq, const float* __restrict__ wk,
    const float* __restrict__ wv, const float* __restrict__ wo,
    const float* __restrict__ w1, const float* __restrict__ w2,
    const float* __restrict__ ofk,
    unsigned short* __restrict__ dst)
{
  int i4 = (blockIdx.x*256 + threadIdx.x)*4;
  if (i4 >= 1779072) return;
  const float* src; int off;
  if (i4 < 147456){ src = wq; off = i4; }
  else if (i4 < 294912){ src = wk; off = i4 - 147456; }
  else if (i4 < 442368){ src = wv; off = i4 - 294912; }
  else if (i4 < 589824){ src = wo; off = i4 - 442368; }
  else if (i4 < 1179648){ src = w1; off = i4 - 589824; }
  else if (i4 < 1769472){ src = w2; off = i4 - 1179648; }
  else { src = ofk; off = i4 - 1769472; }
  float4 v = *(const float4*)(src + off);
  uint2 o;
  o.x = ((unsigned)f2bf(v.y) << 16) | f2bf(v.x);
  o.y = ((unsigned)f2bf(v.w) << 16) | f2bf(v.z);
  *(uint2*)(dst + i4) = o;
}

// ---------------- LayerNorm over C=384, one wave/row, 4 rows/block --------------
// BIN=0: f32 input (scalar loads); optional outb2 = bf16 copy of raw input
// BIN=1: bf16 input (vectorized 6 ch/lane)
template<int BIN>
__global__ __launch_bounds__(256) void k_ln(const float* __restrict__ xf,
    const unsigned short* __restrict__ xb,
    const float* __restrict__ g, const float* __restrict__ b,
    unsigned short* __restrict__ outb, unsigned short* __restrict__ outb2)
{
  int row = blockIdx.x*4 + (threadIdx.x >> 6);
  int l = threadIdx.x & 63;
  float v[6]; int ch[6];
  if constexpr (BIN){
    int cA = 4*l, cB = 256 + 2*l;
    ch[0]=cA; ch[1]=cA+1; ch[2]=cA+2; ch[3]=cA+3; ch[4]=cB; ch[5]=cB+1;
    const unsigned short* xp = xb + (size_t)row * CC;
    uint2 u2 = *(const uint2*)(xp + cA);
    unsigned u1 = *(const unsigned*)(xp + cB);
    v[0]=lo16(u2.x); v[1]=hi16(u2.x); v[2]=lo16(u2.y); v[3]=hi16(u2.y);
    v[4]=lo16(u1);   v[5]=hi16(u1);
  } else {
    const float* xp = xf + (size_t)row * CC;
#pragma unroll
    for (int p = 0; p < 6; p++){ ch[p] = l + 64*p; v[p] = xp[ch[p]]; }
  }
  float s = 0.f, s2 = 0.f;
#pragma unroll
  for (int p = 0; p < 6; p++){ s += v[p]; s2 += v[p]*v[p]; }
#pragma unroll
  for (int m = 32; m; m >>= 1){ s += __shfl_xor(s, m); s2 += __shfl_xor(s2, m); }
  float mu = s * (1.f/CC);
  float var = s2 * (1.f/CC) - mu*mu;
  float rs = rsqrtf(var + 1e-5f);
  float o[6];
#pragma unroll
  for (int p = 0; p < 6; p++) o[p] = (v[p] - mu) * rs * g[ch[p]] + b[ch[p]];
  unsigned short* op = outb + (size_t)row*CC;
  if constexpr (BIN){
    uint2 st;
    st.x = ((unsigned)f2bf(o[1]) << 16) | f2bf(o[0]);
    st.y = ((unsigned)f2bf(o[3]) << 16) | f2bf(o[2]);
    *(uint2*)(op + ch[0]) = st;
    *(unsigned*)(op + ch[4]) = ((unsigned)f2bf(o[5]) << 16) | f2bf(o[4]);
  } else {
#pragma unroll
    for (int p = 0; p < 6; p++) op[ch[p]] = f2bf(o[p]);
    if (outb2){
      unsigned short* op2 = outb2 + (size_t)row*CC;
#pragma unroll
      for (int p = 0; p < 6; p++) op2[ch[p]] = f2bf(v[p]);
    }
  }
}

// ---------------- unified 64x128 GEMM, BK=64, dbuf LDS + gload_lds + XCD swizzle -
// out(M,N) = A(M,K) @ W(N,K)^T + bias.  1D grid, ntn = N/128 tiles. K % 64 == 0.
// EPI 3: bf16 gelu out
// EPI 5: bf16 * QSCALE out
// EPI 6: fused K|V (N=768): col<384 -> KB row-major; col>=384 -> VT key-permuted
// EPI 7: + bf16 res -> f32 out
// EPI 8: + bf16 res -> bf16 out
// VT phys key order (per 64-block): phys = (k6&0x23)|((k6&0xC)<<1)|((k6&0x10)>>2)
template<int EPI>
__global__ __launch_bounds__(256) void k_g64(
    const unsigned short* __restrict__ A, const unsigned short* __restrict__ W,
    const float* __restrict__ bias, const float* __restrict__ bias2,
    const unsigned short* __restrict__ resb,
    float* __restrict__ outf, unsigned short* __restrict__ outb,
    unsigned short* __restrict__ outb2, int ntn, int N, int K)
{
  __shared__ unsigned short As[2][4096];   // 64 rows x 64 cols, 8-slot swizzled
  __shared__ unsigned short Bs[2][8192];   // 128 rows x 64 cols
  int bid = blockIdx.x;
  int cpx = gridDim.x >> 3;
  int id = (bid & 7)*cpx + (bid >> 3);     // XCD-chunk swizzle
  int bn = (id % ntn) * 128;
  int bm = (id / ntn) * 64;
  int t = threadIdx.x;
  int w = t >> 6, l = t & 63;
  int g = l >> 4, ln = l & 15;
  int wm = w >> 1, wn = w & 1;             // wave: 32 rows x 64 cols
  f32x4 acc[2][4];
#pragma unroll
  for (int i = 0; i < 2; i++)
#pragma unroll
    for (int j = 0; j < 4; j++) acc[i][j] = (f32x4){0.f,0.f,0.f,0.f};
  // staging round j: rows j*32 + (t>>3), slot t&7; src col slot = (t&7)^((t>>3)&7)
  int srcoff = ((t & 7) ^ ((t >> 3) & 7)) * 8;
  int srowA = t >> 3;
  const unsigned short* Ap0 = A + (size_t)(bm + srowA)*K + srcoff;
  const unsigned short* Ap1 = A + (size_t)(bm + 32 + srowA)*K + srcoff;
  const unsigned short* Wp0 = W + (size_t)(bn + srowA)*K + srcoff;
  const unsigned short* Wp1 = W + (size_t)(bn + 32 + srowA)*K + srcoff;
  const unsigned short* Wp2 = W + (size_t)(bn + 64 + srowA)*K + srcoff;
  const unsigned short* Wp3 = W + (size_t)(bn + 96 + srowA)*K + srcoff;
  int NT = K >> 6;
  int wl = w*512;
  gload16(Ap0, &As[0][wl]);
  gload16(Ap1, &As[0][wl + 2048]);
  gload16(Wp0, &Bs[0][wl]);
  gload16(Wp1, &Bs[0][wl + 2048]);
  gload16(Wp2, &Bs[0][wl + 4096]);
  gload16(Wp3, &Bs[0][wl + 6144]);
  __syncthreads();
  for (int kt = 0; kt < NT; kt++){
    int cur = kt & 1;
    if (kt + 1 < NT){
      int k0 = (kt + 1) << 6;
      gload16(Ap0 + k0, &As[cur ^ 1][wl]);
      gload16(Ap1 + k0, &As[cur ^ 1][wl + 2048]);
      gload16(Wp0 + k0, &Bs[cur ^ 1][wl]);
      gload16(Wp1 + k0, &Bs[cur ^ 1][wl + 2048]);
      gload16(Wp2 + k0, &Bs[cur ^ 1][wl + 4096]);
      gload16(Wp3 + k0, &Bs[cur ^ 1][wl + 6144]);
    }
#pragma unroll
    for (int kk = 0; kk < 2; kk++){
      bf16x8 af[2], bf[4];
#pragma unroll
      for (int mi = 0; mi < 2; mi++){
        int row = wm*32 + mi*16 + ln;
        int sl = (kk*4 + g) ^ (row & 7);
        af[mi] = *(const bf16x8*)((const char*)As[cur] + row*128 + sl*16);
      }
#pragma unroll
      for (int ni = 0; ni < 4; ni++){
        int row = wn*64 + ni*16 + ln;
        int sl = (kk*4 + g) ^ (row & 7);
        bf[ni] = *(const bf16x8*)((const char*)Bs[cur] + row*128 + sl*16);
      }
#pragma unroll
      for (int mi = 0; mi < 2; mi++)
#pragma unroll
        for (int ni = 0; ni < 4; ni++)
          acc[mi][ni] = mfma16(af[mi], bf[ni], acc[mi][ni]);
    }
    if (kt + 1 < NT) __syncthreads();
  }
#pragma unroll
  for (int mi = 0; mi < 2; mi++)
#pragma unroll
  for (int ni = 0; ni < 4; ni++){
    int col = bn + wn*64 + ni*16 + ln;
    float bv;
    if constexpr (EPI == 6) bv = col < 384 ? bias[col] : bias2[col - 384];
    else bv = bias[col];
#pragma unroll
    for (int i = 0; i < 4; i++){
      int row = bm + wm*32 + mi*16 + g*4 + i;
      float v = acc[mi][ni][i] + bv;
      if constexpr (EPI == 3) outb[(size_t)row*N + col] = f2bf(gelu_fast(v));
      if constexpr (EPI == 5) outb[(size_t)row*N + col] = f2bf(v * QSCALE);
      if constexpr (EPI == 7){ v += bf2f(resb[(size_t)row*N + col]); outf[(size_t)row*N + col] = v; }
      if constexpr (EPI == 8){ v += bf2f(resb[(size_t)row*N + col]); outb[(size_t)row*N + col] = f2bf(v); }
      if constexpr (EPI == 6){
        if (col < 384){
          outb[(size_t)row*384 + col] = f2bf(v);
        } else {
          int c = col - 384;
          int bb = row >> 10, key = row & 1023, h = c >> 5, d = c & 31;
          int k6 = key & 63;
          int phys = (key & ~63) | (k6 & 0x23) | ((k6 & 0xC) << 1) | ((k6 & 0x10) >> 2);
          outb2[(size_t)(((bb*12 + h) << 5) + d)*1024 + phys] = f2bf(v);
        }
      }
    }
  }
}

// ---------------- fused offset net + grid sample: one WAVE per pixel -------------
// 8 channels/thread on 48 active lanes; all accesses are 16B uint4
__global__ __launch_bounds__(64) void k_offset_sample(
    const unsigned short* __restrict__ qs, const unsigned short* __restrict__ xnb,
    const unsigned short* __restrict__ okb,  // bf16 offk [25][384]
    const float* __restrict__ offkb,
    const float* __restrict__ offg, const float* __restrict__ offb,
    const float* __restrict__ Woff, const float* __restrict__ boff,
    unsigned short* __restrict__ xsb)
{
  int blk = blockIdx.x;
  int pix = (blk & 7)*2048 + (blk >> 3);   // each XCD gets 2 contiguous images
  int b = pix >> 10, n = pix & 1023;
  int y = n >> 5, x = n & 31;
  int t = threadIdx.x;
  int c8 = (t < 48 ? t : 47) * 8;          // clamped channel base (lanes 48+ idle)
  float act = t < 48 ? 1.f : 0.f;
  const unsigned short* qb = qs + (size_t)b*1024*CC;
  int ry[5], rx[5]; unsigned my[5], mx[5];
#pragma unroll
  for (int k = 0; k < 5; k++){
    int yy = y + k - 2, xx = x + k - 2;
    my[k] = (yy >= 0 && yy < 32) ? 0xFFFFFFFFu : 0u;
    mx[k] = (xx >= 0 && xx < 32) ? 0xFFFFFFFFu : 0u;
    int yc = yy < 0 ? 0 : (yy > 31 ? 31 : yy);
    int xc = xx < 0 ? 0 : (xx > 31 ? 31 : xx);
    ry[k] = yc*32*CC; rx[k] = xc*CC;
  }
  float a[8];
#pragma unroll
  for (int j = 0; j < 8; j++) a[j] = 0.f;
#pragma unroll
  for (int ky = 0; ky < 5; ky++)
#pragma unroll
  for (int kx = 0; kx < 5; kx++){
    int tap = ky*5 + kx;
    unsigned m = my[ky] & mx[kx];
    uint4 q4 = *(const uint4*)(qb + ry[ky] + rx[kx] + c8);
    uint4 w4 = *(const uint4*)(okb + tap*CC + c8);
    q4.x &= m; q4.y &= m; q4.z &= m; q4.w &= m;
    a[0] = fmaf(lo16(q4.x), lo16(w4.x), a[0]);
    a[1] = fmaf(hi16(q4.x), hi16(w4.x), a[1]);
    a[2] = fmaf(lo16(q4.y), lo16(w4.y), a[2]);
    a[3] = fmaf(hi16(q4.y), hi16(w4.y), a[3]);
    a[4] = fmaf(lo16(q4.z), lo16(w4.z), a[4]);
    a[5] = fmaf(hi16(q4.z), hi16(w4.z), a[5]);
    a[6] = fmaf(lo16(q4.w), lo16(w4.w), a[6]);
    a[7] = fmaf(hi16(q4.w), hi16(w4.w), a[7]);
  }
  float4 kbA = *(const float4*)(offkb + c8);
  float4 kbB = *(const float4*)(offkb + c8 + 4);
  float c[8];
  c[0] = act * fmaf(a[0], INVQS, kbA.x);
  c[1] = act * fmaf(a[1], INVQS, kbA.y);
  c[2] = act * fmaf(a[2], INVQS, kbA.z);
  c[3] = act * fmaf(a[3], INVQS, kbA.w);
  c[4] = act * fmaf(a[4], INVQS, kbB.x);
  c[5] = act * fmaf(a[5], INVQS, kbB.y);
  c[6] = act * fmaf(a[6], INVQS, kbB.z);
  c[7] = act * fmaf(a[7], INVQS, kbB.w);
  float s = 0.f, s2 = 0.f;
#pragma unroll
  for (int j = 0; j < 8; j++){ s += c[j]; s2 += c[j]*c[j]; }
#pragma unroll
  for (int m2 = 32; m2; m2 >>= 1){ s += __shfl_xor(s, m2); s2 += __shfl_xor(s2, m2); }
  float mu = s * (1.f/CC);
  float var = s2 * (1.f/CC) - mu*mu;
  float rs = rsqrtf(var + 1e-5f);
  float4 gA = *(const float4*)(offg + c8); float4 gB = *(const float4*)(offg + c8 + 4);
  float4 oA = *(const float4*)(offb + c8); float4 oB = *(const float4*)(offb + c8 + 4);
  float4 wA = *(const float4*)(Woff + c8); float4 wB = *(const float4*)(Woff + c8 + 4);
  float4 wC = *(const float4*)(Woff + CC + c8); float4 wD = *(const float4*)(Woff + CC + c8 + 4);
  float gg[8] = {gA.x,gA.y,gA.z,gA.w,gB.x,gB.y,gB.z,gB.w};
  float bb[8] = {oA.x,oA.y,oA.z,oA.w,oB.x,oB.y,oB.z,oB.w};
  float w0[8] = {wA.x,wA.y,wA.z,wA.w,wB.x,wB.y,wB.z,wB.w};
  float w1[8] = {wC.x,wC.y,wC.z,wC.w,wD.x,wD.y,wD.z,wD.w};
  float p0 = 0.f, p1 = 0.f;
#pragma unroll
  for (int j = 0; j < 8; j++){
    float v = gelu_fast((c[j] - mu)*rs*gg[j] + bb[j]) * act;
    p0 = fmaf(v, w0[j], p0);
    p1 = fmaf(v, w1[j], p1);
  }
#pragma unroll
  for (int m2 = 32; m2; m2 >>= 1){ p0 += __shfl_xor(p0, m2); p1 += __shfl_xor(p1, m2); }
  float offy = tanh_fast(p0 + boff[0]) * 0.125f;
  float offx = tanh_fast(p1 + boff[1]) * 0.125f;
  float py = ((y + 0.5f)/16.f - 1.f + offy + 1.f) * 0.5f * 31.f;
  float px = ((x + 0.5f)/16.f - 1.f + offx + 1.f) * 0.5f * 31.f;
  float y0f = floorf(py), x0f = floorf(px);
  float wy = py - y0f, wx = px - x0f;
  int y0 = (int)y0f, x0 = (int)x0f;
  y0 = y0 < 0 ? 0 : (y0 > 31 ? 31 : y0);
  x0 = x0 < 0 ? 0 : (x0 > 31 ? 31 : x0);
  int y1 = y0 + 1 > 31 ? 31 : y0 + 1;
  int x1 = x0 + 1 > 31 ? 31 : x0 + 1;
  const unsigned short* s00 = xnb + (size_t)(b*1024 + y0*32 + x0)*CC + c8;
  const unsigned short* s01 = xnb + (size_t)(b*1024 + y0*32 + x1)*CC + c8;
  const unsigned short* s10 = xnb + (size_t)(b*1024 + y1*32 + x0)*CC + c8;
  const unsigned short* s11 = xnb + (size_t)(b*1024 + y1*32 + x1)*CC + c8;
  float w00 = (1.f-wy)*(1.f-wx), w01 = (1.f-wy)*wx, w10 = wy*(1.f-wx), w11 = wy*wx;
  uint4 A0 = *(const uint4*)s00;
  uint4 A1 = *(const uint4*)s01;
  uint4 A2 = *(const uint4*)s10;
  uint4 A3 = *(const uint4*)s11;
  if (t < 48){
    float r[8];
    r[0] = w00*lo16(A0.x) + w01*lo16(A1.x) + w10*lo16(A2.x) + w11*lo16(A3.x);
    r[1] = w00*hi16(A0.x) + w01*hi16(A1.x) + w10*hi16(A2.x) + w11*hi16(A3.x);
    r[2] = w00*lo16(A0.y) + w01*lo16(A1.y) + w10*lo16(A2.y) + w11*lo16(A3.y);
    r[3] = w00*hi16(A0.y) + w01*hi16(A1.y) + w10*hi16(A2.y) + w11*hi16(A3.y);
    r[4] = w00*lo16(A0.z) + w01*lo16(A1.z) + w10*lo16(A2.z) + w11*lo16(A3.z);
    r[5] = w00*hi16(A0.z) + w01*hi16(A1.z) + w10*hi16(A2.z) + w11*hi16(A3.z);
    r[6] = w00*lo16(A0.w) + w01*lo16(A1.w) + w10*lo16(A2.w) + w11*lo16(A3.w);
    r[7] = w00*hi16(A0.w) + w01*hi16(A1.w) + w10*hi16(A2.w) + w11*hi16(A3.w);
    uint4 st;
    st.x = ((unsigned)f2bf(r[1]) << 16) | f2bf(r[0]);
    st.y = ((unsigned)f2bf(r[3]) << 16) | f2bf(r[2]);
    st.z = ((unsigned)f2bf(r[5]) << 16) | f2bf(r[4]);
    st.w = ((unsigned)f2bf(r[7]) << 16) | f2bf(r[6]);
    *(uint4*)(xsb + (size_t)(b*1024 + n)*CC + c8) = st;
  }
}

// ---------------- attention: swapped QK^T, 64 q-rows/wave, 128-key buffers -------
// qs: bf16 Q scaled by QSCALE; kb row-major; vt: V^T [b][h][d][1024] key-permuted
// Block covers 256 q-rows (4 waves x 64); grid 768 = 4 qt x 12 h x 16 b.
__global__ __launch_bounds__(256) void k_attn(
    const unsigned short* __restrict__ qs, const unsigned short* __restrict__ kb,
    const unsigned short* __restrict__ vt, unsigned short* __restrict__ ob)
{
  __shared__ unsigned short Ks[2][128][40];  // [buf][key][dim]
  __shared__ unsigned short Vs[2][32][136];  // [buf][dim][physkey]
  int blk = blockIdx.x;
  int sw = (blk & 7)*96 + (blk >> 3);     // XCD-grouped
  int qt = sw & 3, h = (sw >> 2) % 12, b = sw / 48;
  int t = threadIdx.x;
  int w = t >> 6, l = t & 63;
  int g = l >> 4, ln = l & 15;
  int q0 = qt*256 + w*64;
  bf16x8 qa[4];
#pragma unroll
  for (int mi = 0; mi < 4; mi++)
    qa[mi] = *(const bf16x8*)&qs[(size_t)(b*1024 + q0 + mi*16 + ln)*CC + h*32 + g*8];
  bf16x8 vones;
#pragma unroll
  for (int j = 0; j < 8; j++) vones[j] = (short)0x3F80;   // bf16 1.0
  f32x4 z = {0.f,0.f,0.f,0.f};
  f32x4 oacc[4][2];
#pragma unroll
  for (int mi = 0; mi < 4; mi++){ oacc[mi][0]=z; oacc[mi][1]=z; }
  f32x4 lacc[4]; lacc[0]=z; lacc[1]=z; lacc[2]=z; lacc[3]=z;
  int krow = t >> 2, kc = (t & 3)*8;
  int vdim = t >> 3, vc = (t & 7)*8;
  const unsigned short* kptr = kb + (size_t)(b*1024 + krow)*CC + h*32 + kc;
  const unsigned short* vptr = vt + (size_t)((b*12 + h)*32 + vdim)*1024 + vc;
  {
    uint4 k0r = *(const uint4*)kptr;
    uint4 k1r = *(const uint4*)(kptr + (size_t)64*CC);
    uint4 v0r = *(const uint4*)vptr;
    uint4 v1r = *(const uint4*)(vptr + 64);
    *(uint4*)&Ks[0][krow][kc] = k0r;
    *(uint4*)&Ks[0][64 + krow][kc] = k1r;
    *(uint4*)&Vs[0][vdim][vc] = v0r;
    *(uint4*)&Vs[0][vdim][64 + vc] = v1r;
  }
  __syncthreads();
  for (int kt = 0; kt < 8; kt++){
    int cur = kt & 1;
    uint4 k0r, k1r, v0r, v1r;
    if (kt < 7){
      size_t k0 = (size_t)(kt + 1)*128;
      k0r = *(const uint4*)(kptr + k0*CC);
      k1r = *(const uint4*)(kptr + (k0 + 64)*CC);
      v0r = *(const uint4*)(vptr + k0);
      v1r = *(const uint4*)(vptr + k0 + 64);
    }
#pragma unroll
    for (int sub = 0; sub < 2; sub++){
#pragma unroll
      for (int k2 = 0; k2 < 2; k2++){
        bf16x8 kf0 = *(const bf16x8*)&Ks[cur][sub*64 + (2*k2)*16 + ln][g*8];
        bf16x8 kf1 = *(const bf16x8*)&Ks[cur][sub*64 + (2*k2+1)*16 + ln][g*8];
        bf16x8 va0 = *(const bf16x8*)&Vs[cur][ln][sub*64 + k2*32 + g*8];
        bf16x8 va1 = *(const bf16x8*)&Vs[cur][16 + ln][sub*64 + k2*32 + g*8];
        __builtin_amdgcn_s_setprio(1);
#pragma unroll
        for (int mi = 0; mi < 4; mi++){
          f32x4 s0 = mfma16(kf0, qa[mi], z);     // S^T
          f32x4 s1 = mfma16(kf1, qa[mi], z);
          float e0 = fexp2(s0[0]), e1 = fexp2(s0[1]);
          float e2 = fexp2(s0[2]), e3 = fexp2(s0[3]);
          float f0 = fexp2(s1[0]), f1 = fexp2(s1[1]);
          float f2 = fexp2(s1[2]), f3 = fexp2(s1[3]);
          uint4 pw;
          pw.x = packbf(e0, e1);
          pw.y = packbf(e2, e3);
          pw.z = packbf(f0, f1);
          pw.w = packbf(f2, f3);
          bf16x8 pa = *(bf16x8*)&pw;
          oacc[mi][0] = mfma16(pa, va0, oacc[mi][0]);
          oacc[mi][1] = mfma16(pa, va1, oacc[mi][1]);
          lacc[mi] = mfma16(pa, vones, lacc[mi]);
        }
        __builtin_amdgcn_s_setprio(0);
      }
    }
    if (kt < 7){
      *(uint4*)&Ks[cur ^ 1][krow][kc] = k0r;
      *(uint4*)&Ks[cur ^ 1][64 + krow][kc] = k1r;
      *(uint4*)&Vs[cur ^ 1][vdim][vc] = v0r;
      *(uint4*)&Vs[cur ^ 1][vdim][64 + vc] = v1r;
      __syncthreads();
    }
  }
  float rinv[4][4];
#pragma unroll
  for (int mi = 0; mi < 4; mi++)
#pragma unroll
    for (int i = 0; i < 4; i++) rinv[mi][i] = frcp(lacc[mi][i]);
#pragma unroll
  for (int mi = 0; mi < 4; mi++)
#pragma unroll
  for (int d2 = 0; d2 < 2; d2++)
#pragma unroll
  for (int i = 0; i < 4; i++){
    float v = oacc[mi][d2][i] * rinv[mi][i];
    int row = q0 + mi*16 + g*4 + i;
    ob[(size_t)(b*1024 + row)*CC + h*32 + d2*16 + ln] = f2bf(v);
  }
}

extern "C" void kernel_launch(void* const* d_in, const int* in_sizes, int n_in,
                              void* d_out, int out_size, void* d_ws, size_t ws_size,
                              hipStream_t stream)
{
  (void)in_sizes; (void)n_in; (void)out_size; (void)ws_size;
  const float* x     = (const float*)d_in[0];
  const float* ln1g  = (const float*)d_in[1];
  const float* ln1b  = (const float*)d_in[2];
  const float* Wq    = (const float*)d_in[3];
  const float* bq    = (const float*)d_in[4];
  const float* offk  = (const float*)d_in[5];
  const float* offkb = (const float*)d_in[6];
  const float* offg  = (const float*)d_in[7];
  const float* offb  = (const float*)d_in[8];
  const float* Woff  = (const float*)d_in[9];
  const float* boff  = (const float*)d_in[10];
  const float* Wk    = (const float*)d_in[11];
  const float* bk    = (const float*)d_in[12];
  const float* Wv    = (const float*)d_in[13];
  const float* bv    = (const float*)d_in[14];
  const float* Wo    = (const float*)d_in[15];
  const float* bo    = (const float*)d_in[16];
  const float* ln2g  = (const float*)d_in[17];
  const float* ln2b  = (const float*)d_in[18];
  const float* W1    = (const float*)d_in[19];
  const float* b1    = (const float*)d_in[20];
  const float* W2    = (const float*)d_in[21];
  const float* b2    = (const float*)d_in[22];

  char* ws = (char*)d_ws;
  unsigned short* X2B = (unsigned short*)ws;
  unsigned short* XB  = (unsigned short*)(ws + 12582912);
  unsigned short* XSB = (unsigned short*)(ws + 25165824);
  unsigned short* KB  = (unsigned short*)(ws + 37748736);
  unsigned short* VT  = (unsigned short*)(ws + 50331648);
  unsigned short* OB  = (unsigned short*)(ws + 62914560);
  unsigned short* XNB = (unsigned short*)(ws + 75497472);
  unsigned short* QSB = (unsigned short*)(ws + 88080384);
  unsigned short* YB  = QSB;
  unsigned short* HB  = (unsigned short*)(ws + 25165824);
  unsigned short* WQB = (unsigned short*)(ws + 100663296);
  unsigned short* WKB = WQB + 147456;   // Wk rows 0-383, Wv rows 384-767 (contiguous)
  unsigned short* WOB = WKB + 294912;
  unsigned short* W1B = WOB + 147456;
  unsigned short* W2B = W1B + 589824;
  unsigned short* OKB = W2B + 589824;   // bf16 offk [25][384]

  k_cvt_all<<<1738, 256, 0, stream>>>(Wq, Wk, Wv, Wo, W1, W2, offk, WQB);
  k_ln<0><<<4096, 256, 0, stream>>>(x, nullptr, ln1g, ln1b, XNB, XB);
  k_g64<5><<<768, 256, 0, stream>>>(XNB, WQB, bq, nullptr, nullptr, nullptr, QSB, nullptr, 3, 384, 384);
  k_offset_sample<<<16384, 64, 0, stream>>>(QSB, XNB, OKB, offkb, offg, offb, Woff, boff, XSB);
  k_g64<6><<<1536, 256, 0, stream>>>(XSB, WKB, bk, bv, nullptr, nullptr, KB, VT, 6, 768, 384);
  k_attn<<<768, 256, 0, stream>>>(QSB, KB, VT, OB);
  k_g64<8><<<768, 256, 0, stream>>>(OB, WOB, bo, nullptr, XB, nullptr, X2B, nullptr, 3, 384, 384);
  k_ln<1><<<4096, 256, 0, stream>>>(nullptr, X2B, ln2g, ln2b, YB, nullptr);
  k_g64<3><<<3072, 256, 0, stream>>>(YB, W1B, b1, nullptr, nullptr, nullptr, HB, nullptr, 12, 1536, 384);
  k_g64<7><<<768, 256, 0, stream>>>(HB, W2B, b2, nullptr, X2B, (float*)d_out, nullptr, nullptr, 3, 384, 1536);
}